// Round 1
// baseline (1690.337 us; speedup 1.0000x reference)
//
#include <hip/hip_runtime.h>
#include <hip/hip_bf16.h>

typedef unsigned short u16;
typedef unsigned int u32;

#define NP 20000
#define NS 10000
#define NE 400000
#define H  512
#define FDIM 64

__device__ __forceinline__ float bl16(u32 w){ return __uint_as_float(w << 16); }
__device__ __forceinline__ float bh16(u32 w){ return __uint_as_float(w & 0xffff0000u); }
__device__ __forceinline__ u16 f2bf(float f){
  u32 u = __float_as_uint(f);
  u32 r = u + 0x7fffu + ((u >> 16) & 1u);
  return (u16)(r >> 16);
}
__device__ __forceinline__ u32 pack2(float a, float b){
  return (u32)f2bf(a) | ((u32)f2bf(b) << 16);
}

// ---------------- input projection: Y = relu(X @ W + b), X [n,64] f32, W [64,512], Y bf16 ----------------
__global__ __launch_bounds__(256) void proj_kernel(const float* __restrict__ X, const float* __restrict__ W,
                                                   const float* __restrict__ b, u16* __restrict__ Y, int n)
{
  __shared__ float xs[8][FDIM];
  int tid = threadIdx.x;
  int m0 = blockIdx.x * 8;
  {
    int r = tid >> 6, c = tid & 63;
    int m = m0 + r;
    xs[r][c] = (m < n) ? X[(size_t)m*FDIM + c] : 0.f;
    m = m0 + r + 4;
    xs[r+4][c] = (m < n) ? X[(size_t)m*FDIM + c] : 0.f;
  }
  __syncthreads();
  float acc[8][2] = {};
  int c0 = tid, c1 = tid + 256;
  for (int k = 0; k < FDIM; ++k){
    float w0 = W[k*H + c0];
    float w1 = W[k*H + c1];
    #pragma unroll
    for (int r = 0; r < 8; ++r){
      float xv = xs[r][k];
      acc[r][0] = fmaf(xv, w0, acc[r][0]);
      acc[r][1] = fmaf(xv, w1, acc[r][1]);
    }
  }
  float b0 = b[c0], b1 = b[c1];
  #pragma unroll
  for (int r = 0; r < 8; ++r){
    int m = m0 + r;
    if (m < n){
      Y[(size_t)m*H + c0] = f2bf(fmaxf(acc[r][0] + b0, 0.f));
      Y[(size_t)m*H + c1] = f2bf(fmaxf(acc[r][1] + b1, 0.f));
    }
  }
}

// ---------------- CSR build ----------------
__global__ void hist_kernel(const int* __restrict__ ps_dst, const int* __restrict__ sp_dst,
                            int* __restrict__ cnt_s, int* __restrict__ cnt_p)
{
  int e = blockIdx.x * blockDim.x + threadIdx.x;
  if (e < NE){
    atomicAdd(&cnt_s[ps_dst[e]], 1);
    atomicAdd(&cnt_p[sp_dst[e]], 1);
  }
}

__global__ __launch_bounds__(1024) void scan_kernel(const int* __restrict__ cnt, int n,
                                                    int* __restrict__ rowptr, int* __restrict__ cursor)
{
  __shared__ int lds[1024];
  __shared__ int carry_s;
  int tid = threadIdx.x;
  if (tid == 0) carry_s = 0;
  __syncthreads();
  for (int base = 0; base < n; base += 1024){
    int i = base + tid;
    int v = (i < n) ? cnt[i] : 0;
    lds[tid] = v;
    __syncthreads();
    for (int off = 1; off < 1024; off <<= 1){
      int t = (tid >= off) ? lds[tid - off] : 0;
      __syncthreads();
      lds[tid] += t;
      __syncthreads();
    }
    int incl = lds[tid];
    int cb = carry_s;
    if (i < n){
      rowptr[i] = cb + incl - v;
      cursor[i] = cb + incl - v;
    }
    __syncthreads();
    if (tid == 0) carry_s = cb + lds[1023];
    __syncthreads();
  }
  if (tid == 0) rowptr[n] = carry_s;
}

__global__ void scatter_kernel(const int* __restrict__ ps_src, const int* __restrict__ ps_dst,
                               const int* __restrict__ sp_src, const int* __restrict__ sp_dst,
                               int* __restrict__ cur_s, int* __restrict__ cur_p,
                               int* __restrict__ sorted_ps, int* __restrict__ sorted_sp)
{
  int e = blockIdx.x * blockDim.x + threadIdx.x;
  if (e < NE){
    int pos = atomicAdd(&cur_s[ps_dst[e]], 1);
    sorted_ps[pos] = ps_src[e];
    int pos2 = atomicAdd(&cur_p[sp_dst[e]], 1);
    sorted_sp[pos2] = sp_src[e];
  }
}

// ---------------- mean aggregation: one wave per dst row ----------------
__global__ __launch_bounds__(256) void agg_kernel(const u16* __restrict__ X, const int* __restrict__ rowptr,
                                                  const int* __restrict__ srcs, u16* __restrict__ M, int n_dst)
{
  int wid = (blockIdx.x << 2) + (threadIdx.x >> 6);
  int lane = threadIdx.x & 63;
  if (wid >= n_dst) return;
  int beg = rowptr[wid], end = rowptr[wid + 1];
  float acc[8] = {0,0,0,0,0,0,0,0};
  for (int i = beg; i < end; ++i){
    int s = srcs[i];
    uint4 v = *(const uint4*)(X + (size_t)s*H + (lane << 3));
    acc[0] += bl16(v.x); acc[1] += bh16(v.x);
    acc[2] += bl16(v.y); acc[3] += bh16(v.y);
    acc[4] += bl16(v.z); acc[5] += bh16(v.z);
    acc[6] += bl16(v.w); acc[7] += bh16(v.w);
  }
  float inv = 1.f / (float)max(end - beg, 1);
  uint4 o;
  o.x = pack2(acc[0]*inv, acc[1]*inv);
  o.y = pack2(acc[2]*inv, acc[3]*inv);
  o.z = pack2(acc[4]*inv, acc[5]*inv);
  o.w = pack2(acc[6]*inv, acc[7]*inv);
  *(uint4*)(M + (size_t)wid*H + (lane << 3)) = o;
}

// ---------------- fused GEMM: C = act(A@W1 [+ B@W2] [+ bias]), A/B bf16 [n,512], W f32 [512,512] ----------------
__global__ __launch_bounds__(256) void gemm_kernel(
    const u16* __restrict__ A, const float* __restrict__ W1,
    const u16* __restrict__ B, const float* __restrict__ W2,
    const float* __restrict__ bias, u16* __restrict__ C, int nrows, int do_relu)
{
  __shared__ float as_[16][68];
  __shared__ float wsm[16][68];
  int tid = threadIdx.x;
  int tx = tid & 15, ty = tid >> 4;
  int m0 = blockIdx.y * 64, n0 = blockIdx.x * 64;
  float acc[4][4] = {};
  for (int phase = 0; phase < 2; ++phase){
    const u16* Ap = phase ? B : A;
    const float* Wp = phase ? W2 : W1;
    if (!Ap) break;
    for (int k0 = 0; k0 < H; k0 += 16){
      {
        int row = tid >> 2;
        int ks = (tid & 3) << 2;
        int m = m0 + row;
        float f0, f1, f2, f3;
        if (m < nrows){
          uint2 v = *(const uint2*)(Ap + (size_t)m*H + k0 + ks);
          f0 = bl16(v.x); f1 = bh16(v.x); f2 = bl16(v.y); f3 = bh16(v.y);
        } else { f0 = f1 = f2 = f3 = 0.f; }
        as_[ks+0][row] = f0; as_[ks+1][row] = f1; as_[ks+2][row] = f2; as_[ks+3][row] = f3;
      }
      {
        int kk = tid >> 4;
        int c = (tid & 15) << 2;
        float4 w = *(const float4*)(Wp + (size_t)(k0+kk)*H + n0 + c);
        *(float4*)&wsm[kk][c] = w;
      }
      __syncthreads();
      #pragma unroll
      for (int kk = 0; kk < 16; ++kk){
        float4 av = *(const float4*)&as_[kk][ty << 2];
        float4 wv = *(const float4*)&wsm[kk][tx << 2];
        float a[4] = {av.x, av.y, av.z, av.w};
        float w[4] = {wv.x, wv.y, wv.z, wv.w};
        #pragma unroll
        for (int i = 0; i < 4; ++i)
          #pragma unroll
          for (int j = 0; j < 4; ++j)
            acc[i][j] = fmaf(a[i], w[j], acc[i][j]);
      }
      __syncthreads();
    }
  }
  float bv[4] = {0,0,0,0};
  if (bias){
    #pragma unroll
    for (int j = 0; j < 4; ++j) bv[j] = bias[n0 + (tx<<2) + j];
  }
  #pragma unroll
  for (int i = 0; i < 4; ++i){
    int m = m0 + (ty<<2) + i;
    if (m < nrows){
      float v0 = acc[i][0] + bv[0], v1 = acc[i][1] + bv[1];
      float v2 = acc[i][2] + bv[2], v3 = acc[i][3] + bv[3];
      if (do_relu){
        v0 = fmaxf(v0, 0.f); v1 = fmaxf(v1, 0.f);
        v2 = fmaxf(v2, 0.f); v3 = fmaxf(v3, 0.f);
      }
      uint2 o; o.x = pack2(v0, v1); o.y = pack2(v2, v3);
      *(uint2*)(C + (size_t)m*H + n0 + (tx<<2)) = o;
    }
  }
}

// ---------------- edge decoder: one wave per edge ----------------
__global__ __launch_bounds__(256) void edge_kernel(
    const u16* __restrict__ Adec, const u16* __restrict__ Bdec,
    const float* __restrict__ d1W, const float* __restrict__ d1b,
    const float* __restrict__ d2W, const float* __restrict__ d2b,
    const int* __restrict__ row, const int* __restrict__ col,
    const float* __restrict__ attr, float* __restrict__ out)
{
  int lane = threadIdx.x & 63;
  int wid = (blockIdx.x << 2) + (threadIdx.x >> 6);
  int nw = gridDim.x << 2;
  int j0 = lane << 3;
  float w1a[8], w1b[8], bb[8], w2[8][3];
  #pragma unroll
  for (int q = 0; q < 8; ++q){
    w1a[q] = d1W[(size_t)1024*H + j0 + q];
    w1b[q] = d1W[(size_t)1025*H + j0 + q];
    bb[q]  = d1b[j0 + q];
    w2[q][0] = d2W[(j0+q)*3 + 0];
    w2[q][1] = d2W[(j0+q)*3 + 1];
    w2[q][2] = d2W[(j0+q)*3 + 2];
  }
  float ob0 = d2b[0], ob1 = d2b[1], ob2 = d2b[2];
  for (int e = wid; e < NE; e += nw){
    int r = row[e], c = col[e];
    float a0 = attr[2*e], a1 = attr[2*e+1];
    uint4 va = *(const uint4*)(Adec + (size_t)r*H + j0);
    uint4 vb = *(const uint4*)(Bdec + (size_t)c*H + j0);
    float fa[8] = {bl16(va.x),bh16(va.x),bl16(va.y),bh16(va.y),bl16(va.z),bh16(va.z),bl16(va.w),bh16(va.w)};
    float fb[8] = {bl16(vb.x),bh16(vb.x),bl16(vb.y),bh16(vb.y),bl16(vb.z),bh16(vb.z),bl16(vb.w),bh16(vb.w)};
    float s0 = 0.f, s1 = 0.f, s2 = 0.f;
    #pragma unroll
    for (int q = 0; q < 8; ++q){
      float h = fa[q] + fb[q] + bb[q];
      h = fmaf(a0, w1a[q], h);
      h = fmaf(a1, w1b[q], h);
      h = fmaxf(h, 0.f);
      s0 = fmaf(h, w2[q][0], s0);
      s1 = fmaf(h, w2[q][1], s1);
      s2 = fmaf(h, w2[q][2], s2);
    }
    #pragma unroll
    for (int off = 32; off > 0; off >>= 1){
      s0 += __shfl_xor(s0, off);
      s1 += __shfl_xor(s1, off);
      s2 += __shfl_xor(s2, off);
    }
    if (lane == 0){
      out[(size_t)e*3 + 0] = s0 + ob0;
      out[(size_t)e*3 + 1] = s1 + ob1;
      out[(size_t)e*3 + 2] = s2 + ob2;
    }
  }
}

extern "C" void kernel_launch(void* const* d_in, const int* in_sizes, int n_in,
                              void* d_out, int out_size, void* d_ws, size_t ws_size,
                              hipStream_t stream)
{
  const float* x_pol    = (const float*)d_in[0];
  const float* x_stock  = (const float*)d_in[1];
  const float* attr     = (const float*)d_in[2];
  const float* Wp       = (const float*)d_in[3];
  const float* bp       = (const float*)d_in[4];
  const float* Wst      = (const float*)d_in[5];
  const float* bst      = (const float*)d_in[6];
  const float* c1_ps_Wl = (const float*)d_in[7];
  const float* c1_ps_bl = (const float*)d_in[8];
  const float* c1_ps_Wr = (const float*)d_in[9];
  const float* c1_sp_Wl = (const float*)d_in[10];
  const float* c1_sp_bl = (const float*)d_in[11];
  const float* c1_sp_Wr = (const float*)d_in[12];
  const float* c2_ps_Wl = (const float*)d_in[13];
  const float* c2_ps_bl = (const float*)d_in[14];
  const float* c2_ps_Wr = (const float*)d_in[15];
  const float* c2_sp_Wl = (const float*)d_in[16];
  const float* c2_sp_bl = (const float*)d_in[17];
  const float* c2_sp_Wr = (const float*)d_in[18];
  const float* d1W      = (const float*)d_in[19];
  const float* d1b      = (const float*)d_in[20];
  const float* d2W      = (const float*)d_in[21];
  const float* d2b      = (const float*)d_in[22];
  const int* ps_src     = (const int*)d_in[23];
  const int* ps_dst     = (const int*)d_in[24];
  const int* sp_src     = (const int*)d_in[25];
  const int* sp_dst     = (const int*)d_in[26];
  const int* trow       = (const int*)d_in[27];
  const int* tcol       = (const int*)d_in[28];
  float* out = (float*)d_out;

  char* ws = (char*)d_ws;
  size_t off = 0;
  auto alloc = [&](size_t bytes)->char*{
    char* p = ws + off;
    off += (bytes + 255) & ~(size_t)255;
    return p;
  };
  u16* P0 = (u16*)alloc((size_t)NP*H*2);   // hp -> hp2
  u16* P1 = (u16*)alloc((size_t)NP*H*2);   // hp1
  u16* S0 = (u16*)alloc((size_t)NS*H*2);   // hs -> hs2
  u16* S1 = (u16*)alloc((size_t)NS*H*2);   // hs1
  u16* MP = (u16*)alloc((size_t)NP*H*2);   // mean into pol / Adec
  u16* MS = (u16*)alloc((size_t)NS*H*2);   // mean into stock / Bdec
  int* cnt_s    = (int*)alloc((size_t)NS*4);
  int* cnt_p    = (int*)alloc((size_t)NP*4);
  int* rowptr_s = (int*)alloc((size_t)(NS+1)*4);
  int* rowptr_p = (int*)alloc((size_t)(NP+1)*4);
  int* cur_s    = (int*)alloc((size_t)NS*4);
  int* cur_p    = (int*)alloc((size_t)NP*4);
  int* sorted_ps = (int*)alloc((size_t)NE*4);
  int* sorted_sp = (int*)alloc((size_t)NE*4);

  // CSR build (shared by conv1 and conv2)
  hipMemsetAsync(cnt_s, 0, (size_t)NS*4, stream);
  hipMemsetAsync(cnt_p, 0, (size_t)NP*4, stream);
  hist_kernel<<<(NE+255)/256, 256, 0, stream>>>(ps_dst, sp_dst, cnt_s, cnt_p);
  scan_kernel<<<1, 1024, 0, stream>>>(cnt_s, NS, rowptr_s, cur_s);
  scan_kernel<<<1, 1024, 0, stream>>>(cnt_p, NP, rowptr_p, cur_p);
  scatter_kernel<<<(NE+255)/256, 256, 0, stream>>>(ps_src, ps_dst, sp_src, sp_dst,
                                                   cur_s, cur_p, sorted_ps, sorted_sp);

  // input projections
  proj_kernel<<<(NP+7)/8, 256, 0, stream>>>(x_pol, Wp, bp, P0, NP);
  proj_kernel<<<(NS+7)/8, 256, 0, stream>>>(x_stock, Wst, bst, S0, NS);

  // conv1
  agg_kernel<<<(NS+3)/4, 256, 0, stream>>>(P0, rowptr_s, sorted_ps, MS, NS);
  gemm_kernel<<<dim3(8,(NS+63)/64), 256, 0, stream>>>(MS, c1_ps_Wl, S0, c1_ps_Wr, c1_ps_bl, S1, NS, 1);
  agg_kernel<<<(NP+3)/4, 256, 0, stream>>>(S0, rowptr_p, sorted_sp, MP, NP);
  gemm_kernel<<<dim3(8,(NP+63)/64), 256, 0, stream>>>(MP, c1_sp_Wl, P0, c1_sp_Wr, c1_sp_bl, P1, NP, 1);

  // conv2
  agg_kernel<<<(NS+3)/4, 256, 0, stream>>>(P1, rowptr_s, sorted_ps, MS, NS);
  gemm_kernel<<<dim3(8,(NS+63)/64), 256, 0, stream>>>(MS, c2_ps_Wl, S1, c2_ps_Wr, c2_ps_bl, S0, NS, 1);
  agg_kernel<<<(NP+3)/4, 256, 0, stream>>>(S1, rowptr_p, sorted_sp, MP, NP);
  gemm_kernel<<<dim3(8,(NP+63)/64), 256, 0, stream>>>(MP, c2_sp_Wl, P1, c2_sp_Wr, c2_sp_bl, P0, NP, 1);

  // decoder precompute: Adec = hp2 @ d1W[0:512,:], Bdec = hs2 @ d1W[512:1024,:]
  gemm_kernel<<<dim3(8,(NP+63)/64), 256, 0, stream>>>(P0, d1W, nullptr, nullptr, nullptr, MP, NP, 0);
  gemm_kernel<<<dim3(8,(NS+63)/64), 256, 0, stream>>>(S0, d1W + (size_t)512*H, nullptr, nullptr, nullptr, MS, NS, 0);

  // per-edge decoder
  edge_kernel<<<1024, 256, 0, stream>>>(MP, MS, d1W, d1b, d2W, d2b, trow, tcol, attr, out);
}

// Round 2
// 725.733 us; speedup vs baseline: 2.3291x; 2.3291x over previous
//
#include <hip/hip_runtime.h>
#include <hip/hip_bf16.h>

typedef unsigned short u16;
typedef unsigned int u32;
typedef __attribute__((ext_vector_type(8))) short short8;
typedef __attribute__((ext_vector_type(4))) float f32x4;

#define NP 20000
#define NS 10000
#define NE 400000
#define H  512
#define FDIM 64

__device__ __forceinline__ float bl16(u32 w){ return __uint_as_float(w << 16); }
__device__ __forceinline__ float bh16(u32 w){ return __uint_as_float(w & 0xffff0000u); }
__device__ __forceinline__ u16 f2bf(float f){
  u32 u = __float_as_uint(f);
  u32 r = u + 0x7fffu + ((u >> 16) & 1u);
  return (u16)(r >> 16);
}
__device__ __forceinline__ u32 pack2(float a, float b){
  return (u32)f2bf(a) | ((u32)f2bf(b) << 16);
}
__device__ __forceinline__ void gload16(const void* g, void* l){
  __builtin_amdgcn_global_load_lds((const __attribute__((address_space(1))) u32*)g,
                                   (__attribute__((address_space(3))) u32*)l, 16, 0, 0);
}

// ---------------- input projection: Y = relu(X @ W + b), X [n,64] f32, W [64,512], Y bf16 ----------------
__global__ __launch_bounds__(256) void proj_kernel(const float* __restrict__ X, const float* __restrict__ W,
                                                   const float* __restrict__ b, u16* __restrict__ Y, int n)
{
  __shared__ float xs[8][FDIM];
  int tid = threadIdx.x;
  int m0 = blockIdx.x * 8;
  {
    int r = tid >> 6, c = tid & 63;
    int m = m0 + r;
    xs[r][c] = (m < n) ? X[(size_t)m*FDIM + c] : 0.f;
    m = m0 + r + 4;
    xs[r+4][c] = (m < n) ? X[(size_t)m*FDIM + c] : 0.f;
  }
  __syncthreads();
  float acc[8][2] = {};
  int c0 = tid, c1 = tid + 256;
  for (int k = 0; k < FDIM; ++k){
    float w0 = W[k*H + c0];
    float w1 = W[k*H + c1];
    #pragma unroll
    for (int r = 0; r < 8; ++r){
      float xv = xs[r][k];
      acc[r][0] = fmaf(xv, w0, acc[r][0]);
      acc[r][1] = fmaf(xv, w1, acc[r][1]);
    }
  }
  float b0 = b[c0], b1 = b[c1];
  #pragma unroll
  for (int r = 0; r < 8; ++r){
    int m = m0 + r;
    if (m < n){
      Y[(size_t)m*H + c0] = f2bf(fmaxf(acc[r][0] + b0, 0.f));
      Y[(size_t)m*H + c1] = f2bf(fmaxf(acc[r][1] + b1, 0.f));
    }
  }
}

// ---------------- weight convert+transpose: Wt[n][k] = bf16(W[k][n]), W [512][512] f32 ----------------
struct TPair { const float* src; u16* dst; };
struct TArgs { TPair m[10]; };

__global__ __launch_bounds__(256) void wtrans_kernel(TArgs args)
{
  __shared__ float lds[32][33];
  int mat = blockIdx.z;
  const float* __restrict__ src = args.m[mat].src;
  u16* __restrict__ dst = args.m[mat].dst;
  int k0 = blockIdx.y << 5, n0 = blockIdx.x << 5;
  int t = threadIdx.x;
  int r = t >> 3, c4 = (t & 7) << 2;
  float4 v = *(const float4*)(src + (size_t)(k0 + r)*H + n0 + c4);
  lds[r][c4+0] = v.x; lds[r][c4+1] = v.y; lds[r][c4+2] = v.z; lds[r][c4+3] = v.w;
  __syncthreads();
  uint2 o;
  o.x = pack2(lds[c4+0][r], lds[c4+1][r]);
  o.y = pack2(lds[c4+2][r], lds[c4+3][r]);
  *(uint2*)(dst + (size_t)(n0 + r)*H + k0 + c4) = o;
}

// ---------------- CSR build ----------------
__global__ void hist_kernel(const int* __restrict__ ps_dst, const int* __restrict__ sp_dst,
                            int* __restrict__ cnt_s, int* __restrict__ cnt_p)
{
  int e = blockIdx.x * blockDim.x + threadIdx.x;
  if (e < NE){
    atomicAdd(&cnt_s[ps_dst[e]], 1);
    atomicAdd(&cnt_p[sp_dst[e]], 1);
  }
}

__global__ __launch_bounds__(1024) void scan_kernel(const int* __restrict__ cnt, int n,
                                                    int* __restrict__ rowptr, int* __restrict__ cursor)
{
  __shared__ int lds[1024];
  __shared__ int carry_s;
  int tid = threadIdx.x;
  if (tid == 0) carry_s = 0;
  __syncthreads();
  for (int base = 0; base < n; base += 1024){
    int i = base + tid;
    int v = (i < n) ? cnt[i] : 0;
    lds[tid] = v;
    __syncthreads();
    for (int off = 1; off < 1024; off <<= 1){
      int t = (tid >= off) ? lds[tid - off] : 0;
      __syncthreads();
      lds[tid] += t;
      __syncthreads();
    }
    int incl = lds[tid];
    int cb = carry_s;
    if (i < n){
      rowptr[i] = cb + incl - v;
      cursor[i] = cb + incl - v;
    }
    __syncthreads();
    if (tid == 0) carry_s = cb + lds[1023];
    __syncthreads();
  }
  if (tid == 0) rowptr[n] = carry_s;
}

__global__ void scatter_kernel(const int* __restrict__ ps_src, const int* __restrict__ ps_dst,
                               const int* __restrict__ sp_src, const int* __restrict__ sp_dst,
                               int* __restrict__ cur_s, int* __restrict__ cur_p,
                               int* __restrict__ sorted_ps, int* __restrict__ sorted_sp)
{
  int e = blockIdx.x * blockDim.x + threadIdx.x;
  if (e < NE){
    int pos = atomicAdd(&cur_s[ps_dst[e]], 1);
    sorted_ps[pos] = ps_src[e];
    int pos2 = atomicAdd(&cur_p[sp_dst[e]], 1);
    sorted_sp[pos2] = sp_src[e];
  }
}

// ---------------- mean aggregation: one wave per dst row, 2-edge unroll for MLP ----------------
__global__ __launch_bounds__(256) void agg_kernel(const u16* __restrict__ X, const int* __restrict__ rowptr,
                                                  const int* __restrict__ srcs, u16* __restrict__ M, int n_dst)
{
  int wid = (blockIdx.x << 2) + (threadIdx.x >> 6);
  int lane = threadIdx.x & 63;
  if (wid >= n_dst) return;
  int beg = rowptr[wid], end = rowptr[wid + 1];
  float acc[8] = {0,0,0,0,0,0,0,0};
  int i = beg;
  for (; i + 2 <= end; i += 2){
    int s0 = srcs[i], s1 = srcs[i+1];
    uint4 v0 = *(const uint4*)(X + (size_t)s0*H + (lane << 3));
    uint4 v1 = *(const uint4*)(X + (size_t)s1*H + (lane << 3));
    acc[0] += bl16(v0.x); acc[1] += bh16(v0.x);
    acc[2] += bl16(v0.y); acc[3] += bh16(v0.y);
    acc[4] += bl16(v0.z); acc[5] += bh16(v0.z);
    acc[6] += bl16(v0.w); acc[7] += bh16(v0.w);
    acc[0] += bl16(v1.x); acc[1] += bh16(v1.x);
    acc[2] += bl16(v1.y); acc[3] += bh16(v1.y);
    acc[4] += bl16(v1.z); acc[5] += bh16(v1.z);
    acc[6] += bl16(v1.w); acc[7] += bh16(v1.w);
  }
  if (i < end){
    int s0 = srcs[i];
    uint4 v0 = *(const uint4*)(X + (size_t)s0*H + (lane << 3));
    acc[0] += bl16(v0.x); acc[1] += bh16(v0.x);
    acc[2] += bl16(v0.y); acc[3] += bh16(v0.y);
    acc[4] += bl16(v0.z); acc[5] += bh16(v0.z);
    acc[6] += bl16(v0.w); acc[7] += bh16(v0.w);
  }
  float inv = 1.f / (float)max(end - beg, 1);
  uint4 o;
  o.x = pack2(acc[0]*inv, acc[1]*inv);
  o.y = pack2(acc[2]*inv, acc[3]*inv);
  o.z = pack2(acc[4]*inv, acc[5]*inv);
  o.w = pack2(acc[6]*inv, acc[7]*inv);
  *(uint4*)(M + (size_t)wid*H + (lane << 3)) = o;
}

// ---------------- MFMA GEMM: C = act(A1@W1t^T [+ A2@W2t^T] [+ bias]) ----------------
// A [n,512] bf16 row-major; Wt [512][512] bf16 with Wt[n][k] = W[k][n].
// 128x128 tile, 4 waves (2x2), each wave 64x64 = 4x4 frags of 16x16x32 MFMA, BK=64.
// Staging: global_load_lds w16, linear LDS dest, XOR-swizzled (chunk^row&7) source;
// reads apply the same swizzle -> 16B-slot spread across 8 rows (G4 recipe).
__global__ __launch_bounds__(256) void gemm_mfma(
    const u16* __restrict__ A1, const u16* __restrict__ W1t,
    const u16* __restrict__ A2, const u16* __restrict__ W2t,
    const float* __restrict__ bias, u16* __restrict__ C, int nrows, int do_relu)
{
  __shared__ u16 As[128*64];
  __shared__ u16 Bs[128*64];
  char* AsB = (char*)As;
  char* BsB = (char*)Bs;
  int t = threadIdx.x;
  int w = t >> 6, l = t & 63;
  int wr = w >> 1, wc = w & 1;
  int lr = l & 15, lg = l >> 4;
  int m0 = blockIdx.y << 7, n0 = blockIdx.x << 7;

  f32x4 acc[4][4];
  #pragma unroll
  for (int i = 0; i < 4; ++i)
    #pragma unroll
    for (int j = 0; j < 4; ++j)
      acc[i][j] = (f32x4){0.f, 0.f, 0.f, 0.f};

  for (int phase = 0; phase < 2; ++phase){
    const u16* Ap = phase ? A2 : A1;
    const u16* Wp = phase ? W2t : W1t;
    if (!Ap) break;
    for (int k0 = 0; k0 < H; k0 += 64){
      // stage A-tile [128][64] and B-tile [128][64] (16 KB each)
      #pragma unroll
      for (int i = 0; i < 4; ++i){
        int c = i*256 + t;           // 16B chunk index, linear LDS position
        int row = c >> 3, p = c & 7;
        int k8 = p ^ (row & 7);      // inverse-swizzled global chunk
        gload16(Ap + (size_t)(m0 + row)*H + k0 + k8*8, AsB + c*16);
        gload16(Wp + (size_t)(n0 + row)*H + k0 + k8*8, BsB + c*16);
      }
      __syncthreads();               // compiler drains vmcnt(0) here
      #pragma unroll
      for (int ks = 0; ks < 2; ++ks){
        short8 a[4], b[4];
        int kc = (ks << 2) + lg;
        #pragma unroll
        for (int mi = 0; mi < 4; ++mi){
          int r = (wr << 6) + (mi << 4) + lr;
          a[mi] = *(const short8*)(AsB + r*128 + ((kc ^ (r & 7)) << 4));
        }
        #pragma unroll
        for (int ni = 0; ni < 4; ++ni){
          int r = (wc << 6) + (ni << 4) + lr;
          b[ni] = *(const short8*)(BsB + r*128 + ((kc ^ (r & 7)) << 4));
        }
        #pragma unroll
        for (int mi = 0; mi < 4; ++mi)
          #pragma unroll
          for (int ni = 0; ni < 4; ++ni)
            acc[mi][ni] = __builtin_amdgcn_mfma_f32_16x16x32_bf16(a[mi], b[ni], acc[mi][ni], 0, 0, 0);
      }
      __syncthreads();               // LDS reads done before next-step overwrite
    }
  }

  // epilogue: C/D layout row=(l>>4)*4+j, col=l&15
  float bv[4];
  #pragma unroll
  for (int ni = 0; ni < 4; ++ni)
    bv[ni] = bias ? bias[n0 + (wc << 6) + (ni << 4) + lr] : 0.f;
  #pragma unroll
  for (int mi = 0; mi < 4; ++mi){
    #pragma unroll
    for (int j = 0; j < 4; ++j){
      int m = m0 + (wr << 6) + (mi << 4) + (lg << 2) + j;
      if (m < nrows){
        #pragma unroll
        for (int ni = 0; ni < 4; ++ni){
          float v = acc[mi][ni][j] + bv[ni];
          if (do_relu) v = fmaxf(v, 0.f);
          C[(size_t)m*H + n0 + (wc << 6) + (ni << 4) + lr] = f2bf(v);
        }
      }
    }
  }
}

// ---------------- edge decoder: one wave per edge ----------------
__global__ __launch_bounds__(256) void edge_kernel(
    const u16* __restrict__ Adec, const u16* __restrict__ Bdec,
    const float* __restrict__ d1W, const float* __restrict__ d1b,
    const float* __restrict__ d2W, const float* __restrict__ d2b,
    const int* __restrict__ row, const int* __restrict__ col,
    const float* __restrict__ attr, float* __restrict__ out)
{
  int lane = threadIdx.x & 63;
  int wid = (blockIdx.x << 2) + (threadIdx.x >> 6);
  int nw = gridDim.x << 2;
  int j0 = lane << 3;
  float w1a[8], w1b[8], bb[8], w2[8][3];
  #pragma unroll
  for (int q = 0; q < 8; ++q){
    w1a[q] = d1W[(size_t)1024*H + j0 + q];
    w1b[q] = d1W[(size_t)1025*H + j0 + q];
    bb[q]  = d1b[j0 + q];
    w2[q][0] = d2W[(j0+q)*3 + 0];
    w2[q][1] = d2W[(j0+q)*3 + 1];
    w2[q][2] = d2W[(j0+q)*3 + 2];
  }
  float ob0 = d2b[0], ob1 = d2b[1], ob2 = d2b[2];
  for (int e = wid; e < NE; e += nw){
    int r = row[e], c = col[e];
    float a0 = attr[2*e], a1 = attr[2*e+1];
    uint4 va = *(const uint4*)(Adec + (size_t)r*H + j0);
    uint4 vb = *(const uint4*)(Bdec + (size_t)c*H + j0);
    float fa[8] = {bl16(va.x),bh16(va.x),bl16(va.y),bh16(va.y),bl16(va.z),bh16(va.z),bl16(va.w),bh16(va.w)};
    float fb[8] = {bl16(vb.x),bh16(vb.x),bl16(vb.y),bh16(vb.y),bl16(vb.z),bh16(vb.z),bl16(vb.w),bh16(vb.w)};
    float s0 = 0.f, s1 = 0.f, s2 = 0.f;
    #pragma unroll
    for (int q = 0; q < 8; ++q){
      float h = fa[q] + fb[q] + bb[q];
      h = fmaf(a0, w1a[q], h);
      h = fmaf(a1, w1b[q], h);
      h = fmaxf(h, 0.f);
      s0 = fmaf(h, w2[q][0], s0);
      s1 = fmaf(h, w2[q][1], s1);
      s2 = fmaf(h, w2[q][2], s2);
    }
    #pragma unroll
    for (int off = 32; off > 0; off >>= 1){
      s0 += __shfl_xor(s0, off);
      s1 += __shfl_xor(s1, off);
      s2 += __shfl_xor(s2, off);
    }
    if (lane == 0){
      out[(size_t)e*3 + 0] = s0 + ob0;
      out[(size_t)e*3 + 1] = s1 + ob1;
      out[(size_t)e*3 + 2] = s2 + ob2;
    }
  }
}

extern "C" void kernel_launch(void* const* d_in, const int* in_sizes, int n_in,
                              void* d_out, int out_size, void* d_ws, size_t ws_size,
                              hipStream_t stream)
{
  const float* x_pol    = (const float*)d_in[0];
  const float* x_stock  = (const float*)d_in[1];
  const float* attr     = (const float*)d_in[2];
  const float* Wp       = (const float*)d_in[3];
  const float* bp       = (const float*)d_in[4];
  const float* Wst      = (const float*)d_in[5];
  const float* bst      = (const float*)d_in[6];
  const float* c1_ps_Wl = (const float*)d_in[7];
  const float* c1_ps_bl = (const float*)d_in[8];
  const float* c1_ps_Wr = (const float*)d_in[9];
  const float* c1_sp_Wl = (const float*)d_in[10];
  const float* c1_sp_bl = (const float*)d_in[11];
  const float* c1_sp_Wr = (const float*)d_in[12];
  const float* c2_ps_Wl = (const float*)d_in[13];
  const float* c2_ps_bl = (const float*)d_in[14];
  const float* c2_ps_Wr = (const float*)d_in[15];
  const float* c2_sp_Wl = (const float*)d_in[16];
  const float* c2_sp_bl = (const float*)d_in[17];
  const float* c2_sp_Wr = (const float*)d_in[18];
  const float* d1W      = (const float*)d_in[19];
  const float* d1b      = (const float*)d_in[20];
  const float* d2W      = (const float*)d_in[21];
  const float* d2b      = (const float*)d_in[22];
  const int* ps_src     = (const int*)d_in[23];
  const int* ps_dst     = (const int*)d_in[24];
  const int* sp_src     = (const int*)d_in[25];
  const int* sp_dst     = (const int*)d_in[26];
  const int* trow       = (const int*)d_in[27];
  const int* tcol       = (const int*)d_in[28];
  float* out = (float*)d_out;

  char* ws = (char*)d_ws;
  size_t off = 0;
  auto alloc = [&](size_t bytes)->char*{
    char* p = ws + off;
    off += (bytes + 255) & ~(size_t)255;
    return p;
  };
  u16* P0 = (u16*)alloc((size_t)NP*H*2);   // hp -> hp2
  u16* P1 = (u16*)alloc((size_t)NP*H*2);   // hp1
  u16* S0 = (u16*)alloc((size_t)NS*H*2);   // hs -> hs2
  u16* S1 = (u16*)alloc((size_t)NS*H*2);   // hs1
  u16* MP = (u16*)alloc((size_t)NP*H*2);   // mean into pol / Adec
  u16* MS = (u16*)alloc((size_t)NS*H*2);   // mean into stock / Bdec
  u16* Wt[10];
  for (int i = 0; i < 10; ++i) Wt[i] = (u16*)alloc((size_t)H*H*2);
  int* cnt_s    = (int*)alloc((size_t)NS*4);
  int* cnt_p    = (int*)alloc((size_t)NP*4);
  int* rowptr_s = (int*)alloc((size_t)(NS+1)*4);
  int* rowptr_p = (int*)alloc((size_t)(NP+1)*4);
  int* cur_s    = (int*)alloc((size_t)NS*4);
  int* cur_p    = (int*)alloc((size_t)NP*4);
  int* sorted_ps = (int*)alloc((size_t)NE*4);
  int* sorted_sp = (int*)alloc((size_t)NE*4);
  // pad region so GEMM tile-tail staging reads past last matrix stay in-bounds
  alloc((size_t)128*H*2);

  // weight convert+transpose (independent of everything else)
  TArgs ta;
  ta.m[0] = {c1_ps_Wl, Wt[0]}; ta.m[1] = {c1_ps_Wr, Wt[1]};
  ta.m[2] = {c1_sp_Wl, Wt[2]}; ta.m[3] = {c1_sp_Wr, Wt[3]};
  ta.m[4] = {c2_ps_Wl, Wt[4]}; ta.m[5] = {c2_ps_Wr, Wt[5]};
  ta.m[6] = {c2_sp_Wl, Wt[6]}; ta.m[7] = {c2_sp_Wr, Wt[7]};
  ta.m[8] = {d1W, Wt[8]};                      // rows 0..511   (pol part)
  ta.m[9] = {d1W + (size_t)512*H, Wt[9]};      // rows 512..1023 (stock part)
  wtrans_kernel<<<dim3(16,16,10), 256, 0, stream>>>(ta);

  // CSR build (shared by conv1 and conv2)
  hipMemsetAsync(cnt_s, 0, (size_t)NS*4, stream);
  hipMemsetAsync(cnt_p, 0, (size_t)NP*4, stream);
  hist_kernel<<<(NE+255)/256, 256, 0, stream>>>(ps_dst, sp_dst, cnt_s, cnt_p);
  scan_kernel<<<1, 1024, 0, stream>>>(cnt_s, NS, rowptr_s, cur_s);
  scan_kernel<<<1, 1024, 0, stream>>>(cnt_p, NP, rowptr_p, cur_p);
  scatter_kernel<<<(NE+255)/256, 256, 0, stream>>>(ps_src, ps_dst, sp_src, sp_dst,
                                                   cur_s, cur_p, sorted_ps, sorted_sp);

  // input projections
  proj_kernel<<<(NP+7)/8, 256, 0, stream>>>(x_pol, Wp, bp, P0, NP);
  proj_kernel<<<(NS+7)/8, 256, 0, stream>>>(x_stock, Wst, bst, S0, NS);

  // conv1
  agg_kernel<<<(NS+3)/4, 256, 0, stream>>>(P0, rowptr_s, sorted_ps, MS, NS);
  gemm_mfma<<<dim3(4,(NS+127)/128), 256, 0, stream>>>(MS, Wt[0], S0, Wt[1], c1_ps_bl, S1, NS, 1);
  agg_kernel<<<(NP+3)/4, 256, 0, stream>>>(S0, rowptr_p, sorted_sp, MP, NP);
  gemm_mfma<<<dim3(4,(NP+127)/128), 256, 0, stream>>>(MP, Wt[2], P0, Wt[3], c1_sp_bl, P1, NP, 1);

  // conv2
  agg_kernel<<<(NS+3)/4, 256, 0, stream>>>(P1, rowptr_s, sorted_ps, MS, NS);
  gemm_mfma<<<dim3(4,(NS+127)/128), 256, 0, stream>>>(MS, Wt[4], S1, Wt[5], c2_ps_bl, S0, NS, 1);
  agg_kernel<<<(NP+3)/4, 256, 0, stream>>>(S1, rowptr_p, sorted_sp, MP, NP);
  gemm_mfma<<<dim3(4,(NP+127)/128), 256, 0, stream>>>(MP, Wt[6], P1, Wt[7], c2_sp_bl, P0, NP, 1);

  // decoder precompute: Adec = hp2 @ d1W[0:512,:], Bdec = hs2 @ d1W[512:1024,:]
  gemm_mfma<<<dim3(4,(NP+127)/128), 256, 0, stream>>>(P0, Wt[8], nullptr, nullptr, nullptr, MP, NP, 0);
  gemm_mfma<<<dim3(4,(NS+127)/128), 256, 0, stream>>>(S0, Wt[9], nullptr, nullptr, nullptr, MS, NS, 0);

  // per-edge decoder
  edge_kernel<<<1024, 256, 0, stream>>>(MP, MS, d1W, d1b, d2W, d2b, trow, tcol, attr, out);
}

// Round 3
// 692.316 us; speedup vs baseline: 2.4416x; 1.0483x over previous
//
#include <hip/hip_runtime.h>
#include <hip/hip_bf16.h>

typedef unsigned short u16;
typedef unsigned int u32;
typedef __attribute__((ext_vector_type(8))) short short8;
typedef __attribute__((ext_vector_type(4))) float f32x4;

#define NP 20000
#define NS 10000
#define NE 400000
#define H  512
#define FDIM 64

__device__ __forceinline__ float bl16(u32 w){ return __uint_as_float(w << 16); }
__device__ __forceinline__ float bh16(u32 w){ return __uint_as_float(w & 0xffff0000u); }
__device__ __forceinline__ u16 f2bf(float f){
  u32 u = __float_as_uint(f);
  u32 r = u + 0x7fffu + ((u >> 16) & 1u);
  return (u16)(r >> 16);
}
__device__ __forceinline__ u32 pack2(float a, float b){
  return (u32)f2bf(a) | ((u32)f2bf(b) << 16);
}
__device__ __forceinline__ void gload16(const void* g, void* l){
  __builtin_amdgcn_global_load_lds((const __attribute__((address_space(1))) u32*)g,
                                   (__attribute__((address_space(3))) u32*)l, 16, 0, 0);
}

// ---------------- input projection: Y = relu(X @ W + b), X [n,64] f32, W [64,512], Y bf16 ----------------
__global__ __launch_bounds__(256) void proj_kernel(const float* __restrict__ X, const float* __restrict__ W,
                                                   const float* __restrict__ b, u16* __restrict__ Y, int n)
{
  __shared__ float xs[8][FDIM];
  int tid = threadIdx.x;
  int m0 = blockIdx.x * 8;
  {
    int r = tid >> 6, c = tid & 63;
    int m = m0 + r;
    xs[r][c] = (m < n) ? X[(size_t)m*FDIM + c] : 0.f;
    m = m0 + r + 4;
    xs[r+4][c] = (m < n) ? X[(size_t)m*FDIM + c] : 0.f;
  }
  __syncthreads();
  float acc[8][2] = {};
  int c0 = tid, c1 = tid + 256;
  for (int k = 0; k < FDIM; ++k){
    float w0 = W[k*H + c0];
    float w1 = W[k*H + c1];
    #pragma unroll
    for (int r = 0; r < 8; ++r){
      float xv = xs[r][k];
      acc[r][0] = fmaf(xv, w0, acc[r][0]);
      acc[r][1] = fmaf(xv, w1, acc[r][1]);
    }
  }
  float b0 = b[c0], b1 = b[c1];
  #pragma unroll
  for (int r = 0; r < 8; ++r){
    int m = m0 + r;
    if (m < n){
      Y[(size_t)m*H + c0] = f2bf(fmaxf(acc[r][0] + b0, 0.f));
      Y[(size_t)m*H + c1] = f2bf(fmaxf(acc[r][1] + b1, 0.f));
    }
  }
}

// ---------------- weight convert+transpose: Wt[n][k] = bf16(W[k][n]), W [512][512] f32 ----------------
struct TPair { const float* src; u16* dst; };
struct TArgs { TPair m[10]; };

__global__ __launch_bounds__(256) void wtrans_kernel(TArgs args)
{
  __shared__ float lds[32][33];
  int mat = blockIdx.z;
  const float* __restrict__ src = args.m[mat].src;
  u16* __restrict__ dst = args.m[mat].dst;
  int k0 = blockIdx.y << 5, n0 = blockIdx.x << 5;
  int t = threadIdx.x;
  int r = t >> 3, c4 = (t & 7) << 2;
  float4 v = *(const float4*)(src + (size_t)(k0 + r)*H + n0 + c4);
  lds[r][c4+0] = v.x; lds[r][c4+1] = v.y; lds[r][c4+2] = v.z; lds[r][c4+3] = v.w;
  __syncthreads();
  uint2 o;
  o.x = pack2(lds[c4+0][r], lds[c4+1][r]);
  o.y = pack2(lds[c4+2][r], lds[c4+3][r]);
  *(uint2*)(dst + (size_t)(n0 + r)*H + k0 + c4) = o;
}

// ---------------- CSR build (3 relations: ps->s, sp->p, trade->p) ----------------
__global__ void hist_kernel(const int* __restrict__ ps_dst, const int* __restrict__ sp_dst,
                            const int* __restrict__ trow,
                            int* __restrict__ cnt_s, int* __restrict__ cnt_p, int* __restrict__ cnt_t)
{
  int e = blockIdx.x * blockDim.x + threadIdx.x;
  if (e < NE){
    atomicAdd(&cnt_s[ps_dst[e]], 1);
    atomicAdd(&cnt_p[sp_dst[e]], 1);
    atomicAdd(&cnt_t[trow[e]], 1);
  }
}

// in-place exclusive scan: writes rowptr[0..n] and overwrites cnt[i] with the
// exclusive prefix (used as scatter cursor). One block per array.
__device__ void scan_one(int* cnt, int n, int* rowptr)
{
  __shared__ int lds[1024];
  __shared__ int carry_s;
  int tid = threadIdx.x;
  if (tid == 0) carry_s = 0;
  __syncthreads();
  for (int base = 0; base < n; base += 1024){
    int i = base + tid;
    int v = (i < n) ? cnt[i] : 0;
    lds[tid] = v;
    __syncthreads();
    for (int off = 1; off < 1024; off <<= 1){
      int t = (tid >= off) ? lds[tid - off] : 0;
      __syncthreads();
      lds[tid] += t;
      __syncthreads();
    }
    int incl = lds[tid];
    int cb = carry_s;
    if (i < n){
      rowptr[i] = cb + incl - v;
      cnt[i] = cb + incl - v;
    }
    __syncthreads();
    if (tid == 0) carry_s = cb + lds[1023];
    __syncthreads();
  }
  if (tid == 0) rowptr[n] = carry_s;
}

__global__ __launch_bounds__(1024) void scan3_kernel(int* c0, int n0, int* r0,
                                                     int* c1, int n1, int* r1,
                                                     int* c2, int n2, int* r2)
{
  if (blockIdx.x == 0) scan_one(c0, n0, r0);
  else if (blockIdx.x == 1) scan_one(c1, n1, r1);
  else scan_one(c2, n2, r2);
}

__global__ void scatter_kernel(const int* __restrict__ ps_src, const int* __restrict__ ps_dst,
                               const int* __restrict__ sp_src, const int* __restrict__ sp_dst,
                               const int* __restrict__ trow,
                               int* __restrict__ cur_s, int* __restrict__ cur_p, int* __restrict__ cur_t,
                               int* __restrict__ sorted_ps, int* __restrict__ sorted_sp,
                               int* __restrict__ sorted_te)
{
  int e = blockIdx.x * blockDim.x + threadIdx.x;
  if (e < NE){
    int pos = atomicAdd(&cur_s[ps_dst[e]], 1);
    sorted_ps[pos] = ps_src[e];
    int pos2 = atomicAdd(&cur_p[sp_dst[e]], 1);
    sorted_sp[pos2] = sp_src[e];
    int pos3 = atomicAdd(&cur_t[trow[e]], 1);
    sorted_te[pos3] = e;
  }
}

// ---------------- paired mean aggregation: one wave per dst row, both relations in one launch ----------------
__global__ __launch_bounds__(256) void agg2_kernel(
    const u16* __restrict__ X0, const int* __restrict__ rp0, const int* __restrict__ s0,
    u16* __restrict__ M0, int n0,
    const u16* __restrict__ X1, const int* __restrict__ rp1, const int* __restrict__ s1,
    u16* __restrict__ M1, int n1)
{
  int wid = (blockIdx.x << 2) + (threadIdx.x >> 6);
  int lane = threadIdx.x & 63;
  const u16* X; const int* rp; const int* ss; u16* M; int row;
  if (wid < n0){ X = X0; rp = rp0; ss = s0; M = M0; row = wid; }
  else if (wid < n0 + n1){ X = X1; rp = rp1; ss = s1; M = M1; row = wid - n0; }
  else return;
  int beg = rp[row], end = rp[row + 1];
  float acc[8] = {0,0,0,0,0,0,0,0};
  int i = beg;
  for (; i + 2 <= end; i += 2){
    int sa = ss[i], sb = ss[i+1];
    uint4 v0 = *(const uint4*)(X + (size_t)sa*H + (lane << 3));
    uint4 v1 = *(const uint4*)(X + (size_t)sb*H + (lane << 3));
    acc[0] += bl16(v0.x); acc[1] += bh16(v0.x);
    acc[2] += bl16(v0.y); acc[3] += bh16(v0.y);
    acc[4] += bl16(v0.z); acc[5] += bh16(v0.z);
    acc[6] += bl16(v0.w); acc[7] += bh16(v0.w);
    acc[0] += bl16(v1.x); acc[1] += bh16(v1.x);
    acc[2] += bl16(v1.y); acc[3] += bh16(v1.y);
    acc[4] += bl16(v1.z); acc[5] += bh16(v1.z);
    acc[6] += bl16(v1.w); acc[7] += bh16(v1.w);
  }
  if (i < end){
    int sa = ss[i];
    uint4 v0 = *(const uint4*)(X + (size_t)sa*H + (lane << 3));
    acc[0] += bl16(v0.x); acc[1] += bh16(v0.x);
    acc[2] += bl16(v0.y); acc[3] += bh16(v0.y);
    acc[4] += bl16(v0.z); acc[5] += bh16(v0.z);
    acc[6] += bl16(v0.w); acc[7] += bh16(v0.w);
  }
  float inv = 1.f / (float)max(end - beg, 1);
  uint4 o;
  o.x = pack2(acc[0]*inv, acc[1]*inv);
  o.y = pack2(acc[2]*inv, acc[3]*inv);
  o.z = pack2(acc[4]*inv, acc[5]*inv);
  o.w = pack2(acc[6]*inv, acc[7]*inv);
  *(uint4*)(M + (size_t)row*H + (lane << 3)) = o;
}

// ---------------- MFMA GEMM pair: two independent problems per launch (blockIdx.z) ----------------
// C = act(A1@W1t^T [+ A2@W2t^T] [+ bias]); Wt[n][k] = bf16(W[k][n]).
// 128x128 tile, 4 waves (2x2), each wave 64x64 = 4x4 frags of 16x16x32 MFMA, BK=64.
struct GemmProb {
  const u16* A1; const u16* W1t; const u16* A2; const u16* W2t;
  const float* bias; u16* C; int nrows; int relu;
};

__global__ __launch_bounds__(256) void gemm_mfma2(GemmProb Pa, GemmProb Pb)
{
  GemmProb P = blockIdx.z ? Pb : Pa;
  int m0 = blockIdx.y << 7, n0 = blockIdx.x << 7;
  if (m0 >= P.nrows) return;

  __shared__ u16 As[128*64];
  __shared__ u16 Bs[128*64];
  char* AsB = (char*)As;
  char* BsB = (char*)Bs;
  int t = threadIdx.x;
  int w = t >> 6, l = t & 63;
  int wr = w >> 1, wc = w & 1;
  int lr = l & 15, lg = l >> 4;

  f32x4 acc[4][4];
  #pragma unroll
  for (int i = 0; i < 4; ++i)
    #pragma unroll
    for (int j = 0; j < 4; ++j)
      acc[i][j] = (f32x4){0.f, 0.f, 0.f, 0.f};

  for (int phase = 0; phase < 2; ++phase){
    const u16* Ap = phase ? P.A2 : P.A1;
    const u16* Wp = phase ? P.W2t : P.W1t;
    if (!Ap) break;
    for (int k0 = 0; k0 < H; k0 += 64){
      #pragma unroll
      for (int i = 0; i < 4; ++i){
        int c = i*256 + t;           // 16B chunk index, linear LDS position
        int row = c >> 3, p = c & 7;
        int k8 = p ^ (row & 7);      // inverse-swizzled global chunk
        gload16(Ap + (size_t)(m0 + row)*H + k0 + k8*8, AsB + c*16);
        gload16(Wp + (size_t)(n0 + row)*H + k0 + k8*8, BsB + c*16);
      }
      __syncthreads();
      #pragma unroll
      for (int ks = 0; ks < 2; ++ks){
        short8 a[4], b[4];
        int kc = (ks << 2) + lg;
        #pragma unroll
        for (int mi = 0; mi < 4; ++mi){
          int r = (wr << 6) + (mi << 4) + lr;
          a[mi] = *(const short8*)(AsB + r*128 + ((kc ^ (r & 7)) << 4));
        }
        #pragma unroll
        for (int ni = 0; ni < 4; ++ni){
          int r = (wc << 6) + (ni << 4) + lr;
          b[ni] = *(const short8*)(BsB + r*128 + ((kc ^ (r & 7)) << 4));
        }
        #pragma unroll
        for (int mi = 0; mi < 4; ++mi)
          #pragma unroll
          for (int ni = 0; ni < 4; ++ni)
            acc[mi][ni] = __builtin_amdgcn_mfma_f32_16x16x32_bf16(a[mi], b[ni], acc[mi][ni], 0, 0, 0);
      }
      __syncthreads();
    }
  }

  float bv[4];
  #pragma unroll
  for (int ni = 0; ni < 4; ++ni)
    bv[ni] = P.bias ? P.bias[n0 + (wc << 6) + (ni << 4) + lr] : 0.f;
  #pragma unroll
  for (int mi = 0; mi < 4; ++mi){
    #pragma unroll
    for (int j = 0; j < 4; ++j){
      int m = m0 + (wr << 6) + (mi << 4) + (lg << 2) + j;
      if (m < P.nrows){
        #pragma unroll
        for (int ni = 0; ni < 4; ++ni){
          float v = acc[mi][ni][j] + bv[ni];
          if (P.relu) v = fmaxf(v, 0.f);
          P.C[(size_t)m*H + n0 + (wc << 6) + (ni << 4) + lr] = f2bf(v);
        }
      }
    }
  }
}

// ---------------- edge decoder, row-CSR: one wave per politician row ----------------
// A-row loaded once to registers; loop gathers only B[col] (+attr), prefetched 1 deep.
__global__ __launch_bounds__(256) void edge_row_kernel(
    const u16* __restrict__ Adec, const u16* __restrict__ Bdec,
    const float* __restrict__ d1W, const float* __restrict__ d1b,
    const float* __restrict__ d2W, const float* __restrict__ d2b,
    const int* __restrict__ rowptr_t, const int* __restrict__ sorted_te,
    const int* __restrict__ tcol, const float* __restrict__ attr,
    float* __restrict__ out)
{
  int lane = threadIdx.x & 63;
  int p = (blockIdx.x << 2) + (threadIdx.x >> 6);
  if (p >= NP) return;
  int beg = rowptr_t[p], end = rowptr_t[p + 1];
  if (beg == end) return;
  int j0 = lane << 3;

  float w1a[8], w1b[8], bb[8], w2[8][3];
  #pragma unroll
  for (int q = 0; q < 8; ++q){
    w1a[q] = d1W[(size_t)1024*H + j0 + q];
    w1b[q] = d1W[(size_t)1025*H + j0 + q];
    bb[q]  = d1b[j0 + q];
    w2[q][0] = d2W[(j0+q)*3 + 0];
    w2[q][1] = d2W[(j0+q)*3 + 1];
    w2[q][2] = d2W[(j0+q)*3 + 2];
  }
  float ob0 = d2b[0], ob1 = d2b[1], ob2 = d2b[2];

  uint4 va = *(const uint4*)(Adec + (size_t)p*H + j0);
  float fa[8] = {bl16(va.x),bh16(va.x),bl16(va.y),bh16(va.y),
                 bl16(va.z),bh16(va.z),bl16(va.w),bh16(va.w)};
  #pragma unroll
  for (int q = 0; q < 8; ++q) fa[q] += bb[q];   // fold bias into A-row once

  // prefetch pipeline (1 deep)
  int e = sorted_te[beg];
  float a0 = attr[2*e], a1 = attr[2*e+1];
  uint4 vb = *(const uint4*)(Bdec + (size_t)tcol[e]*H + j0);

  for (int i = beg; i < end; ++i){
    int e_c = e; float a0c = a0, a1c = a1; uint4 vbc = vb;
    if (i + 1 < end){
      e = sorted_te[i+1];
      a0 = attr[2*e]; a1 = attr[2*e+1];
      vb = *(const uint4*)(Bdec + (size_t)tcol[e]*H + j0);
    }
    float fb[8] = {bl16(vbc.x),bh16(vbc.x),bl16(vbc.y),bh16(vbc.y),
                   bl16(vbc.z),bh16(vbc.z),bl16(vbc.w),bh16(vbc.w)};
    float s0 = 0.f, s1 = 0.f, s2 = 0.f;
    #pragma unroll
    for (int q = 0; q < 8; ++q){
      float h = fa[q] + fb[q];
      h = fmaf(a0c, w1a[q], h);
      h = fmaf(a1c, w1b[q], h);
      h = fmaxf(h, 0.f);
      s0 = fmaf(h, w2[q][0], s0);
      s1 = fmaf(h, w2[q][1], s1);
      s2 = fmaf(h, w2[q][2], s2);
    }
    #pragma unroll
    for (int off = 32; off > 0; off >>= 1){
      s0 += __shfl_xor(s0, off);
      s1 += __shfl_xor(s1, off);
      s2 += __shfl_xor(s2, off);
    }
    if (lane == 0){
      out[(size_t)e_c*3 + 0] = s0 + ob0;
      out[(size_t)e_c*3 + 1] = s1 + ob1;
      out[(size_t)e_c*3 + 2] = s2 + ob2;
    }
  }
}

extern "C" void kernel_launch(void* const* d_in, const int* in_sizes, int n_in,
                              void* d_out, int out_size, void* d_ws, size_t ws_size,
                              hipStream_t stream)
{
  const float* x_pol    = (const float*)d_in[0];
  const float* x_stock  = (const float*)d_in[1];
  const float* attr     = (const float*)d_in[2];
  const float* Wp       = (const float*)d_in[3];
  const float* bp       = (const float*)d_in[4];
  const float* Wst      = (const float*)d_in[5];
  const float* bst      = (const float*)d_in[6];
  const float* c1_ps_Wl = (const float*)d_in[7];
  const float* c1_ps_bl = (const float*)d_in[8];
  const float* c1_ps_Wr = (const float*)d_in[9];
  const float* c1_sp_Wl = (const float*)d_in[10];
  const float* c1_sp_bl = (const float*)d_in[11];
  const float* c1_sp_Wr = (const float*)d_in[12];
  const float* c2_ps_Wl = (const float*)d_in[13];
  const float* c2_ps_bl = (const float*)d_in[14];
  const float* c2_ps_Wr = (const float*)d_in[15];
  const float* c2_sp_Wl = (const float*)d_in[16];
  const float* c2_sp_bl = (const float*)d_in[17];
  const float* c2_sp_Wr = (const float*)d_in[18];
  const float* d1W      = (const float*)d_in[19];
  const float* d1b      = (const float*)d_in[20];
  const float* d2W      = (const float*)d_in[21];
  const float* d2b      = (const float*)d_in[22];
  const int* ps_src     = (const int*)d_in[23];
  const int* ps_dst     = (const int*)d_in[24];
  const int* sp_src     = (const int*)d_in[25];
  const int* sp_dst     = (const int*)d_in[26];
  const int* trow       = (const int*)d_in[27];
  const int* tcol       = (const int*)d_in[28];
  float* out = (float*)d_out;

  char* ws = (char*)d_ws;
  size_t off = 0;
  auto alloc = [&](size_t bytes)->char*{
    char* p = ws + off;
    off += (bytes + 255) & ~(size_t)255;
    return p;
  };
  u16* P0 = (u16*)alloc((size_t)NP*H*2);   // hp -> hp2
  u16* P1 = (u16*)alloc((size_t)NP*H*2);   // hp1
  u16* S0 = (u16*)alloc((size_t)NS*H*2);   // hs -> hs2
  u16* S1 = (u16*)alloc((size_t)NS*H*2);   // hs1
  u16* MP = (u16*)alloc((size_t)NP*H*2);   // mean into pol / Adec
  u16* MS = (u16*)alloc((size_t)NS*H*2);   // mean into stock / Bdec
  u16* Wt[10];
  for (int i = 0; i < 10; ++i) Wt[i] = (u16*)alloc((size_t)H*H*2);
  int* cnt_s    = (int*)alloc((size_t)NS*4);      // becomes cursor after scan
  int* cnt_p    = (int*)alloc((size_t)NP*4);
  int* cnt_t    = (int*)alloc((size_t)NP*4);
  int* rowptr_s = (int*)alloc((size_t)(NS+1)*4);
  int* rowptr_p = (int*)alloc((size_t)(NP+1)*4);
  int* rowptr_t = (int*)alloc((size_t)(NP+1)*4);
  int* sorted_ps = (int*)alloc((size_t)NE*4);
  int* sorted_sp = (int*)alloc((size_t)NE*4);
  int* sorted_te = (int*)alloc((size_t)NE*4);
  // pad region so GEMM tile-tail staging reads past last matrix stay in-bounds
  alloc((size_t)128*H*2);

  // weight convert+transpose (independent of everything else)
  TArgs ta;
  ta.m[0] = {c1_ps_Wl, Wt[0]}; ta.m[1] = {c1_ps_Wr, Wt[1]};
  ta.m[2] = {c1_sp_Wl, Wt[2]}; ta.m[3] = {c1_sp_Wr, Wt[3]};
  ta.m[4] = {c2_ps_Wl, Wt[4]}; ta.m[5] = {c2_ps_Wr, Wt[5]};
  ta.m[6] = {c2_sp_Wl, Wt[6]}; ta.m[7] = {c2_sp_Wr, Wt[7]};
  ta.m[8] = {d1W, Wt[8]};                      // d1_W rows 0..511   (pol part)
  ta.m[9] = {d1W + (size_t)512*H, Wt[9]};      // d1_W rows 512..1023 (stock part)
  wtrans_kernel<<<dim3(16,16,10), 256, 0, stream>>>(ta);

  // CSR build (ps->stock, sp->pol, trade->pol)
  hipMemsetAsync(cnt_s, 0, (size_t)NS*4, stream);
  hipMemsetAsync(cnt_p, 0, (size_t)NP*4, stream);
  hipMemsetAsync(cnt_t, 0, (size_t)NP*4, stream);
  hist_kernel<<<(NE+255)/256, 256, 0, stream>>>(ps_dst, sp_dst, trow, cnt_s, cnt_p, cnt_t);
  scan3_kernel<<<3, 1024, 0, stream>>>(cnt_s, NS, rowptr_s, cnt_p, NP, rowptr_p, cnt_t, NP, rowptr_t);
  scatter_kernel<<<(NE+255)/256, 256, 0, stream>>>(ps_src, ps_dst, sp_src, sp_dst, trow,
                                                   cnt_s, cnt_p, cnt_t,
                                                   sorted_ps, sorted_sp, sorted_te);

  // input projections
  proj_kernel<<<(NP+7)/8, 256, 0, stream>>>(x_pol, Wp, bp, P0, NP);
  proj_kernel<<<(NS+7)/8, 256, 0, stream>>>(x_stock, Wst, bst, S0, NS);

  int aggGrid = (NS + NP + 3) / 4;
  int gRows = (NP + 127) / 128;   // max rows tiles across paired problems

  // conv1: MS = mean_ps(P0), MP = mean_sp(S0); then paired GEMM
  agg2_kernel<<<aggGrid, 256, 0, stream>>>(P0, rowptr_s, sorted_ps, MS, NS,
                                           S0, rowptr_p, sorted_sp, MP, NP);
  {
    GemmProb a = {MS, Wt[0], S0, Wt[1], c1_ps_bl, S1, NS, 1};
    GemmProb b = {MP, Wt[2], P0, Wt[3], c1_sp_bl, P1, NP, 1};
    gemm_mfma2<<<dim3(4, gRows, 2), 256, 0, stream>>>(a, b);
  }

  // conv2
  agg2_kernel<<<aggGrid, 256, 0, stream>>>(P1, rowptr_s, sorted_ps, MS, NS,
                                           S1, rowptr_p, sorted_sp, MP, NP);
  {
    GemmProb a = {MS, Wt[4], S1, Wt[5], c2_ps_bl, S0, NS, 1};
    GemmProb b = {MP, Wt[6], P1, Wt[7], c2_sp_bl, P0, NP, 1};
    gemm_mfma2<<<dim3(4, gRows, 2), 256, 0, stream>>>(a, b);
  }

  // decoder precompute pair: Adec = hp2 @ d1W[0:512,:], Bdec = hs2 @ d1W[512:1024,:]
  {
    GemmProb a = {P0, Wt[8], nullptr, nullptr, nullptr, MP, NP, 0};
    GemmProb b = {S0, Wt[9], nullptr, nullptr, nullptr, MS, NS, 0};
    gemm_mfma2<<<dim3(4, gRows, 2), 256, 0, stream>>>(a, b);
  }

  // per-edge decoder over trade-CSR (one wave per politician row)
  edge_row_kernel<<<(NP+3)/4, 256, 0, stream>>>(MP, MS, d1W, d1b, d2W, d2b,
                                                rowptr_t, sorted_te, tcol, attr, out);
}

// Round 4
// 657.911 us; speedup vs baseline: 2.5692x; 1.0523x over previous
//
#include <hip/hip_runtime.h>
#include <hip/hip_bf16.h>

typedef unsigned short u16;
typedef unsigned int u32;
typedef __attribute__((ext_vector_type(8))) short short8;
typedef __attribute__((ext_vector_type(4))) float f32x4;

#define NP 20000
#define NS 10000
#define NE 400000
#define H  512
#define FDIM 64
#define ECHUNK 16

__device__ __forceinline__ float bl16(u32 w){ return __uint_as_float(w << 16); }
__device__ __forceinline__ float bh16(u32 w){ return __uint_as_float(w & 0xffff0000u); }
__device__ __forceinline__ u16 f2bf(float f){
  u32 u = __float_as_uint(f);
  u32 r = u + 0x7fffu + ((u >> 16) & 1u);
  return (u16)(r >> 16);
}
__device__ __forceinline__ u32 pack2(float a, float b){
  return (u32)f2bf(a) | ((u32)f2bf(b) << 16);
}
__device__ __forceinline__ void gload16(const void* g, void* l){
  __builtin_amdgcn_global_load_lds((const __attribute__((address_space(1))) u32*)g,
                                   (__attribute__((address_space(3))) u32*)l, 16, 0, 0);
}

// ---------------- input projection: Y = relu(X @ W + b), X [n,64] f32, W [64,512], Y bf16 ----------------
__global__ __launch_bounds__(256) void proj_kernel(const float* __restrict__ X, const float* __restrict__ W,
                                                   const float* __restrict__ b, u16* __restrict__ Y, int n)
{
  __shared__ float xs[8][FDIM];
  int tid = threadIdx.x;
  int m0 = blockIdx.x * 8;
  {
    int r = tid >> 6, c = tid & 63;
    int m = m0 + r;
    xs[r][c] = (m < n) ? X[(size_t)m*FDIM + c] : 0.f;
    m = m0 + r + 4;
    xs[r+4][c] = (m < n) ? X[(size_t)m*FDIM + c] : 0.f;
  }
  __syncthreads();
  float acc[8][2] = {};
  int c0 = tid, c1 = tid + 256;
  for (int k = 0; k < FDIM; ++k){
    float w0 = W[k*H + c0];
    float w1 = W[k*H + c1];
    #pragma unroll
    for (int r = 0; r < 8; ++r){
      float xv = xs[r][k];
      acc[r][0] = fmaf(xv, w0, acc[r][0]);
      acc[r][1] = fmaf(xv, w1, acc[r][1]);
    }
  }
  float b0 = b[c0], b1 = b[c1];
  #pragma unroll
  for (int r = 0; r < 8; ++r){
    int m = m0 + r;
    if (m < n){
      Y[(size_t)m*H + c0] = f2bf(fmaxf(acc[r][0] + b0, 0.f));
      Y[(size_t)m*H + c1] = f2bf(fmaxf(acc[r][1] + b1, 0.f));
    }
  }
}

// ---------------- weight convert+transpose: Wt[n][k] = bf16(W[k][n]), W [512][512] f32 ----------------
struct TPair { const float* src; u16* dst; };
struct TArgs { TPair m[10]; };

__global__ __launch_bounds__(256) void wtrans_kernel(TArgs args)
{
  __shared__ float lds[32][33];
  int mat = blockIdx.z;
  const float* __restrict__ src = args.m[mat].src;
  u16* __restrict__ dst = args.m[mat].dst;
  int k0 = blockIdx.y << 5, n0 = blockIdx.x << 5;
  int t = threadIdx.x;
  int r = t >> 3, c4 = (t & 7) << 2;
  float4 v = *(const float4*)(src + (size_t)(k0 + r)*H + n0 + c4);
  lds[r][c4+0] = v.x; lds[r][c4+1] = v.y; lds[r][c4+2] = v.z; lds[r][c4+3] = v.w;
  __syncthreads();
  uint2 o;
  o.x = pack2(lds[c4+0][r], lds[c4+1][r]);
  o.y = pack2(lds[c4+2][r], lds[c4+3][r]);
  *(uint2*)(dst + (size_t)(n0 + r)*H + k0 + c4) = o;
}

// ---------------- CSR build (3 relations: ps->s, sp->p, trade->p) ----------------
__global__ void hist_kernel(const int* __restrict__ ps_dst, const int* __restrict__ sp_dst,
                            const int* __restrict__ trow,
                            int* __restrict__ cnt_s, int* __restrict__ cnt_p, int* __restrict__ cnt_t)
{
  int e = blockIdx.x * blockDim.x + threadIdx.x;
  if (e < NE){
    atomicAdd(&cnt_s[ps_dst[e]], 1);
    atomicAdd(&cnt_p[sp_dst[e]], 1);
    atomicAdd(&cnt_t[trow[e]], 1);
  }
}

// in-place exclusive scan: writes rowptr[0..n] and overwrites cnt[i] with the
// exclusive prefix (used as scatter cursor). One block per array.
__device__ void scan_one(int* cnt, int n, int* rowptr)
{
  __shared__ int lds[1024];
  __shared__ int carry_s;
  int tid = threadIdx.x;
  if (tid == 0) carry_s = 0;
  __syncthreads();
  for (int base = 0; base < n; base += 1024){
    int i = base + tid;
    int v = (i < n) ? cnt[i] : 0;
    lds[tid] = v;
    __syncthreads();
    for (int off = 1; off < 1024; off <<= 1){
      int t = (tid >= off) ? lds[tid - off] : 0;
      __syncthreads();
      lds[tid] += t;
      __syncthreads();
    }
    int incl = lds[tid];
    int cb = carry_s;
    if (i < n){
      rowptr[i] = cb + incl - v;
      cnt[i] = cb + incl - v;
    }
    __syncthreads();
    if (tid == 0) carry_s = cb + lds[1023];
    __syncthreads();
  }
  if (tid == 0) rowptr[n] = carry_s;
}

__global__ __launch_bounds__(1024) void scan3_kernel(int* c0, int n0, int* r0,
                                                     int* c1, int n1, int* r1,
                                                     int* c2, int n2, int* r2)
{
  if (blockIdx.x == 0) scan_one(c0, n0, r0);
  else if (blockIdx.x == 1) scan_one(c1, n1, r1);
  else scan_one(c2, n2, r2);
}

// scatter: ps/sp store src index; trade stores PACKED meta {e,row,col} + {a0,a1}
// so the edge decoder reads sequential metadata instead of 3 random gathers/edge.
__global__ void scatter_kernel(const int* __restrict__ ps_src, const int* __restrict__ ps_dst,
                               const int* __restrict__ sp_src, const int* __restrict__ sp_dst,
                               const int* __restrict__ trow, const int* __restrict__ tcol,
                               const float* __restrict__ attr,
                               int* __restrict__ cur_s, int* __restrict__ cur_p, int* __restrict__ cur_t,
                               int* __restrict__ sorted_ps, int* __restrict__ sorted_sp,
                               int4* __restrict__ meta_t, float2* __restrict__ attr_t)
{
  int e = blockIdx.x * blockDim.x + threadIdx.x;
  if (e < NE){
    int pos = atomicAdd(&cur_s[ps_dst[e]], 1);
    sorted_ps[pos] = ps_src[e];
    int pos2 = atomicAdd(&cur_p[sp_dst[e]], 1);
    sorted_sp[pos2] = sp_src[e];
    int r = trow[e];
    int pos3 = atomicAdd(&cur_t[r], 1);
    meta_t[pos3] = make_int4(e, r, tcol[e], 0);
    attr_t[pos3] = make_float2(attr[2*e], attr[2*e+1]);
  }
}

// ---------------- paired mean aggregation: one wave per dst row, 4 gathers in flight ----------------
__global__ __launch_bounds__(256) void agg2_kernel(
    const u16* __restrict__ X0, const int* __restrict__ rp0, const int* __restrict__ s0,
    u16* __restrict__ M0, int n0,
    const u16* __restrict__ X1, const int* __restrict__ rp1, const int* __restrict__ s1,
    u16* __restrict__ M1, int n1)
{
  int wid = (blockIdx.x << 2) + (threadIdx.x >> 6);
  int lane = threadIdx.x & 63;
  const u16* X; const int* rp; const int* ss; u16* M; int row;
  if (wid < n0){ X = X0; rp = rp0; ss = s0; M = M0; row = wid; }
  else if (wid < n0 + n1){ X = X1; rp = rp1; ss = s1; M = M1; row = wid - n0; }
  else return;
  int beg = rp[row], end = rp[row + 1];
  float acc[8] = {0,0,0,0,0,0,0,0};
  int j0 = lane << 3;
#define ACCV(v) { acc[0] += bl16(v.x); acc[1] += bh16(v.x); \
                  acc[2] += bl16(v.y); acc[3] += bh16(v.y); \
                  acc[4] += bl16(v.z); acc[5] += bh16(v.z); \
                  acc[6] += bl16(v.w); acc[7] += bh16(v.w); }
  int i = beg;
  for (; i + 4 <= end; i += 4){
    int sa = ss[i], sb = ss[i+1], sc = ss[i+2], sd = ss[i+3];
    uint4 v0 = *(const uint4*)(X + (size_t)sa*H + j0);
    uint4 v1 = *(const uint4*)(X + (size_t)sb*H + j0);
    uint4 v2 = *(const uint4*)(X + (size_t)sc*H + j0);
    uint4 v3 = *(const uint4*)(X + (size_t)sd*H + j0);
    ACCV(v0); ACCV(v1); ACCV(v2); ACCV(v3);
  }
  for (; i < end; ++i){
    int sa = ss[i];
    uint4 v0 = *(const uint4*)(X + (size_t)sa*H + j0);
    ACCV(v0);
  }
#undef ACCV
  float inv = 1.f / (float)max(end - beg, 1);
  uint4 o;
  o.x = pack2(acc[0]*inv, acc[1]*inv);
  o.y = pack2(acc[2]*inv, acc[3]*inv);
  o.z = pack2(acc[4]*inv, acc[5]*inv);
  o.w = pack2(acc[6]*inv, acc[7]*inv);
  *(uint4*)(M + (size_t)row*H + j0) = o;
}

// ---------------- MFMA GEMM pair: two independent problems per launch (blockIdx.z) ----------------
struct GemmProb {
  const u16* A1; const u16* W1t; const u16* A2; const u16* W2t;
  const float* bias; u16* C; int nrows; int relu;
};

__global__ __launch_bounds__(256) void gemm_mfma2(GemmProb Pa, GemmProb Pb)
{
  GemmProb P = blockIdx.z ? Pb : Pa;
  int m0 = blockIdx.y << 7, n0 = blockIdx.x << 7;
  if (m0 >= P.nrows) return;

  __shared__ u16 As[128*64];
  __shared__ u16 Bs[128*64];
  char* AsB = (char*)As;
  char* BsB = (char*)Bs;
  int t = threadIdx.x;
  int w = t >> 6, l = t & 63;
  int wr = w >> 1, wc = w & 1;
  int lr = l & 15, lg = l >> 4;

  f32x4 acc[4][4];
  #pragma unroll
  for (int i = 0; i < 4; ++i)
    #pragma unroll
    for (int j = 0; j < 4; ++j)
      acc[i][j] = (f32x4){0.f, 0.f, 0.f, 0.f};

  for (int phase = 0; phase < 2; ++phase){
    const u16* Ap = phase ? P.A2 : P.A1;
    const u16* Wp = phase ? P.W2t : P.W1t;
    if (!Ap) break;
    for (int k0 = 0; k0 < H; k0 += 64){
      #pragma unroll
      for (int i = 0; i < 4; ++i){
        int c = i*256 + t;           // 16B chunk index, linear LDS position
        int row = c >> 3, p = c & 7;
        int k8 = p ^ (row & 7);      // inverse-swizzled global chunk
        gload16(Ap + (size_t)(m0 + row)*H + k0 + k8*8, AsB + c*16);
        gload16(Wp + (size_t)(n0 + row)*H + k0 + k8*8, BsB + c*16);
      }
      __syncthreads();
      #pragma unroll
      for (int ks = 0; ks < 2; ++ks){
        short8 a[4], b[4];
        int kc = (ks << 2) + lg;
        #pragma unroll
        for (int mi = 0; mi < 4; ++mi){
          int r = (wr << 6) + (mi << 4) + lr;
          a[mi] = *(const short8*)(AsB + r*128 + ((kc ^ (r & 7)) << 4));
        }
        #pragma unroll
        for (int ni = 0; ni < 4; ++ni){
          int r = (wc << 6) + (ni << 4) + lr;
          b[ni] = *(const short8*)(BsB + r*128 + ((kc ^ (r & 7)) << 4));
        }
        #pragma unroll
        for (int mi = 0; mi < 4; ++mi)
          #pragma unroll
          for (int ni = 0; ni < 4; ++ni)
            acc[mi][ni] = __builtin_amdgcn_mfma_f32_16x16x32_bf16(a[mi], b[ni], acc[mi][ni], 0, 0, 0);
      }
      __syncthreads();
    }
  }

  float bv[4];
  #pragma unroll
  for (int ni = 0; ni < 4; ++ni)
    bv[ni] = P.bias ? P.bias[n0 + (wc << 6) + (ni << 4) + lr] : 0.f;
  #pragma unroll
  for (int mi = 0; mi < 4; ++mi){
    #pragma unroll
    for (int j = 0; j < 4; ++j){
      int m = m0 + (wr << 6) + (mi << 4) + (lg << 2) + j;
      if (m < P.nrows){
        #pragma unroll
        for (int ni = 0; ni < 4; ++ni){
          float v = acc[mi][ni][j] + bv[ni];
          if (P.relu) v = fmaxf(v, 0.f);
          P.C[(size_t)m*H + n0 + (wc << 6) + (ni << 4) + lr] = f2bf(v);
        }
      }
    }
  }
}

// ---------------- edge decoder: one wave per 16-edge chunk, packed sequential metadata ----------------
// Rows are non-decreasing along the trade-CSR order, so the A-row register cache
// reloads only on (wave-uniform) row change. B gathers pipelined 2-deep.
__global__ __launch_bounds__(256) void edge_chunk_kernel(
    const u16* __restrict__ Adec, const u16* __restrict__ Bdec,
    const float* __restrict__ d1W, const float* __restrict__ d1b,
    const float* __restrict__ d2W, const float* __restrict__ d2b,
    const int4* __restrict__ meta_t, const float2* __restrict__ attr_t,
    float* __restrict__ out)
{
  int lane = threadIdx.x & 63;
  int ch = (blockIdx.x << 2) + (threadIdx.x >> 6);
  int base = ch * ECHUNK;
  if (base >= NE) return;
  int j0 = lane << 3;

  float w1a[8], w1b[8], bb[8], w2[8][3];
  #pragma unroll
  for (int q = 0; q < 8; ++q){
    w1a[q] = d1W[(size_t)1024*H + j0 + q];
    w1b[q] = d1W[(size_t)1025*H + j0 + q];
    bb[q]  = d1b[j0 + q];
    w2[q][0] = d2W[(j0+q)*3 + 0];
    w2[q][1] = d2W[(j0+q)*3 + 1];
    w2[q][2] = d2W[(j0+q)*3 + 2];
  }
  float ob0 = d2b[0], ob1 = d2b[1], ob2 = d2b[2];

  int cached_r = -1;
  float fa[8];

  auto compute = [&](int e, float a0, float a1, uint4 vb){
    float fb[8] = {bl16(vb.x),bh16(vb.x),bl16(vb.y),bh16(vb.y),
                   bl16(vb.z),bh16(vb.z),bl16(vb.w),bh16(vb.w)};
    float s0 = 0.f, s1 = 0.f, s2 = 0.f;
    #pragma unroll
    for (int q = 0; q < 8; ++q){
      float h = fa[q] + fb[q];
      h = fmaf(a0, w1a[q], h);
      h = fmaf(a1, w1b[q], h);
      h = fmaxf(h, 0.f);
      s0 = fmaf(h, w2[q][0], s0);
      s1 = fmaf(h, w2[q][1], s1);
      s2 = fmaf(h, w2[q][2], s2);
    }
    #pragma unroll
    for (int off = 32; off > 0; off >>= 1){
      s0 += __shfl_xor(s0, off);
      s1 += __shfl_xor(s1, off);
      s2 += __shfl_xor(s2, off);
    }
    if (lane == 0){
      out[(size_t)e*3 + 0] = s0 + ob0;
      out[(size_t)e*3 + 1] = s1 + ob1;
      out[(size_t)e*3 + 2] = s2 + ob2;
    }
  };
  auto loadA = [&](int r){
    cached_r = r;
    uint4 va = *(const uint4*)(Adec + (size_t)r*H + j0);
    fa[0] = bl16(va.x)+bb[0]; fa[1] = bh16(va.x)+bb[1];
    fa[2] = bl16(va.y)+bb[2]; fa[3] = bh16(va.y)+bb[3];
    fa[4] = bl16(va.z)+bb[4]; fa[5] = bh16(va.z)+bb[5];
    fa[6] = bl16(va.w)+bb[6]; fa[7] = bh16(va.w)+bb[7];
  };

  // prologue: load pair 0
  int4 mA = meta_t[base + 0];
  int4 mB = meta_t[base + 1];
  float2 aA = attr_t[base + 0];
  float2 aB = attr_t[base + 1];
  uint4 vbA = *(const uint4*)(Bdec + (size_t)mA.z*H + j0);
  uint4 vbB = *(const uint4*)(Bdec + (size_t)mB.z*H + j0);

  for (int i = 0; i < ECHUNK; i += 2){
    // issue next pair's loads (independent of current compute)
    int4 mA2 = {}, mB2 = {};
    float2 aA2 = {}, aB2 = {};
    uint4 vbA2 = {}, vbB2 = {};
    if (i + 2 < ECHUNK){
      mA2 = meta_t[base + i + 2];
      mB2 = meta_t[base + i + 3];
      aA2 = attr_t[base + i + 2];
      aB2 = attr_t[base + i + 3];
      vbA2 = *(const uint4*)(Bdec + (size_t)mA2.z*H + j0);
      vbB2 = *(const uint4*)(Bdec + (size_t)mB2.z*H + j0);
    }
    if (mA.y != cached_r) loadA(mA.y);
    compute(mA.x, aA.x, aA.y, vbA);
    if (mB.y != cached_r) loadA(mB.y);
    compute(mB.x, aB.x, aB.y, vbB);
    mA = mA2; mB = mB2; aA = aA2; aB = aB2; vbA = vbA2; vbB = vbB2;
  }
}

extern "C" void kernel_launch(void* const* d_in, const int* in_sizes, int n_in,
                              void* d_out, int out_size, void* d_ws, size_t ws_size,
                              hipStream_t stream)
{
  const float* x_pol    = (const float*)d_in[0];
  const float* x_stock  = (const float*)d_in[1];
  const float* attr     = (const float*)d_in[2];
  const float* Wp       = (const float*)d_in[3];
  const float* bp       = (const float*)d_in[4];
  const float* Wst      = (const float*)d_in[5];
  const float* bst      = (const float*)d_in[6];
  const float* c1_ps_Wl = (const float*)d_in[7];
  const float* c1_ps_bl = (const float*)d_in[8];
  const float* c1_ps_Wr = (const float*)d_in[9];
  const float* c1_sp_Wl = (const float*)d_in[10];
  const float* c1_sp_bl = (const float*)d_in[11];
  const float* c1_sp_Wr = (const float*)d_in[12];
  const float* c2_ps_Wl = (const float*)d_in[13];
  const float* c2_ps_bl = (const float*)d_in[14];
  const float* c2_ps_Wr = (const float*)d_in[15];
  const float* c2_sp_Wl = (const float*)d_in[16];
  const float* c2_sp_bl = (const float*)d_in[17];
  const float* c2_sp_Wr = (const float*)d_in[18];
  const float* d1W      = (const float*)d_in[19];
  const float* d1b      = (const float*)d_in[20];
  const float* d2W      = (const float*)d_in[21];
  const float* d2b      = (const float*)d_in[22];
  const int* ps_src     = (const int*)d_in[23];
  const int* ps_dst     = (const int*)d_in[24];
  const int* sp_src     = (const int*)d_in[25];
  const int* sp_dst     = (const int*)d_in[26];
  const int* trow       = (const int*)d_in[27];
  const int* tcol       = (const int*)d_in[28];
  float* out = (float*)d_out;

  char* ws = (char*)d_ws;
  size_t off = 0;
  auto alloc = [&](size_t bytes)->char*{
    char* p = ws + off;
    off += (bytes + 255) & ~(size_t)255;
    return p;
  };
  u16* P0 = (u16*)alloc((size_t)NP*H*2);   // hp -> hp2
  u16* P1 = (u16*)alloc((size_t)NP*H*2);   // hp1
  u16* S0 = (u16*)alloc((size_t)NS*H*2);   // hs -> hs2
  u16* S1 = (u16*)alloc((size_t)NS*H*2);   // hs1
  u16* MP = (u16*)alloc((size_t)NP*H*2);   // mean into pol / Adec
  u16* MS = (u16*)alloc((size_t)NS*H*2);   // mean into stock / Bdec
  u16* Wt[10];
  for (int i = 0; i < 10; ++i) Wt[i] = (u16*)alloc((size_t)H*H*2);
  int* cnt_s    = (int*)alloc((size_t)NS*4);      // becomes cursor after scan
  int* cnt_p    = (int*)alloc((size_t)NP*4);
  int* cnt_t    = (int*)alloc((size_t)NP*4);
  int* rowptr_s = (int*)alloc((size_t)(NS+1)*4);
  int* rowptr_p = (int*)alloc((size_t)(NP+1)*4);
  int* rowptr_t = (int*)alloc((size_t)(NP+1)*4);
  int* sorted_ps = (int*)alloc((size_t)NE*4);
  int* sorted_sp = (int*)alloc((size_t)NE*4);
  int4* meta_t   = (int4*)alloc((size_t)NE*16);
  float2* attr_t = (float2*)alloc((size_t)NE*8);
  // pad region so GEMM tile-tail staging reads past last matrix stay in-bounds
  alloc((size_t)128*H*2);

  // weight convert+transpose (independent of everything else)
  TArgs ta;
  ta.m[0] = {c1_ps_Wl, Wt[0]}; ta.m[1] = {c1_ps_Wr, Wt[1]};
  ta.m[2] = {c1_sp_Wl, Wt[2]}; ta.m[3] = {c1_sp_Wr, Wt[3]};
  ta.m[4] = {c2_ps_Wl, Wt[4]}; ta.m[5] = {c2_ps_Wr, Wt[5]};
  ta.m[6] = {c2_sp_Wl, Wt[6]}; ta.m[7] = {c2_sp_Wr, Wt[7]};
  ta.m[8] = {d1W, Wt[8]};                      // d1_W rows 0..511   (pol part)
  ta.m[9] = {d1W + (size_t)512*H, Wt[9]};      // d1_W rows 512..1023 (stock part)
  wtrans_kernel<<<dim3(16,16,10), 256, 0, stream>>>(ta);

  // CSR build (ps->stock, sp->pol, trade->pol)
  hipMemsetAsync(cnt_s, 0, (size_t)NS*4, stream);
  hipMemsetAsync(cnt_p, 0, (size_t)NP*4, stream);
  hipMemsetAsync(cnt_t, 0, (size_t)NP*4, stream);
  hist_kernel<<<(NE+255)/256, 256, 0, stream>>>(ps_dst, sp_dst, trow, cnt_s, cnt_p, cnt_t);
  scan3_kernel<<<3, 1024, 0, stream>>>(cnt_s, NS, rowptr_s, cnt_p, NP, rowptr_p, cnt_t, NP, rowptr_t);
  scatter_kernel<<<(NE+255)/256, 256, 0, stream>>>(ps_src, ps_dst, sp_src, sp_dst, trow, tcol, attr,
                                                   cnt_s, cnt_p, cnt_t,
                                                   sorted_ps, sorted_sp, meta_t, attr_t);

  // input projections
  proj_kernel<<<(NP+7)/8, 256, 0, stream>>>(x_pol, Wp, bp, P0, NP);
  proj_kernel<<<(NS+7)/8, 256, 0, stream>>>(x_stock, Wst, bst, S0, NS);

  int aggGrid = (NS + NP + 3) / 4;
  int gRows = (NP + 127) / 128;   // max rows tiles across paired problems

  // conv1: MS = mean_ps(P0), MP = mean_sp(S0); then paired GEMM
  agg2_kernel<<<aggGrid, 256, 0, stream>>>(P0, rowptr_s, sorted_ps, MS, NS,
                                           S0, rowptr_p, sorted_sp, MP, NP);
  {
    GemmProb a = {MS, Wt[0], S0, Wt[1], c1_ps_bl, S1, NS, 1};
    GemmProb b = {MP, Wt[2], P0, Wt[3], c1_sp_bl, P1, NP, 1};
    gemm_mfma2<<<dim3(4, gRows, 2), 256, 0, stream>>>(a, b);
  }

  // conv2
  agg2_kernel<<<aggGrid, 256, 0, stream>>>(P1, rowptr_s, sorted_ps, MS, NS,
                                           S1, rowptr_p, sorted_sp, MP, NP);
  {
    GemmProb a = {MS, Wt[4], S1, Wt[5], c2_ps_bl, S0, NS, 1};
    GemmProb b = {MP, Wt[6], P1, Wt[7], c2_sp_bl, P0, NP, 1};
    gemm_mfma2<<<dim3(4, gRows, 2), 256, 0, stream>>>(a, b);
  }

  // decoder precompute pair: Adec = hp2 @ d1W[0:512,:], Bdec = hs2 @ d1W[512:1024,:]
  {
    GemmProb a = {P0, Wt[8], nullptr, nullptr, nullptr, MP, NP, 0};
    GemmProb b = {S0, Wt[9], nullptr, nullptr, nullptr, MS, NS, 0};
    gemm_mfma2<<<dim3(4, gRows, 2), 256, 0, stream>>>(a, b);
  }

  // per-edge decoder: one wave per 16-edge chunk of the trade-CSR
  int nchunks = NE / ECHUNK;
  edge_chunk_kernel<<<(nchunks + 3) / 4, 256, 0, stream>>>(MP, MS, d1W, d1b, d2W, d2b,
                                                           meta_t, attr_t, out);
}

// Round 5
// 628.385 us; speedup vs baseline: 2.6900x; 1.0470x over previous
//
#include <hip/hip_runtime.h>
#include <hip/hip_bf16.h>

typedef unsigned short u16;
typedef unsigned int u32;
typedef __attribute__((ext_vector_type(8))) short short8;
typedef __attribute__((ext_vector_type(4))) float f32x4;
typedef __attribute__((ext_vector_type(2))) float f32x2;

#define NP 20000
#define NS 10000
#define NE 400000
#define H  512
#define FDIM 64
#define ECHUNK 16

__device__ __forceinline__ float bl16(u32 w){ return __uint_as_float(w << 16); }
__device__ __forceinline__ float bh16(u32 w){ return __uint_as_float(w & 0xffff0000u); }
__device__ __forceinline__ u16 f2bf(float f){
  u32 u = __float_as_uint(f);
  u32 r = u + 0x7fffu + ((u >> 16) & 1u);
  return (u16)(r >> 16);
}
__device__ __forceinline__ u32 pack2(float a, float b){
  return (u32)f2bf(a) | ((u32)f2bf(b) << 16);
}
__device__ __forceinline__ void gload16(const void* g, void* l){
  __builtin_amdgcn_global_load_lds((const __attribute__((address_space(1))) u32*)g,
                                   (__attribute__((address_space(3))) u32*)l, 16, 0, 0);
}
// packed fp32 (VOP3P, gfx90a+): 2 fma / 2 add per instruction
__device__ __forceinline__ f32x2 pk_fma(f32x2 a, f32x2 b, f32x2 c){
  f32x2 d;
  asm("v_pk_fma_f32 %0, %1, %2, %3" : "=v"(d) : "v"(a), "v"(b), "v"(c));
  return d;
}
__device__ __forceinline__ f32x2 pk_add(f32x2 a, f32x2 b){
  f32x2 d;
  asm("v_pk_add_f32 %0, %1, %2" : "=v"(d) : "v"(a), "v"(b));
  return d;
}

// ---------------- input projection: Y = relu(X @ W + b), X [n,64] f32, W [64,512], Y bf16 ----------------
__global__ __launch_bounds__(256) void proj_kernel(const float* __restrict__ X, const float* __restrict__ W,
                                                   const float* __restrict__ b, u16* __restrict__ Y, int n)
{
  __shared__ float xs[8][FDIM];
  int tid = threadIdx.x;
  int m0 = blockIdx.x * 8;
  {
    int r = tid >> 6, c = tid & 63;
    int m = m0 + r;
    xs[r][c] = (m < n) ? X[(size_t)m*FDIM + c] : 0.f;
    m = m0 + r + 4;
    xs[r+4][c] = (m < n) ? X[(size_t)m*FDIM + c] : 0.f;
  }
  __syncthreads();
  float acc[8][2] = {};
  int c0 = tid, c1 = tid + 256;
  for (int k = 0; k < FDIM; ++k){
    float w0 = W[k*H + c0];
    float w1 = W[k*H + c1];
    #pragma unroll
    for (int r = 0; r < 8; ++r){
      float xv = xs[r][k];
      acc[r][0] = fmaf(xv, w0, acc[r][0]);
      acc[r][1] = fmaf(xv, w1, acc[r][1]);
    }
  }
  float b0 = b[c0], b1 = b[c1];
  #pragma unroll
  for (int r = 0; r < 8; ++r){
    int m = m0 + r;
    if (m < n){
      Y[(size_t)m*H + c0] = f2bf(fmaxf(acc[r][0] + b0, 0.f));
      Y[(size_t)m*H + c1] = f2bf(fmaxf(acc[r][1] + b1, 0.f));
    }
  }
}

// ---------------- weight convert+transpose: Wt[n][k] = bf16(W[k][n]), W [512][512] f32 ----------------
struct TPair { const float* src; u16* dst; };
struct TArgs { TPair m[10]; };

__global__ __launch_bounds__(256) void wtrans_kernel(TArgs args)
{
  __shared__ float lds[32][33];
  int mat = blockIdx.z;
  const float* __restrict__ src = args.m[mat].src;
  u16* __restrict__ dst = args.m[mat].dst;
  int k0 = blockIdx.y << 5, n0 = blockIdx.x << 5;
  int t = threadIdx.x;
  int r = t >> 3, c4 = (t & 7) << 2;
  float4 v = *(const float4*)(src + (size_t)(k0 + r)*H + n0 + c4);
  lds[r][c4+0] = v.x; lds[r][c4+1] = v.y; lds[r][c4+2] = v.z; lds[r][c4+3] = v.w;
  __syncthreads();
  uint2 o;
  o.x = pack2(lds[c4+0][r], lds[c4+1][r]);
  o.y = pack2(lds[c4+2][r], lds[c4+3][r]);
  *(uint2*)(dst + (size_t)(n0 + r)*H + k0 + c4) = o;
}

// ---------------- CSR build (3 relations: ps->s, sp->p, trade->p) ----------------
__global__ void hist_kernel(const int* __restrict__ ps_dst, const int* __restrict__ sp_dst,
                            const int* __restrict__ trow,
                            int* __restrict__ cnt_s, int* __restrict__ cnt_p, int* __restrict__ cnt_t)
{
  int e = blockIdx.x * blockDim.x + threadIdx.x;
  if (e < NE){
    atomicAdd(&cnt_s[ps_dst[e]], 1);
    atomicAdd(&cnt_p[sp_dst[e]], 1);
    atomicAdd(&cnt_t[trow[e]], 1);
  }
}

// in-place exclusive scan via wave-shuffle (4 barriers/chunk, was ~21).
// writes rowptr[0..n]; overwrites cnt[i] with exclusive prefix (scatter cursor).
__device__ void scan_one(int* cnt, int n, int* rowptr)
{
  __shared__ int wsum[16];
  __shared__ int carry_s;
  int tid = threadIdx.x;
  int lane = tid & 63, wv = tid >> 6;
  if (tid == 0) carry_s = 0;
  for (int base = 0; base < n; base += 1024){
    __syncthreads();                       // protects carry_s/wsum reuse
    int i = base + tid;
    int v = (i < n) ? cnt[i] : 0;
    int x = v;
    #pragma unroll
    for (int off = 1; off < 64; off <<= 1){
      int t = __shfl_up(x, off);
      if (lane >= off) x += t;
    }
    if (lane == 63) wsum[wv] = x;
    __syncthreads();
    if (wv == 0 && lane < 16){
      int y = wsum[lane];
      #pragma unroll
      for (int off = 1; off < 16; off <<= 1){
        int t = __shfl_up(y, off, 16);
        if (lane >= off) y += t;
      }
      wsum[lane] = y;
    }
    __syncthreads();
    int woff = (wv > 0) ? wsum[wv-1] : 0;
    int cb = carry_s;
    int excl = cb + woff + x - v;
    if (i < n){ rowptr[i] = excl; cnt[i] = excl; }
    __syncthreads();
    if (tid == 1023) carry_s = cb + woff + x;   // running total
  }
  __syncthreads();
  if (tid == 0) rowptr[n] = carry_s;
}

__global__ __launch_bounds__(1024) void scan3_kernel(int* c0, int n0, int* r0,
                                                     int* c1, int n1, int* r1,
                                                     int* c2, int n2, int* r2)
{
  if (blockIdx.x == 0) scan_one(c0, n0, r0);
  else if (blockIdx.x == 1) scan_one(c1, n1, r1);
  else scan_one(c2, n2, r2);
}

// scatter: ps/sp store src index; trade stores PACKED meta {e,row,col} + {a0,a1}
__global__ void scatter_kernel(const int* __restrict__ ps_src, const int* __restrict__ ps_dst,
                               const int* __restrict__ sp_src, const int* __restrict__ sp_dst,
                               const int* __restrict__ trow, const int* __restrict__ tcol,
                               const float* __restrict__ attr,
                               int* __restrict__ cur_s, int* __restrict__ cur_p, int* __restrict__ cur_t,
                               int* __restrict__ sorted_ps, int* __restrict__ sorted_sp,
                               int4* __restrict__ meta_t, float2* __restrict__ attr_t)
{
  int e = blockIdx.x * blockDim.x + threadIdx.x;
  if (e < NE){
    int pos = atomicAdd(&cur_s[ps_dst[e]], 1);
    sorted_ps[pos] = ps_src[e];
    int pos2 = atomicAdd(&cur_p[sp_dst[e]], 1);
    sorted_sp[pos2] = sp_src[e];
    int r = trow[e];
    int pos3 = atomicAdd(&cur_t[r], 1);
    meta_t[pos3] = make_int4(e, r, tcol[e], 0);
    attr_t[pos3] = make_float2(attr[2*e], attr[2*e+1]);
  }
}

// ---------------- paired mean aggregation: one wave per dst row, 8 gathers in flight ----------------
__global__ __launch_bounds__(256) void agg2_kernel(
    const u16* __restrict__ X0, const int* __restrict__ rp0, const int* __restrict__ s0,
    u16* __restrict__ M0, int n0,
    const u16* __restrict__ X1, const int* __restrict__ rp1, const int* __restrict__ s1,
    u16* __restrict__ M1, int n1)
{
  int wid = (blockIdx.x << 2) + (threadIdx.x >> 6);
  int lane = threadIdx.x & 63;
  const u16* X; const int* rp; const int* ss; u16* M; int row;
  if (wid < n0){ X = X0; rp = rp0; ss = s0; M = M0; row = wid; }
  else if (wid < n0 + n1){ X = X1; rp = rp1; ss = s1; M = M1; row = wid - n0; }
  else return;
  int beg = rp[row], end = rp[row + 1];
  f32x2 ac0 = {0,0}, ac1 = {0,0}, ac2 = {0,0}, ac3 = {0,0};
  int j0 = lane << 3;
#define ACCP(v) { ac0 = pk_add(ac0, (f32x2){bl16(v.x), bh16(v.x)}); \
                  ac1 = pk_add(ac1, (f32x2){bl16(v.y), bh16(v.y)}); \
                  ac2 = pk_add(ac2, (f32x2){bl16(v.z), bh16(v.z)}); \
                  ac3 = pk_add(ac3, (f32x2){bl16(v.w), bh16(v.w)}); }
  int i = beg;
  for (; i + 8 <= end; i += 8){
    int sa = ss[i+0], sb = ss[i+1], sc = ss[i+2], sd = ss[i+3];
    int se = ss[i+4], sf = ss[i+5], sg = ss[i+6], sh = ss[i+7];
    uint4 v0 = *(const uint4*)(X + (size_t)sa*H + j0);
    uint4 v1 = *(const uint4*)(X + (size_t)sb*H + j0);
    uint4 v2 = *(const uint4*)(X + (size_t)sc*H + j0);
    uint4 v3 = *(const uint4*)(X + (size_t)sd*H + j0);
    uint4 v4 = *(const uint4*)(X + (size_t)se*H + j0);
    uint4 v5 = *(const uint4*)(X + (size_t)sf*H + j0);
    uint4 v6 = *(const uint4*)(X + (size_t)sg*H + j0);
    uint4 v7 = *(const uint4*)(X + (size_t)sh*H + j0);
    ACCP(v0); ACCP(v1); ACCP(v2); ACCP(v3);
    ACCP(v4); ACCP(v5); ACCP(v6); ACCP(v7);
  }
  for (; i + 2 <= end; i += 2){
    int sa = ss[i], sb = ss[i+1];
    uint4 v0 = *(const uint4*)(X + (size_t)sa*H + j0);
    uint4 v1 = *(const uint4*)(X + (size_t)sb*H + j0);
    ACCP(v0); ACCP(v1);
  }
  if (i < end){
    int sa = ss[i];
    uint4 v0 = *(const uint4*)(X + (size_t)sa*H + j0);
    ACCP(v0);
  }
#undef ACCP
  float inv = 1.f / (float)max(end - beg, 1);
  uint4 o;
  o.x = pack2(ac0.x*inv, ac0.y*inv);
  o.y = pack2(ac1.x*inv, ac1.y*inv);
  o.z = pack2(ac2.x*inv, ac2.y*inv);
  o.w = pack2(ac3.x*inv, ac3.y*inv);
  *(uint4*)(M + (size_t)row*H + j0) = o;
}

// ---------------- MFMA GEMM pair: two independent problems per launch (blockIdx.z) ----------------
struct GemmProb {
  const u16* A1; const u16* W1t; const u16* A2; const u16* W2t;
  const float* bias; u16* C; int nrows; int relu;
};

__global__ __launch_bounds__(256) void gemm_mfma2(GemmProb Pa, GemmProb Pb)
{
  GemmProb P = blockIdx.z ? Pb : Pa;
  int m0 = blockIdx.y << 7, n0 = blockIdx.x << 7;
  if (m0 >= P.nrows) return;

  __shared__ u16 As[128*64];
  __shared__ u16 Bs[128*64];
  char* AsB = (char*)As;
  char* BsB = (char*)Bs;
  int t = threadIdx.x;
  int w = t >> 6, l = t & 63;
  int wr = w >> 1, wc = w & 1;
  int lr = l & 15, lg = l >> 4;

  f32x4 acc[4][4];
  #pragma unroll
  for (int i = 0; i < 4; ++i)
    #pragma unroll
    for (int j = 0; j < 4; ++j)
      acc[i][j] = (f32x4){0.f, 0.f, 0.f, 0.f};

  for (int phase = 0; phase < 2; ++phase){
    const u16* Ap = phase ? P.A2 : P.A1;
    const u16* Wp = phase ? P.W2t : P.W1t;
    if (!Ap) break;
    for (int k0 = 0; k0 < H; k0 += 64){
      #pragma unroll
      for (int i = 0; i < 4; ++i){
        int c = i*256 + t;           // 16B chunk index, linear LDS position
        int row = c >> 3, p = c & 7;
        int k8 = p ^ (row & 7);      // inverse-swizzled global chunk
        gload16(Ap + (size_t)(m0 + row)*H + k0 + k8*8, AsB + c*16);
        gload16(Wp + (size_t)(n0 + row)*H + k0 + k8*8, BsB + c*16);
      }
      __syncthreads();
      #pragma unroll
      for (int ks = 0; ks < 2; ++ks){
        short8 a[4], b[4];
        int kc = (ks << 2) + lg;
        #pragma unroll
        for (int mi = 0; mi < 4; ++mi){
          int r = (wr << 6) + (mi << 4) + lr;
          a[mi] = *(const short8*)(AsB + r*128 + ((kc ^ (r & 7)) << 4));
        }
        #pragma unroll
        for (int ni = 0; ni < 4; ++ni){
          int r = (wc << 6) + (ni << 4) + lr;
          b[ni] = *(const short8*)(BsB + r*128 + ((kc ^ (r & 7)) << 4));
        }
        #pragma unroll
        for (int mi = 0; mi < 4; ++mi)
          #pragma unroll
          for (int ni = 0; ni < 4; ++ni)
            acc[mi][ni] = __builtin_amdgcn_mfma_f32_16x16x32_bf16(a[mi], b[ni], acc[mi][ni], 0, 0, 0);
      }
      __syncthreads();
    }
  }

  float bv[4];
  #pragma unroll
  for (int ni = 0; ni < 4; ++ni)
    bv[ni] = P.bias ? P.bias[n0 + (wc << 6) + (ni << 4) + lr] : 0.f;
  #pragma unroll
  for (int mi = 0; mi < 4; ++mi){
    #pragma unroll
    for (int j = 0; j < 4; ++j){
      int m = m0 + (wr << 6) + (mi << 4) + (lg << 2) + j;
      if (m < P.nrows){
        #pragma unroll
        for (int ni = 0; ni < 4; ++ni){
          float v = acc[mi][ni][j] + bv[ni];
          if (P.relu) v = fmaxf(v, 0.f);
          P.C[(size_t)m*H + n0 + (wc << 6) + (ni << 4) + lr] = f2bf(v);
        }
      }
    }
  }
}

// ---------------- edge decoder: one wave per 16-edge chunk ----------------
// Metadata held one-edge-per-lane (lane<16) and broadcast via shfl; B-row
// gathers pipelined 4 deep; MLP in packed fp32 (v_pk_fma_f32).
__global__ __launch_bounds__(256) void edge_chunk_kernel(
    const u16* __restrict__ Adec, const u16* __restrict__ Bdec,
    const float* __restrict__ d1W, const float* __restrict__ d1b,
    const float* __restrict__ d2W, const float* __restrict__ d2b,
    const int4* __restrict__ meta_t, const float2* __restrict__ attr_t,
    float* __restrict__ out)
{
  int lane = threadIdx.x & 63;
  int ch = (blockIdx.x << 2) + (threadIdx.x >> 6);
  int base = ch * ECHUNK;
  if (base >= NE) return;
  int j0 = lane << 3;

  f32x2 w1a2[4], w1b2[4], bb2[4], w20[4], w21[4], w22[4];
  #pragma unroll
  for (int q = 0; q < 4; ++q){
    int c = j0 + 2*q;
    w1a2[q] = (f32x2){ d1W[(size_t)1024*H + c], d1W[(size_t)1024*H + c + 1] };
    w1b2[q] = (f32x2){ d1W[(size_t)1025*H + c], d1W[(size_t)1025*H + c + 1] };
    bb2[q]  = (f32x2){ d1b[c], d1b[c+1] };
    w20[q]  = (f32x2){ d2W[c*3 + 0], d2W[(c+1)*3 + 0] };
    w21[q]  = (f32x2){ d2W[c*3 + 1], d2W[(c+1)*3 + 1] };
    w22[q]  = (f32x2){ d2W[c*3 + 2], d2W[(c+1)*3 + 2] };
  }
  float ob0 = d2b[0], ob1 = d2b[1], ob2 = d2b[2];

  // lane-held metadata: lane e (<16) owns edge base+e
  int4 mv = make_int4(0,0,0,0);
  float2 av = make_float2(0.f,0.f);
  if (lane < ECHUNK){ mv = meta_t[base + lane]; av = attr_t[base + lane]; }

  int cached_r = -1;
  f32x2 fa2[4];
  auto loadA = [&](int r){
    cached_r = r;
    uint4 va = *(const uint4*)(Adec + (size_t)r*H + j0);
    fa2[0] = pk_add((f32x2){bl16(va.x), bh16(va.x)}, bb2[0]);
    fa2[1] = pk_add((f32x2){bl16(va.y), bh16(va.y)}, bb2[1]);
    fa2[2] = pk_add((f32x2){bl16(va.z), bh16(va.z)}, bb2[2]);
    fa2[3] = pk_add((f32x2){bl16(va.w), bh16(va.w)}, bb2[3]);
  };

  // prologue: 4 B-rows in flight
  uint4 vb[4];
  #pragma unroll
  for (int d = 0; d < 4; ++d){
    int c = __shfl(mv.z, d);
    vb[d] = *(const uint4*)(Bdec + (size_t)c*H + j0);
  }

  #pragma unroll
  for (int i = 0; i < ECHUNK; ++i){
    uint4 vc = vb[i & 3];
    if (i + 4 < ECHUNK){
      int cn = __shfl(mv.z, i + 4);
      vb[i & 3] = *(const uint4*)(Bdec + (size_t)cn*H + j0);
    }
    int e  = __shfl(mv.x, i);
    int r  = __shfl(mv.y, i);
    float a0 = __shfl(av.x, i);
    float a1 = __shfl(av.y, i);
    if (r != cached_r) loadA(r);

    f32x2 a0v = (f32x2){a0, a0}, a1v = (f32x2){a1, a1};
    f32x2 fb[4] = { (f32x2){bl16(vc.x), bh16(vc.x)}, (f32x2){bl16(vc.y), bh16(vc.y)},
                    (f32x2){bl16(vc.z), bh16(vc.z)}, (f32x2){bl16(vc.w), bh16(vc.w)} };
    f32x2 s0 = {0,0}, s1 = {0,0}, s2 = {0,0};
    #pragma unroll
    for (int q = 0; q < 4; ++q){
      f32x2 u = pk_add(fa2[q], fb[q]);
      u = pk_fma(a0v, w1a2[q], u);
      u = pk_fma(a1v, w1b2[q], u);
      u.x = fmaxf(u.x, 0.f); u.y = fmaxf(u.y, 0.f);
      s0 = pk_fma(u, w20[q], s0);
      s1 = pk_fma(u, w21[q], s1);
      s2 = pk_fma(u, w22[q], s2);
    }
    float r0 = s0.x + s0.y, r1 = s1.x + s1.y, r2 = s2.x + s2.y;
    #pragma unroll
    for (int off = 32; off > 0; off >>= 1){
      r0 += __shfl_xor(r0, off);
      r1 += __shfl_xor(r1, off);
      r2 += __shfl_xor(r2, off);
    }
    if (lane == 0){
      out[(size_t)e*3 + 0] = r0 + ob0;
      out[(size_t)e*3 + 1] = r1 + ob1;
      out[(size_t)e*3 + 2] = r2 + ob2;
    }
  }
}

extern "C" void kernel_launch(void* const* d_in, const int* in_sizes, int n_in,
                              void* d_out, int out_size, void* d_ws, size_t ws_size,
                              hipStream_t stream)
{
  const float* x_pol    = (const float*)d_in[0];
  const float* x_stock  = (const float*)d_in[1];
  const float* attr     = (const float*)d_in[2];
  const float* Wp       = (const float*)d_in[3];
  const float* bp       = (const float*)d_in[4];
  const float* Wst      = (const float*)d_in[5];
  const float* bst      = (const float*)d_in[6];
  const float* c1_ps_Wl = (const float*)d_in[7];
  const float* c1_ps_bl = (const float*)d_in[8];
  const float* c1_ps_Wr = (const float*)d_in[9];
  const float* c1_sp_Wl = (const float*)d_in[10];
  const float* c1_sp_bl = (const float*)d_in[11];
  const float* c1_sp_Wr = (const float*)d_in[12];
  const float* c2_ps_Wl = (const float*)d_in[13];
  const float* c2_ps_bl = (const float*)d_in[14];
  const float* c2_ps_Wr = (const float*)d_in[15];
  const float* c2_sp_Wl = (const float*)d_in[16];
  const float* c2_sp_bl = (const float*)d_in[17];
  const float* c2_sp_Wr = (const float*)d_in[18];
  const float* d1W      = (const float*)d_in[19];
  const float* d1b      = (const float*)d_in[20];
  const float* d2W      = (const float*)d_in[21];
  const float* d2b      = (const float*)d_in[22];
  const int* ps_src     = (const int*)d_in[23];
  const int* ps_dst     = (const int*)d_in[24];
  const int* sp_src     = (const int*)d_in[25];
  const int* sp_dst     = (const int*)d_in[26];
  const int* trow       = (const int*)d_in[27];
  const int* tcol       = (const int*)d_in[28];
  float* out = (float*)d_out;

  char* ws = (char*)d_ws;
  size_t off = 0;
  auto alloc = [&](size_t bytes)->char*{
    char* p = ws + off;
    off += (bytes + 255) & ~(size_t)255;
    return p;
  };
  u16* P0 = (u16*)alloc((size_t)NP*H*2);   // hp -> hp2
  u16* P1 = (u16*)alloc((size_t)NP*H*2);   // hp1
  u16* S0 = (u16*)alloc((size_t)NS*H*2);   // hs -> hs2
  u16* S1 = (u16*)alloc((size_t)NS*H*2);   // hs1
  u16* MP = (u16*)alloc((size_t)NP*H*2);   // mean into pol / Adec
  u16* MS = (u16*)alloc((size_t)NS*H*2);   // mean into stock / Bdec
  u16* Wt[10];
  for (int i = 0; i < 10; ++i) Wt[i] = (u16*)alloc((size_t)H*H*2);
  int* cnt_s    = (int*)alloc((size_t)NS*4);      // becomes cursor after scan
  int* cnt_p    = (int*)alloc((size_t)NP*4);
  int* cnt_t    = (int*)alloc((size_t)NP*4);
  int* rowptr_s = (int*)alloc((size_t)(NS+1)*4);
  int* rowptr_p = (int*)alloc((size_t)(NP+1)*4);
  int* rowptr_t = (int*)alloc((size_t)(NP+1)*4);
  int* sorted_ps = (int*)alloc((size_t)NE*4);
  int* sorted_sp = (int*)alloc((size_t)NE*4);
  int4* meta_t   = (int4*)alloc((size_t)NE*16);
  float2* attr_t = (float2*)alloc((size_t)NE*8);
  // pad region so GEMM tile-tail staging reads past last matrix stay in-bounds
  alloc((size_t)128*H*2);

  // weight convert+transpose (independent of everything else)
  TArgs ta;
  ta.m[0] = {c1_ps_Wl, Wt[0]}; ta.m[1] = {c1_ps_Wr, Wt[1]};
  ta.m[2] = {c1_sp_Wl, Wt[2]}; ta.m[3] = {c1_sp_Wr, Wt[3]};
  ta.m[4] = {c2_ps_Wl, Wt[4]}; ta.m[5] = {c2_ps_Wr, Wt[5]};
  ta.m[6] = {c2_sp_Wl, Wt[6]}; ta.m[7] = {c2_sp_Wr, Wt[7]};
  ta.m[8] = {d1W, Wt[8]};                      // d1_W rows 0..511   (pol part)
  ta.m[9] = {d1W + (size_t)512*H, Wt[9]};      // d1_W rows 512..1023 (stock part)
  wtrans_kernel<<<dim3(16,16,10), 256, 0, stream>>>(ta);

  // CSR build (ps->stock, sp->pol, trade->pol)
  hipMemsetAsync(cnt_s, 0, (size_t)NS*4, stream);
  hipMemsetAsync(cnt_p, 0, (size_t)NP*4, stream);
  hipMemsetAsync(cnt_t, 0, (size_t)NP*4, stream);
  hist_kernel<<<(NE+255)/256, 256, 0, stream>>>(ps_dst, sp_dst, trow, cnt_s, cnt_p, cnt_t);
  scan3_kernel<<<3, 1024, 0, stream>>>(cnt_s, NS, rowptr_s, cnt_p, NP, rowptr_p, cnt_t, NP, rowptr_t);
  scatter_kernel<<<(NE+255)/256, 256, 0, stream>>>(ps_src, ps_dst, sp_src, sp_dst, trow, tcol, attr,
                                                   cnt_s, cnt_p, cnt_t,
                                                   sorted_ps, sorted_sp, meta_t, attr_t);

  // input projections
  proj_kernel<<<(NP+7)/8, 256, 0, stream>>>(x_pol, Wp, bp, P0, NP);
  proj_kernel<<<(NS+7)/8, 256, 0, stream>>>(x_stock, Wst, bst, S0, NS);

  int aggGrid = (NS + NP + 3) / 4;
  int gRows = (NP + 127) / 128;   // max rows tiles across paired problems

  // conv1: MS = mean_ps(P0), MP = mean_sp(S0); then paired GEMM
  agg2_kernel<<<aggGrid, 256, 0, stream>>>(P0, rowptr_s, sorted_ps, MS, NS,
                                           S0, rowptr_p, sorted_sp, MP, NP);
  {
    GemmProb a = {MS, Wt[0], S0, Wt[1], c1_ps_bl, S1, NS, 1};
    GemmProb b = {MP, Wt[2], P0, Wt[3], c1_sp_bl, P1, NP, 1};
    gemm_mfma2<<<dim3(4, gRows, 2), 256, 0, stream>>>(a, b);
  }

  // conv2
  agg2_kernel<<<aggGrid, 256, 0, stream>>>(P1, rowptr_s, sorted_ps, MS, NS,
                                           S1, rowptr_p, sorted_sp, MP, NP);
  {
    GemmProb a = {MS, Wt[4], S1, Wt[5], c2_ps_bl, S0, NS, 1};
    GemmProb b = {MP, Wt[6], P1, Wt[7], c2_sp_bl, P0, NP, 1};
    gemm_mfma2<<<dim3(4, gRows, 2), 256, 0, stream>>>(a, b);
  }

  // decoder precompute pair: Adec = hp2 @ d1W[0:512,:], Bdec = hs2 @ d1W[512:1024,:]
  {
    GemmProb a = {P0, Wt[8], nullptr, nullptr, nullptr, MP, NP, 0};
    GemmProb b = {S0, Wt[9], nullptr, nullptr, nullptr, MS, NS, 0};
    gemm_mfma2<<<dim3(4, gRows, 2), 256, 0, stream>>>(a, b);
  }

  // per-edge decoder: one wave per 16-edge chunk of the trade-CSR
  int nchunks = NE / ECHUNK;
  edge_chunk_kernel<<<(nchunks + 3) / 4, 256, 0, stream>>>(MP, MS, d1W, d1b, d2W, d2b,
                                                           meta_t, attr_t, out);
}

// Round 6
// 601.469 us; speedup vs baseline: 2.8103x; 1.0448x over previous
//
#include <hip/hip_runtime.h>
#include <hip/hip_bf16.h>

typedef unsigned short u16;
typedef unsigned int u32;
typedef __attribute__((ext_vector_type(8))) short short8;
typedef __attribute__((ext_vector_type(4))) float f32x4;
typedef __attribute__((ext_vector_type(2))) float f32x2;

#define NP 20000
#define NS 10000
#define NE 400000
#define H  512
#define FDIM 64
#define ECHUNK 16

__device__ __forceinline__ float bl16(u32 w){ return __uint_as_float(w << 16); }
__device__ __forceinline__ float bh16(u32 w){ return __uint_as_float(w & 0xffff0000u); }
__device__ __forceinline__ u16 f2bf(float f){
  u32 u = __float_as_uint(f);
  u32 r = u + 0x7fffu + ((u >> 16) & 1u);
  return (u16)(r >> 16);
}
__device__ __forceinline__ u32 pack2(float a, float b){
  return (u32)f2bf(a) | ((u32)f2bf(b) << 16);
}
__device__ __forceinline__ void gload16(const void* g, void* l){
  __builtin_amdgcn_global_load_lds((const __attribute__((address_space(1))) u32*)g,
                                   (__attribute__((address_space(3))) u32*)l, 16, 0, 0);
}
// packed fp32 (VOP3P, gfx90a+): 2 fma / 2 add per instruction
__device__ __forceinline__ f32x2 pk_fma(f32x2 a, f32x2 b, f32x2 c){
  f32x2 d;
  asm("v_pk_fma_f32 %0, %1, %2, %3" : "=v"(d) : "v"(a), "v"(b), "v"(c));
  return d;
}
__device__ __forceinline__ f32x2 pk_add(f32x2 a, f32x2 b){
  f32x2 d;
  asm("v_pk_add_f32 %0, %1, %2" : "=v"(d) : "v"(a), "v"(b));
  return d;
}

// ---------------- input projection: Y = relu(X @ W + b), X [n,64] f32, W [64,512], Y bf16 ----------------
__global__ __launch_bounds__(256) void proj_kernel(const float* __restrict__ X, const float* __restrict__ W,
                                                   const float* __restrict__ b, u16* __restrict__ Y, int n)
{
  __shared__ float xs[8][FDIM];
  int tid = threadIdx.x;
  int m0 = blockIdx.x * 8;
  {
    int r = tid >> 6, c = tid & 63;
    int m = m0 + r;
    xs[r][c] = (m < n) ? X[(size_t)m*FDIM + c] : 0.f;
    m = m0 + r + 4;
    xs[r+4][c] = (m < n) ? X[(size_t)m*FDIM + c] : 0.f;
  }
  __syncthreads();
  float acc[8][2] = {};
  int c0 = tid, c1 = tid + 256;
  for (int k = 0; k < FDIM; ++k){
    float w0 = W[k*H + c0];
    float w1 = W[k*H + c1];
    #pragma unroll
    for (int r = 0; r < 8; ++r){
      float xv = xs[r][k];
      acc[r][0] = fmaf(xv, w0, acc[r][0]);
      acc[r][1] = fmaf(xv, w1, acc[r][1]);
    }
  }
  float b0 = b[c0], b1 = b[c1];
  #pragma unroll
  for (int r = 0; r < 8; ++r){
    int m = m0 + r;
    if (m < n){
      Y[(size_t)m*H + c0] = f2bf(fmaxf(acc[r][0] + b0, 0.f));
      Y[(size_t)m*H + c1] = f2bf(fmaxf(acc[r][1] + b1, 0.f));
    }
  }
}

// ---------------- weight convert+transpose: Wt[n][k] = bf16(W[k][n]), W [512][512] f32 ----------------
struct TPair { const float* src; u16* dst; };
struct TArgs { TPair m[10]; };

__global__ __launch_bounds__(256) void wtrans_kernel(TArgs args)
{
  __shared__ float lds[32][33];
  int mat = blockIdx.z;
  const float* __restrict__ src = args.m[mat].src;
  u16* __restrict__ dst = args.m[mat].dst;
  int k0 = blockIdx.y << 5, n0 = blockIdx.x << 5;
  int t = threadIdx.x;
  int r = t >> 3, c4 = (t & 7) << 2;
  float4 v = *(const float4*)(src + (size_t)(k0 + r)*H + n0 + c4);
  lds[r][c4+0] = v.x; lds[r][c4+1] = v.y; lds[r][c4+2] = v.z; lds[r][c4+3] = v.w;
  __syncthreads();
  uint2 o;
  o.x = pack2(lds[c4+0][r], lds[c4+1][r]);
  o.y = pack2(lds[c4+2][r], lds[c4+3][r]);
  *(uint2*)(dst + (size_t)(n0 + r)*H + k0 + c4) = o;
}

// ---------------- CSR build (3 relations: ps->s, sp->p, trade->p) ----------------
__global__ void hist_kernel(const int* __restrict__ ps_dst, const int* __restrict__ sp_dst,
                            const int* __restrict__ trow,
                            int* __restrict__ cnt_s, int* __restrict__ cnt_p, int* __restrict__ cnt_t)
{
  int e = blockIdx.x * blockDim.x + threadIdx.x;
  if (e < NE){
    atomicAdd(&cnt_s[ps_dst[e]], 1);
    atomicAdd(&cnt_p[sp_dst[e]], 1);
    atomicAdd(&cnt_t[trow[e]], 1);
  }
}

// in-place exclusive scan via wave-shuffle.
__device__ void scan_one(int* cnt, int n, int* rowptr)
{
  __shared__ int wsum[16];
  __shared__ int carry_s;
  int tid = threadIdx.x;
  int lane = tid & 63, wv = tid >> 6;
  if (tid == 0) carry_s = 0;
  for (int base = 0; base < n; base += 1024){
    __syncthreads();                       // protects carry_s/wsum reuse
    int i = base + tid;
    int v = (i < n) ? cnt[i] : 0;
    int x = v;
    #pragma unroll
    for (int off = 1; off < 64; off <<= 1){
      int t = __shfl_up(x, off);
      if (lane >= off) x += t;
    }
    if (lane == 63) wsum[wv] = x;
    __syncthreads();
    if (wv == 0 && lane < 16){
      int y = wsum[lane];
      #pragma unroll
      for (int off = 1; off < 16; off <<= 1){
        int t = __shfl_up(y, off, 16);
        if (lane >= off) y += t;
      }
      wsum[lane] = y;
    }
    __syncthreads();
    int woff = (wv > 0) ? wsum[wv-1] : 0;
    int cb = carry_s;
    int excl = cb + woff + x - v;
    if (i < n){ rowptr[i] = excl; cnt[i] = excl; }
    __syncthreads();
    if (tid == 1023) carry_s = cb + woff + x;   // running total
  }
  __syncthreads();
  if (tid == 0) rowptr[n] = carry_s;
}

__global__ __launch_bounds__(1024) void scan3_kernel(int* c0, int n0, int* r0,
                                                     int* c1, int n1, int* r1,
                                                     int* c2, int n2, int* r2)
{
  if (blockIdx.x == 0) scan_one(c0, n0, r0);
  else if (blockIdx.x == 1) scan_one(c1, n1, r1);
  else scan_one(c2, n2, r2);
}

// scatter: ps/sp store src index; trade stores PACKED meta {e,row,col} + {a0,a1}
__global__ void scatter_kernel(const int* __restrict__ ps_src, const int* __restrict__ ps_dst,
                               const int* __restrict__ sp_src, const int* __restrict__ sp_dst,
                               const int* __restrict__ trow, const int* __restrict__ tcol,
                               const float* __restrict__ attr,
                               int* __restrict__ cur_s, int* __restrict__ cur_p, int* __restrict__ cur_t,
                               int* __restrict__ sorted_ps, int* __restrict__ sorted_sp,
                               int4* __restrict__ meta_t, float2* __restrict__ attr_t)
{
  int e = blockIdx.x * blockDim.x + threadIdx.x;
  if (e < NE){
    int pos = atomicAdd(&cur_s[ps_dst[e]], 1);
    sorted_ps[pos] = ps_src[e];
    int pos2 = atomicAdd(&cur_p[sp_dst[e]], 1);
    sorted_sp[pos2] = sp_src[e];
    int r = trow[e];
    int pos3 = atomicAdd(&cur_t[r], 1);
    meta_t[pos3] = make_int4(e, r, tcol[e], 0);
    attr_t[pos3] = make_float2(attr[2*e], attr[2*e+1]);
  }
}

// ---------------- paired mean aggregation: one wave per dst row, 8 gathers in flight ----------------
__global__ __launch_bounds__(256) void agg2_kernel(
    const u16* __restrict__ X0, const int* __restrict__ rp0, const int* __restrict__ s0,
    u16* __restrict__ M0, int n0,
    const u16* __restrict__ X1, const int* __restrict__ rp1, const int* __restrict__ s1,
    u16* __restrict__ M1, int n1)
{
  int wid = (blockIdx.x << 2) + (threadIdx.x >> 6);
  int lane = threadIdx.x & 63;
  const u16* X; const int* rp; const int* ss; u16* M; int row;
  if (wid < n0){ X = X0; rp = rp0; ss = s0; M = M0; row = wid; }
  else if (wid < n0 + n1){ X = X1; rp = rp1; ss = s1; M = M1; row = wid - n0; }
  else return;
  int beg = rp[row], end = rp[row + 1];
  f32x2 ac0 = {0,0}, ac1 = {0,0}, ac2 = {0,0}, ac3 = {0,0};
  int j0 = lane << 3;
#define ACCP(v) { ac0 = pk_add(ac0, (f32x2){bl16(v.x), bh16(v.x)}); \
                  ac1 = pk_add(ac1, (f32x2){bl16(v.y), bh16(v.y)}); \
                  ac2 = pk_add(ac2, (f32x2){bl16(v.z), bh16(v.z)}); \
                  ac3 = pk_add(ac3, (f32x2){bl16(v.w), bh16(v.w)}); }
  int i = beg;
  for (; i + 8 <= end; i += 8){
    int sa = ss[i+0], sb = ss[i+1], sc = ss[i+2], sd = ss[i+3];
    int se = ss[i+4], sf = ss[i+5], sg = ss[i+6], sh = ss[i+7];
    uint4 v0 = *(const uint4*)(X + (size_t)sa*H + j0);
    uint4 v1 = *(const uint4*)(X + (size_t)sb*H + j0);
    uint4 v2 = *(const uint4*)(X + (size_t)sc*H + j0);
    uint4 v3 = *(const uint4*)(X + (size_t)sd*H + j0);
    uint4 v4 = *(const uint4*)(X + (size_t)se*H + j0);
    uint4 v5 = *(const uint4*)(X + (size_t)sf*H + j0);
    uint4 v6 = *(const uint4*)(X + (size_t)sg*H + j0);
    uint4 v7 = *(const uint4*)(X + (size_t)sh*H + j0);
    ACCP(v0); ACCP(v1); ACCP(v2); ACCP(v3);
    ACCP(v4); ACCP(v5); ACCP(v6); ACCP(v7);
  }
  for (; i + 2 <= end; i += 2){
    int sa = ss[i], sb = ss[i+1];
    uint4 v0 = *(const uint4*)(X + (size_t)sa*H + j0);
    uint4 v1 = *(const uint4*)(X + (size_t)sb*H + j0);
    ACCP(v0); ACCP(v1);
  }
  if (i < end){
    int sa = ss[i];
    uint4 v0 = *(const uint4*)(X + (size_t)sa*H + j0);
    ACCP(v0);
  }
#undef ACCP
  float inv = 1.f / (float)max(end - beg, 1);
  uint4 o;
  o.x = pack2(ac0.x*inv, ac0.y*inv);
  o.y = pack2(ac1.x*inv, ac1.y*inv);
  o.z = pack2(ac2.x*inv, ac2.y*inv);
  o.w = pack2(ac3.x*inv, ac3.y*inv);
  *(uint4*)(M + (size_t)row*H + j0) = o;
}

// ---------------- 256x256 deep-pipelined MFMA GEMM (T3+T4+T5) ----------------
// C = act(A1@W1t^T [+ A2@W2t^T] [+ bias]); Wt[n][k] = bf16(W[k][n]).
// 512 threads = 8 waves (2M x 4N); per-wave output 128x64 = 8x4 frags of 16x16x32.
// Double-buffered 128 KB LDS; per K-tile(64): issue next tile's 8 global_load_lds,
// s_waitcnt vmcnt(8) (counted, never 0 mid-loop), raw s_barrier, then 4 phases of
// {8 ds_read_b128 + 16 MFMA wrapped in setprio}. XOR-swizzle (chunk^row&7) applied
// to BOTH stage source and LDS reads (rule 21). Staging may read up to 255 rows
// past nrows: sources are ws buffers with adjacent allocations (garbage rows
// computed then masked at C-write).
struct GemmProb {
  const u16* A1; const u16* W1t; const u16* A2; const u16* W2t;
  const float* bias; u16* C; int nrows; int relu;
};

__global__ __launch_bounds__(512) void gemm_mfma256(GemmProb Pa, GemmProb Pb)
{
  GemmProb P = blockIdx.z ? Pb : Pa;
  int m0 = blockIdx.y << 8, n0 = blockIdx.x << 8;
  if (m0 >= P.nrows) return;

  __shared__ u16 lds[2][2][256*64];   // [buf][A/B][rows*k] = 128 KB
  int t = threadIdx.x;
  int w = t >> 6, l = t & 63;
  int wm = w >> 2, wn = w & 3;        // 2 x 4 wave grid
  int lr = l & 15, lg = l >> 4;

  f32x4 acc[8][4];
  #pragma unroll
  for (int i = 0; i < 8; ++i)
    #pragma unroll
    for (int j = 0; j < 4; ++j)
      acc[i][j] = (f32x4){0.f, 0.f, 0.f, 0.f};

  const u16* Asrc0 = P.A1; const u16* Asrc1 = P.A2;
  const u16* Wsrc0 = P.W1t; const u16* Wsrc1 = P.W2t;
  int NT = P.A2 ? 16 : 8;             // K-tiles of 64 (two source phases if A2)

  auto STAGE = [&](int kt, int buf){
    const u16* Ap = (kt < 8) ? Asrc0 : Asrc1;
    const u16* Wp = (kt < 8) ? Wsrc0 : Wsrc1;
    int k0 = (kt & 7) << 6;
    char* AsB = (char*)lds[buf][0];
    char* BsB = (char*)lds[buf][1];
    #pragma unroll
    for (int i = 0; i < 4; ++i){
      int c = i*512 + t;              // 16B chunk index, linear LDS position
      int row = c >> 3, p = c & 7;
      int k8 = p ^ (row & 7);         // inverse-swizzled global chunk
      gload16(Ap + (size_t)(m0 + row)*H + k0 + k8*8, AsB + c*16);
      gload16(Wp + (size_t)(n0 + row)*H + k0 + k8*8, BsB + c*16);
    }
  };

  STAGE(0, 0);
  for (int kt = 0; kt < NT; ++kt){
    int cur = kt & 1;
    if (kt + 1 < NT){
      STAGE(kt + 1, cur ^ 1);
      asm volatile("s_waitcnt vmcnt(8)" ::: "memory");   // cur tile's 8 loads done; next 8 in flight
    } else {
      asm volatile("s_waitcnt vmcnt(0)" ::: "memory");   // epilogue drain
    }
    __builtin_amdgcn_sched_barrier(0);
    __builtin_amdgcn_s_barrier();
    __builtin_amdgcn_sched_barrier(0);
    const char* AsB = (const char*)lds[cur][0];
    const char* BsB = (const char*)lds[cur][1];
    #pragma unroll
    for (int ph = 0; ph < 4; ++ph){
      const int mh = ph & 1, ks = ph >> 1;
      short8 a[4], b[4];
      int kc = (ks << 2) + lg;
      #pragma unroll
      for (int i = 0; i < 4; ++i){
        int r = (wm << 7) + (mh << 6) + (i << 4) + lr;
        a[i] = *(const short8*)(AsB + r*128 + ((kc ^ (r & 7)) << 4));
      }
      #pragma unroll
      for (int nf = 0; nf < 4; ++nf){
        int r = (wn << 6) + (nf << 4) + lr;
        b[nf] = *(const short8*)(BsB + r*128 + ((kc ^ (r & 7)) << 4));
      }
      __builtin_amdgcn_s_setprio(1);
      #pragma unroll
      for (int i = 0; i < 4; ++i)
        #pragma unroll
        for (int nf = 0; nf < 4; ++nf)
          acc[(mh << 2) + i][nf] =
            __builtin_amdgcn_mfma_f32_16x16x32_bf16(a[i], b[nf], acc[(mh << 2) + i][nf], 0, 0, 0);
      __builtin_amdgcn_s_setprio(0);
    }
    asm volatile("" ::: "memory");
    __builtin_amdgcn_s_barrier();     // all waves done reading buf[cur] before it's restaged
    __builtin_amdgcn_sched_barrier(0);
  }

  // epilogue: C/D layout row=(l>>4)*4+j, col=l&15
  float bvn[4];
  #pragma unroll
  for (int nf = 0; nf < 4; ++nf)
    bvn[nf] = P.bias ? P.bias[n0 + (wn << 6) + (nf << 4) + lr] : 0.f;
  #pragma unroll
  for (int mf = 0; mf < 8; ++mf){
    #pragma unroll
    for (int j = 0; j < 4; ++j){
      int m = m0 + (wm << 7) + (mf << 4) + (lg << 2) + j;
      if (m < P.nrows){
        #pragma unroll
        for (int nf = 0; nf < 4; ++nf){
          float v = acc[mf][nf][j] + bvn[nf];
          if (P.relu) v = fmaxf(v, 0.f);
          P.C[(size_t)m*H + n0 + (wn << 6) + (nf << 4) + lr] = f2bf(v);
        }
      }
    }
  }
}

// ---------------- edge decoder: one wave per 16-edge chunk ----------------
// d1b is pre-folded into Adec by the decoder-precompute GEMM bias.
__global__ __launch_bounds__(256) void edge_chunk_kernel(
    const u16* __restrict__ Adec, const u16* __restrict__ Bdec,
    const float* __restrict__ d1W, const float* __restrict__ d2W,
    const float* __restrict__ d2b,
    const int4* __restrict__ meta_t, const float2* __restrict__ attr_t,
    float* __restrict__ out)
{
  int lane = threadIdx.x & 63;
  int ch = (blockIdx.x << 2) + (threadIdx.x >> 6);
  int base = ch * ECHUNK;
  if (base >= NE) return;
  int j0 = lane << 3;

  f32x2 w1a2[4], w1b2[4], w20[4], w21[4], w22[4];
  #pragma unroll
  for (int q = 0; q < 4; ++q){
    int c = j0 + 2*q;
    w1a2[q] = (f32x2){ d1W[(size_t)1024*H + c], d1W[(size_t)1024*H + c + 1] };
    w1b2[q] = (f32x2){ d1W[(size_t)1025*H + c], d1W[(size_t)1025*H + c + 1] };
    w20[q]  = (f32x2){ d2W[c*3 + 0], d2W[(c+1)*3 + 0] };
    w21[q]  = (f32x2){ d2W[c*3 + 1], d2W[(c+1)*3 + 1] };
    w22[q]  = (f32x2){ d2W[c*3 + 2], d2W[(c+1)*3 + 2] };
  }
  float ob0 = d2b[0], ob1 = d2b[1], ob2 = d2b[2];

  // lane-held metadata: lane e (<16) owns edge base+e
  int4 mv = make_int4(0,0,0,0);
  float2 av = make_float2(0.f,0.f);
  if (lane < ECHUNK){ mv = meta_t[base + lane]; av = attr_t[base + lane]; }

  int cached_r = -1;
  f32x2 fa2[4];
  auto loadA = [&](int r){
    cached_r = r;
    uint4 va = *(const uint4*)(Adec + (size_t)r*H + j0);
    fa2[0] = (f32x2){bl16(va.x), bh16(va.x)};
    fa2[1] = (f32x2){bl16(va.y), bh16(va.y)};
    fa2[2] = (f32x2){bl16(va.z), bh16(va.z)};
    fa2[3] = (f32x2){bl16(va.w), bh16(va.w)};
  };

  // prologue: 4 B-rows in flight
  uint4 vb[4];
  #pragma unroll
  for (int d = 0; d < 4; ++d){
    int c = __shfl(mv.z, d);
    vb[d] = *(const uint4*)(Bdec + (size_t)c*H + j0);
  }

  #pragma unroll
  for (int i = 0; i < ECHUNK; ++i){
    uint4 vc = vb[i & 3];
    if (i + 4 < ECHUNK){
      int cn = __shfl(mv.z, i + 4);
      vb[i & 3] = *(const uint4*)(Bdec + (size_t)cn*H + j0);
    }
    int e  = __shfl(mv.x, i);
    int r  = __shfl(mv.y, i);
    float a0 = __shfl(av.x, i);
    float a1 = __shfl(av.y, i);
    if (r != cached_r) loadA(r);

    f32x2 a0v = (f32x2){a0, a0}, a1v = (f32x2){a1, a1};
    f32x2 fb[4] = { (f32x2){bl16(vc.x), bh16(vc.x)}, (f32x2){bl16(vc.y), bh16(vc.y)},
                    (f32x2){bl16(vc.z), bh16(vc.z)}, (f32x2){bl16(vc.w), bh16(vc.w)} };
    f32x2 s0 = {0,0}, s1 = {0,0}, s2 = {0,0};
    #pragma unroll
    for (int q = 0; q < 4; ++q){
      f32x2 u = pk_add(fa2[q], fb[q]);
      u = pk_fma(a0v, w1a2[q], u);
      u = pk_fma(a1v, w1b2[q], u);
      u.x = fmaxf(u.x, 0.f); u.y = fmaxf(u.y, 0.f);
      s0 = pk_fma(u, w20[q], s0);
      s1 = pk_fma(u, w21[q], s1);
      s2 = pk_fma(u, w22[q], s2);
    }
    float r0 = s0.x + s0.y, r1 = s1.x + s1.y, r2 = s2.x + s2.y;
    #pragma unroll
    for (int off = 32; off > 0; off >>= 1){
      r0 += __shfl_xor(r0, off);
      r1 += __shfl_xor(r1, off);
      r2 += __shfl_xor(r2, off);
    }
    if (lane == 0){
      out[(size_t)e*3 + 0] = r0 + ob0;
      out[(size_t)e*3 + 1] = r1 + ob1;
      out[(size_t)e*3 + 2] = r2 + ob2;
    }
  }
}

extern "C" void kernel_launch(void* const* d_in, const int* in_sizes, int n_in,
                              void* d_out, int out_size, void* d_ws, size_t ws_size,
                              hipStream_t stream)
{
  const float* x_pol    = (const float*)d_in[0];
  const float* x_stock  = (const float*)d_in[1];
  const float* attr     = (const float*)d_in[2];
  const float* Wp       = (const float*)d_in[3];
  const float* bp       = (const float*)d_in[4];
  const float* Wst      = (const float*)d_in[5];
  const float* bst      = (const float*)d_in[6];
  const float* c1_ps_Wl = (const float*)d_in[7];
  const float* c1_ps_bl = (const float*)d_in[8];
  const float* c1_ps_Wr = (const float*)d_in[9];
  const float* c1_sp_Wl = (const float*)d_in[10];
  const float* c1_sp_bl = (const float*)d_in[11];
  const float* c1_sp_Wr = (const float*)d_in[12];
  const float* c2_ps_Wl = (const float*)d_in[13];
  const float* c2_ps_bl = (const float*)d_in[14];
  const float* c2_ps_Wr = (const float*)d_in[15];
  const float* c2_sp_Wl = (const float*)d_in[16];
  const float* c2_sp_bl = (const float*)d_in[17];
  const float* c2_sp_Wr = (const float*)d_in[18];
  const float* d1W      = (const float*)d_in[19];
  const float* d1b      = (const float*)d_in[20];
  const float* d2W      = (const float*)d_in[21];
  const float* d2b      = (const float*)d_in[22];
  const int* ps_src     = (const int*)d_in[23];
  const int* ps_dst     = (const int*)d_in[24];
  const int* sp_src     = (const int*)d_in[25];
  const int* sp_dst     = (const int*)d_in[26];
  const int* trow       = (const int*)d_in[27];
  const int* tcol       = (const int*)d_in[28];
  float* out = (float*)d_out;

  char* ws = (char*)d_ws;
  size_t off = 0;
  auto alloc = [&](size_t bytes)->char*{
    char* p = ws + off;
    off += (bytes + 255) & ~(size_t)255;
    return p;
  };
  u16* P0 = (u16*)alloc((size_t)NP*H*2);   // hp -> hp2
  u16* P1 = (u16*)alloc((size_t)NP*H*2);   // hp1
  u16* S0 = (u16*)alloc((size_t)NS*H*2);   // hs -> hs2
  u16* S1 = (u16*)alloc((size_t)NS*H*2);   // hs1
  u16* MP = (u16*)alloc((size_t)NP*H*2);   // mean into pol / Adec
  u16* MS = (u16*)alloc((size_t)NS*H*2);   // mean into stock / Bdec
  u16* Wt[10];
  for (int i = 0; i < 10; ++i) Wt[i] = (u16*)alloc((size_t)H*H*2);
  int* cnt_s    = (int*)alloc((size_t)NS*4);      // becomes cursor after scan
  int* cnt_p    = (int*)alloc((size_t)NP*4);
  int* cnt_t    = (int*)alloc((size_t)NP*4);
  int* rowptr_s = (int*)alloc((size_t)(NS+1)*4);
  int* rowptr_p = (int*)alloc((size_t)(NP+1)*4);
  int* rowptr_t = (int*)alloc((size_t)(NP+1)*4);
  int* sorted_ps = (int*)alloc((size_t)NE*4);
  int* sorted_sp = (int*)alloc((size_t)NE*4);
  int4* meta_t   = (int4*)alloc((size_t)NE*16);
  float2* attr_t = (float2*)alloc((size_t)NE*8);
  // pad region: 256-row tile-tail staging reads past last matrix stay in-bounds
  alloc((size_t)256*H*2);

  // weight convert+transpose (independent of everything else)
  TArgs ta;
  ta.m[0] = {c1_ps_Wl, Wt[0]}; ta.m[1] = {c1_ps_Wr, Wt[1]};
  ta.m[2] = {c1_sp_Wl, Wt[2]}; ta.m[3] = {c1_sp_Wr, Wt[3]};
  ta.m[4] = {c2_ps_Wl, Wt[4]}; ta.m[5] = {c2_ps_Wr, Wt[5]};
  ta.m[6] = {c2_sp_Wl, Wt[6]}; ta.m[7] = {c2_sp_Wr, Wt[7]};
  ta.m[8] = {d1W, Wt[8]};                      // d1_W rows 0..511   (pol part)
  ta.m[9] = {d1W + (size_t)512*H, Wt[9]};      // d1_W rows 512..1023 (stock part)
  wtrans_kernel<<<dim3(16,16,10), 256, 0, stream>>>(ta);

  // CSR build (ps->stock, sp->pol, trade->pol)
  hipMemsetAsync(cnt_s, 0, (size_t)NS*4, stream);
  hipMemsetAsync(cnt_p, 0, (size_t)NP*4, stream);
  hipMemsetAsync(cnt_t, 0, (size_t)NP*4, stream);
  hist_kernel<<<(NE+255)/256, 256, 0, stream>>>(ps_dst, sp_dst, trow, cnt_s, cnt_p, cnt_t);
  scan3_kernel<<<3, 1024, 0, stream>>>(cnt_s, NS, rowptr_s, cnt_p, NP, rowptr_p, cnt_t, NP, rowptr_t);
  scatter_kernel<<<(NE+255)/256, 256, 0, stream>>>(ps_src, ps_dst, sp_src, sp_dst, trow, tcol, attr,
                                                   cnt_s, cnt_p, cnt_t,
                                                   sorted_ps, sorted_sp, meta_t, attr_t);

  // input projections
  proj_kernel<<<(NP+7)/8, 256, 0, stream>>>(x_pol, Wp, bp, P0, NP);
  proj_kernel<<<(NS+7)/8, 256, 0, stream>>>(x_stock, Wst, bst, S0, NS);

  int aggGrid = (NS + NP + 3) / 4;
  int gRows = (NP + 255) / 256;   // max row tiles across paired problems

  // conv1: MS = mean_ps(P0), MP = mean_sp(S0); then paired GEMM
  agg2_kernel<<<aggGrid, 256, 0, stream>>>(P0, rowptr_s, sorted_ps, MS, NS,
                                           S0, rowptr_p, sorted_sp, MP, NP);
  {
    GemmProb a = {MS, Wt[0], S0, Wt[1], c1_ps_bl, S1, NS, 1};
    GemmProb b = {MP, Wt[2], P0, Wt[3], c1_sp_bl, P1, NP, 1};
    gemm_mfma256<<<dim3(2, gRows, 2), 512, 0, stream>>>(a, b);
  }

  // conv2
  agg2_kernel<<<aggGrid, 256, 0, stream>>>(P1, rowptr_s, sorted_ps, MS, NS,
                                           S1, rowptr_p, sorted_sp, MP, NP);
  {
    GemmProb a = {MS, Wt[4], S1, Wt[5], c2_ps_bl, S0, NS, 1};
    GemmProb b = {MP, Wt[6], P1, Wt[7], c2_sp_bl, P0, NP, 1};
    gemm_mfma256<<<dim3(2, gRows, 2), 512, 0, stream>>>(a, b);
  }

  // decoder precompute pair: Adec = hp2 @ d1W[0:512,:] + d1b (bias folded), Bdec = hs2 @ d1W[512:1024,:]
  {
    GemmProb a = {P0, Wt[8], nullptr, nullptr, d1b, MP, NP, 0};
    GemmProb b = {S0, Wt[9], nullptr, nullptr, nullptr, MS, NS, 0};
    gemm_mfma256<<<dim3(2, gRows, 2), 512, 0, stream>>>(a, b);
  }

  // per-edge decoder: one wave per 16-edge chunk of the trade-CSR
  int nchunks = NE / ECHUNK;
  edge_chunk_kernel<<<(nchunks + 3) / 4, 256, 0, stream>>>(MP, MS, d1W, d2W, d2b,
                                                           meta_t, attr_t, out);
}

// Round 10
// 580.409 us; speedup vs baseline: 2.9123x; 1.0363x over previous
//
#include <hip/hip_runtime.h>
#include <hip/hip_bf16.h>

typedef unsigned short u16;
typedef unsigned int u32;
typedef __attribute__((ext_vector_type(8))) short short8;
typedef __attribute__((ext_vector_type(4))) float f32x4;
typedef __attribute__((ext_vector_type(2))) float f32x2;

#define NP 20000
#define NS 10000
#define NE 400000
#define H  512
#define FDIM 64
#define ECHUNK 16

__device__ __forceinline__ float bl16(u32 w){ return __uint_as_float(w << 16); }
__device__ __forceinline__ float bh16(u32 w){ return __uint_as_float(w & 0xffff0000u); }
__device__ __forceinline__ u16 f2bf(float f){
  u32 u = __float_as_uint(f);
  u32 r = u + 0x7fffu + ((u >> 16) & 1u);
  return (u16)(r >> 16);
}
__device__ __forceinline__ u32 pack2(float a, float b){
  return (u32)f2bf(a) | ((u32)f2bf(b) << 16);
}
__device__ __forceinline__ void gload16(const void* g, void* l){
  __builtin_amdgcn_global_load_lds((const __attribute__((address_space(1))) u32*)g,
                                   (__attribute__((address_space(3))) u32*)l, 16, 0, 0);
}
// packed fp32 (VOP3P, gfx90a+): 2 fma / 2 add per instruction
__device__ __forceinline__ f32x2 pk_fma(f32x2 a, f32x2 b, f32x2 c){
  f32x2 d;
  asm("v_pk_fma_f32 %0, %1, %2, %3" : "=v"(d) : "v"(a), "v"(b), "v"(c));
  return d;
}
__device__ __forceinline__ f32x2 pk_add(f32x2 a, f32x2 b){
  f32x2 d;
  asm("v_pk_add_f32 %0, %1, %2" : "=v"(d) : "v"(a), "v"(b));
  return d;
}

// ---------------- input projection: Y = relu(X @ W + b), X [n,64] f32, W [64,512], Y bf16 ----------------
__global__ __launch_bounds__(256) void proj_kernel(const float* __restrict__ X, const float* __restrict__ W,
                                                   const float* __restrict__ b, u16* __restrict__ Y, int n)
{
  __shared__ float xs[8][FDIM];
  int tid = threadIdx.x;
  int m0 = blockIdx.x * 8;
  {
    int r = tid >> 6, c = tid & 63;
    int m = m0 + r;
    xs[r][c] = (m < n) ? X[(size_t)m*FDIM + c] : 0.f;
    m = m0 + r + 4;
    xs[r+4][c] = (m < n) ? X[(size_t)m*FDIM + c] : 0.f;
  }
  __syncthreads();
  float acc[8][2] = {};
  int c0 = tid, c1 = tid + 256;
  for (int k = 0; k < FDIM; ++k){
    float w0 = W[k*H + c0];
    float w1 = W[k*H + c1];
    #pragma unroll
    for (int r = 0; r < 8; ++r){
      float xv = xs[r][k];
      acc[r][0] = fmaf(xv, w0, acc[r][0]);
      acc[r][1] = fmaf(xv, w1, acc[r][1]);
    }
  }
  float b0 = b[c0], b1 = b[c1];
  #pragma unroll
  for (int r = 0; r < 8; ++r){
    int m = m0 + r;
    if (m < n){
      Y[(size_t)m*H + c0] = f2bf(fmaxf(acc[r][0] + b0, 0.f));
      Y[(size_t)m*H + c1] = f2bf(fmaxf(acc[r][1] + b1, 0.f));
    }
  }
}

// ---------------- weight convert+transpose: Wt[n][k] = bf16(W[k][n]), W [512][512] f32 ----------------
struct TPair { const float* src; u16* dst; };
struct TArgs { TPair m[10]; };

__global__ __launch_bounds__(256) void wtrans_kernel(TArgs args)
{
  __shared__ float lds[32][33];
  int mat = blockIdx.z;
  const float* __restrict__ src = args.m[mat].src;
  u16* __restrict__ dst = args.m[mat].dst;
  int k0 = blockIdx.y << 5, n0 = blockIdx.x << 5;
  int t = threadIdx.x;
  int r = t >> 3, c4 = (t & 7) << 2;
  float4 v = *(const float4*)(src + (size_t)(k0 + r)*H + n0 + c4);
  lds[r][c4+0] = v.x; lds[r][c4+1] = v.y; lds[r][c4+2] = v.z; lds[r][c4+3] = v.w;
  __syncthreads();
  uint2 o;
  o.x = pack2(lds[c4+0][r], lds[c4+1][r]);
  o.y = pack2(lds[c4+2][r], lds[c4+3][r]);
  *(uint2*)(dst + (size_t)(n0 + r)*H + k0 + c4) = o;
}

// ---------------- W2 B-fragment precompute (bf16): w2f[ks*64+l] = W2[ks*32+(l>>4)*8 .. +7][l&15] ----------------
__global__ __launch_bounds__(256) void w2frag_kernel(const float* __restrict__ d2W, uint4* __restrict__ w2f)
{
  int tid = blockIdx.x*256 + threadIdx.x;   // [0,1024)
  int l = tid & 63;
  int col = l & 15, g = l >> 4;
  int k = (tid >> 6)*32 + g*8;
  float v[8];
  #pragma unroll
  for (int j = 0; j < 8; ++j)
    v[j] = (col < 3) ? d2W[(size_t)(k+j)*3 + col] : 0.f;
  uint4 o;
  o.x = pack2(v[0], v[1]); o.y = pack2(v[2], v[3]);
  o.z = pack2(v[4], v[5]); o.w = pack2(v[6], v[7]);
  w2f[tid] = o;
}

// ---------------- CSR build (3 relations: ps->s, sp->p, trade->p) ----------------
__global__ void hist_kernel(const int* __restrict__ ps_dst, const int* __restrict__ sp_dst,
                            const int* __restrict__ trow,
                            int* __restrict__ cnt_s, int* __restrict__ cnt_p, int* __restrict__ cnt_t)
{
  int e = blockIdx.x * blockDim.x + threadIdx.x;
  if (e < NE){
    atomicAdd(&cnt_s[ps_dst[e]], 1);
    atomicAdd(&cnt_p[sp_dst[e]], 1);
    atomicAdd(&cnt_t[trow[e]], 1);
  }
}

// in-place exclusive scan via wave-shuffle.
__device__ void scan_one(int* cnt, int n, int* rowptr)
{
  __shared__ int wsum[16];
  __shared__ int carry_s;
  int tid = threadIdx.x;
  int lane = tid & 63, wv = tid >> 6;
  if (tid == 0) carry_s = 0;
  for (int base = 0; base < n; base += 1024){
    __syncthreads();                       // protects carry_s/wsum reuse
    int i = base + tid;
    int v = (i < n) ? cnt[i] : 0;
    int x = v;
    #pragma unroll
    for (int off = 1; off < 64; off <<= 1){
      int t = __shfl_up(x, off);
      if (lane >= off) x += t;
    }
    if (lane == 63) wsum[wv] = x;
    __syncthreads();
    if (wv == 0 && lane < 16){
      int y = wsum[lane];
      #pragma unroll
      for (int off = 1; off < 16; off <<= 1){
        int t = __shfl_up(y, off, 16);
        if (lane >= off) y += t;
      }
      wsum[lane] = y;
    }
    __syncthreads();
    int woff = (wv > 0) ? wsum[wv-1] : 0;
    int cb = carry_s;
    int excl = cb + woff + x - v;
    if (i < n){ rowptr[i] = excl; cnt[i] = excl; }
    __syncthreads();
    if (tid == 1023) carry_s = cb + woff + x;   // running total
  }
  __syncthreads();
  if (tid == 0) rowptr[n] = carry_s;
}

__global__ __launch_bounds__(1024) void scan3_kernel(int* c0, int n0, int* r0,
                                                     int* c1, int n1, int* r1,
                                                     int* c2, int n2, int* r2)
{
  if (blockIdx.x == 0) scan_one(c0, n0, r0);
  else if (blockIdx.x == 1) scan_one(c1, n1, r1);
  else scan_one(c2, n2, r2);
}

// scatter: ps/sp store src index; trade stores PACKED meta {e,row,col} + {a0,a1}
__global__ void scatter_kernel(const int* __restrict__ ps_src, const int* __restrict__ ps_dst,
                               const int* __restrict__ sp_src, const int* __restrict__ sp_dst,
                               const int* __restrict__ trow, const int* __restrict__ tcol,
                               const float* __restrict__ attr,
                               int* __restrict__ cur_s, int* __restrict__ cur_p, int* __restrict__ cur_t,
                               int* __restrict__ sorted_ps, int* __restrict__ sorted_sp,
                               int4* __restrict__ meta_t, float2* __restrict__ attr_t)
{
  int e = blockIdx.x * blockDim.x + threadIdx.x;
  if (e < NE){
    int pos = atomicAdd(&cur_s[ps_dst[e]], 1);
    sorted_ps[pos] = ps_src[e];
    int pos2 = atomicAdd(&cur_p[sp_dst[e]], 1);
    sorted_sp[pos2] = sp_src[e];
    int r = trow[e];
    int pos3 = atomicAdd(&cur_t[r], 1);
    meta_t[pos3] = make_int4(e, r, tcol[e], 0);
    attr_t[pos3] = make_float2(attr[2*e], attr[2*e+1]);
  }
}

// ---------------- paired mean aggregation: one wave per dst row, 8 gathers in flight ----------------
__global__ __launch_bounds__(256) void agg2_kernel(
    const u16* __restrict__ X0, const int* __restrict__ rp0, const int* __restrict__ s0,
    u16* __restrict__ M0, int n0,
    const u16* __restrict__ X1, const int* __restrict__ rp1, const int* __restrict__ s1,
    u16* __restrict__ M1, int n1)
{
  int wid = (blockIdx.x << 2) + (threadIdx.x >> 6);
  int lane = threadIdx.x & 63;
  const u16* X; const int* rp; const int* ss; u16* M; int row;
  if (wid < n0){ X = X0; rp = rp0; ss = s0; M = M0; row = wid; }
  else if (wid < n0 + n1){ X = X1; rp = rp1; ss = s1; M = M1; row = wid - n0; }
  else return;
  int beg = rp[row], end = rp[row + 1];
  f32x2 ac0 = {0,0}, ac1 = {0,0}, ac2 = {0,0}, ac3 = {0,0};
  int j0 = lane << 3;
#define ACCP(v) { ac0 = pk_add(ac0, (f32x2){bl16(v.x), bh16(v.x)}); \
                  ac1 = pk_add(ac1, (f32x2){bl16(v.y), bh16(v.y)}); \
                  ac2 = pk_add(ac2, (f32x2){bl16(v.z), bh16(v.z)}); \
                  ac3 = pk_add(ac3, (f32x2){bl16(v.w), bh16(v.w)}); }
  int i = beg;
  for (; i + 8 <= end; i += 8){
    int sa = ss[i+0], sb = ss[i+1], sc = ss[i+2], sd = ss[i+3];
    int se = ss[i+4], sf = ss[i+5], sg = ss[i+6], sh = ss[i+7];
    uint4 v0 = *(const uint4*)(X + (size_t)sa*H + j0);
    uint4 v1 = *(const uint4*)(X + (size_t)sb*H + j0);
    uint4 v2 = *(const uint4*)(X + (size_t)sc*H + j0);
    uint4 v3 = *(const uint4*)(X + (size_t)sd*H + j0);
    uint4 v4 = *(const uint4*)(X + (size_t)se*H + j0);
    uint4 v5 = *(const uint4*)(X + (size_t)sf*H + j0);
    uint4 v6 = *(const uint4*)(X + (size_t)sg*H + j0);
    uint4 v7 = *(const uint4*)(X + (size_t)sh*H + j0);
    ACCP(v0); ACCP(v1); ACCP(v2); ACCP(v3);
    ACCP(v4); ACCP(v5); ACCP(v6); ACCP(v7);
  }
  for (; i + 2 <= end; i += 2){
    int sa = ss[i], sb = ss[i+1];
    uint4 v0 = *(const uint4*)(X + (size_t)sa*H + j0);
    uint4 v1 = *(const uint4*)(X + (size_t)sb*H + j0);
    ACCP(v0); ACCP(v1);
  }
  if (i < end){
    int sa = ss[i];
    uint4 v0 = *(const uint4*)(X + (size_t)sa*H + j0);
    ACCP(v0);
  }
#undef ACCP
  float inv = 1.f / (float)max(end - beg, 1);
  uint4 o;
  o.x = pack2(ac0.x*inv, ac0.y*inv);
  o.y = pack2(ac1.x*inv, ac1.y*inv);
  o.z = pack2(ac2.x*inv, ac2.y*inv);
  o.w = pack2(ac3.x*inv, ac3.y*inv);
  *(uint4*)(M + (size_t)row*H + j0) = o;
}

// ---------------- 256x256 deep-pipelined MFMA GEMM (T3+T4+T5) — R6-proven ----------------
struct GemmProb {
  const u16* A1; const u16* W1t; const u16* A2; const u16* W2t;
  const float* bias; u16* C; int nrows; int relu;
};

__global__ __launch_bounds__(512) void gemm_mfma256(GemmProb Pa, GemmProb Pb)
{
  GemmProb P = blockIdx.z ? Pb : Pa;
  int m0 = blockIdx.y << 8, n0 = blockIdx.x << 8;
  if (m0 >= P.nrows) return;

  __shared__ u16 lds[2][2][256*64];   // [buf][A/B][rows*k] = 128 KB
  int t = threadIdx.x;
  int w = t >> 6, l = t & 63;
  int wm = w >> 2, wn = w & 3;        // 2 x 4 wave grid
  int lr = l & 15, lg = l >> 4;

  f32x4 acc[8][4];
  #pragma unroll
  for (int i = 0; i < 8; ++i)
    #pragma unroll
    for (int j = 0; j < 4; ++j)
      acc[i][j] = (f32x4){0.f, 0.f, 0.f, 0.f};

  const u16* Asrc0 = P.A1; const u16* Asrc1 = P.A2;
  const u16* Wsrc0 = P.W1t; const u16* Wsrc1 = P.W2t;
  int NT = P.A2 ? 16 : 8;

  auto STAGE = [&](int kt, int buf){
    const u16* Ap = (kt < 8) ? Asrc0 : Asrc1;
    const u16* Wp = (kt < 8) ? Wsrc0 : Wsrc1;
    int k0 = (kt & 7) << 6;
    char* AsB = (char*)lds[buf][0];
    char* BsB = (char*)lds[buf][1];
    #pragma unroll
    for (int i = 0; i < 4; ++i){
      int c = i*512 + t;
      int row = c >> 3, p = c & 7;
      int k8 = p ^ (row & 7);
      gload16(Ap + (size_t)(m0 + row)*H + k0 + k8*8, AsB + c*16);
      gload16(Wp + (size_t)(n0 + row)*H + k0 + k8*8, BsB + c*16);
    }
  };

  STAGE(0, 0);
  for (int kt = 0; kt < NT; ++kt){
    int cur = kt & 1;
    if (kt + 1 < NT){
      STAGE(kt + 1, cur ^ 1);
      asm volatile("s_waitcnt vmcnt(8)" ::: "memory");
    } else {
      asm volatile("s_waitcnt vmcnt(0)" ::: "memory");
    }
    __builtin_amdgcn_sched_barrier(0);
    __builtin_amdgcn_s_barrier();
    __builtin_amdgcn_sched_barrier(0);
    const char* AsB = (const char*)lds[cur][0];
    const char* BsB = (const char*)lds[cur][1];
    #pragma unroll
    for (int ph = 0; ph < 4; ++ph){
      const int mh = ph & 1, ks = ph >> 1;
      short8 a[4], b[4];
      int kc = (ks << 2) + lg;
      #pragma unroll
      for (int i = 0; i < 4; ++i){
        int r = (wm << 7) + (mh << 6) + (i << 4) + lr;
        a[i] = *(const short8*)(AsB + r*128 + ((kc ^ (r & 7)) << 4));
      }
      #pragma unroll
      for (int nf = 0; nf < 4; ++nf){
        int r = (wn << 6) + (nf << 4) + lr;
        b[nf] = *(const short8*)(BsB + r*128 + ((kc ^ (r & 7)) << 4));
      }
      __builtin_amdgcn_s_setprio(1);
      #pragma unroll
      for (int i = 0; i < 4; ++i)
        #pragma unroll
        for (int nf = 0; nf < 4; ++nf)
          acc[(mh << 2) + i][nf] =
            __builtin_amdgcn_mfma_f32_16x16x32_bf16(a[i], b[nf], acc[(mh << 2) + i][nf], 0, 0, 0);
      __builtin_amdgcn_s_setprio(0);
    }
    asm volatile("" ::: "memory");
    __builtin_amdgcn_s_barrier();
    __builtin_amdgcn_sched_barrier(0);
  }

  float bvn[4];
  #pragma unroll
  for (int nf = 0; nf < 4; ++nf)
    bvn[nf] = P.bias ? P.bias[n0 + (wn << 6) + (nf << 4) + lr] : 0.f;
  #pragma unroll
  for (int mf = 0; mf < 8; ++mf){
    #pragma unroll
    for (int j = 0; j < 4; ++j){
      int m = m0 + (wm << 7) + (mf << 4) + (lg << 2) + j;
      if (m < P.nrows){
        #pragma unroll
        for (int nf = 0; nf < 4; ++nf){
          float v = acc[mf][nf][j] + bvn[nf];
          if (P.relu) v = fmaxf(v, 0.f);
          P.C[(size_t)m*H + n0 + (wn << 6) + (nf << 4) + lr] = f2bf(v);
        }
      }
    }
  }
}

// ---------------- edge decoder via bf16 MFMA: one wave per 16-edge chunk ----------------
// lane l -> (edge er=l&15, channel-group g=l>>4). Per K-slice ks (32 channels):
// lane computes h[er][ks*32+g*8 .. +7] = relu(A[p]+B[c]+a0*w1a+a1*w1b) in f32
// packed math, packs to bf16 = the mfma_f32_16x16x32_bf16 A-fragment in place.
// B-fragment = precomputed bf16 W2 frags (LDS). D: row=edge=(l>>4)*4+j, col=class=l&15.
// FIX (R9 bug): edge-index shuffles hoisted OUT of the divergent writer branch —
// __shfl from an EXEC-disabled source lane is undefined (G5).
__global__ __launch_bounds__(256) void edge_mfma_kernel(
    const u16* __restrict__ Adec, const u16* __restrict__ Bdec,   // bf16, d1b folded into Adec
    const uint4* __restrict__ w2f, const float* __restrict__ d1W,
    const float* __restrict__ d2b,
    const int4* __restrict__ meta_t, const float2* __restrict__ attr_t,
    float* __restrict__ out)
{
  __shared__ uint4 w2s[16*64];      // 16 KB: bf16 W2 B-fragments per slice
  __shared__ float w1s[2][H];       // 4 KB: d1W rows 1024 (attr0) / 1025 (attr1)
  int t = threadIdx.x;
  #pragma unroll
  for (int i = 0; i < 4; ++i)
    w2s[i*256 + t] = w2f[i*256 + t];
  ((float4*)w1s)[t] = ((const float4*)(d1W + (size_t)1024*H))[t];   // 1024 consecutive floats
  __syncthreads();

  int lane = t & 63;
  int ch = (blockIdx.x << 2) + (t >> 6);
  int base = ch * ECHUNK;
  if (base >= NE) return;
  int er = lane & 15, g = lane >> 4;

  // lane-held metadata: lane i (<16) owns edge base+i; broadcasts below are uniform-flow
  int4 mv = make_int4(0,0,0,0);
  float2 av = make_float2(0.f,0.f);
  if (lane < ECHUNK){ mv = meta_t[base + lane]; av = attr_t[base + lane]; }
  int p = __shfl(mv.y, er);
  int c = __shfl(mv.z, er);
  float a0 = __shfl(av.x, er);
  float a1 = __shfl(av.y, er);
  f32x2 a0v = {a0, a0}, a1v = {a1, a1};

  const u16* Arow = Adec + (size_t)p*H + g*8;
  const u16* Brow = Bdec + (size_t)c*H + g*8;

  f32x4 acc = {0.f, 0.f, 0.f, 0.f};
  #pragma unroll
  for (int ks = 0; ks < 16; ++ks){
    uint4 va = *(const uint4*)(Arow + ks*32);
    uint4 vb = *(const uint4*)(Brow + ks*32);
    const float* wa = &w1s[0][ks*32 + g*8];
    const float* wb = &w1s[1][ks*32 + g*8];
    float4 wa0 = *(const float4*)(wa);
    float4 wa1 = *(const float4*)(wa + 4);
    float4 wb0 = *(const float4*)(wb);
    float4 wb1 = *(const float4*)(wb + 4);
    f32x2 h0 = pk_add((f32x2){bl16(va.x), bh16(va.x)}, (f32x2){bl16(vb.x), bh16(vb.x)});
    f32x2 h1 = pk_add((f32x2){bl16(va.y), bh16(va.y)}, (f32x2){bl16(vb.y), bh16(vb.y)});
    f32x2 h2 = pk_add((f32x2){bl16(va.z), bh16(va.z)}, (f32x2){bl16(vb.z), bh16(vb.z)});
    f32x2 h3 = pk_add((f32x2){bl16(va.w), bh16(va.w)}, (f32x2){bl16(vb.w), bh16(vb.w)});
    h0 = pk_fma(a0v, (f32x2){wa0.x, wa0.y}, h0);
    h1 = pk_fma(a0v, (f32x2){wa0.z, wa0.w}, h1);
    h2 = pk_fma(a0v, (f32x2){wa1.x, wa1.y}, h2);
    h3 = pk_fma(a0v, (f32x2){wa1.z, wa1.w}, h3);
    h0 = pk_fma(a1v, (f32x2){wb0.x, wb0.y}, h0);
    h1 = pk_fma(a1v, (f32x2){wb0.z, wb0.w}, h1);
    h2 = pk_fma(a1v, (f32x2){wb1.x, wb1.y}, h2);
    h3 = pk_fma(a1v, (f32x2){wb1.z, wb1.w}, h3);
    uint4 hh;
    hh.x = pack2(fmaxf(h0.x, 0.f), fmaxf(h0.y, 0.f));
    hh.y = pack2(fmaxf(h1.x, 0.f), fmaxf(h1.y, 0.f));
    hh.z = pack2(fmaxf(h2.x, 0.f), fmaxf(h2.y, 0.f));
    hh.w = pack2(fmaxf(h3.x, 0.f), fmaxf(h3.y, 0.f));
    short8 pa = __builtin_bit_cast(short8, hh);
    short8 pb = __builtin_bit_cast(short8, w2s[ks*64 + lane]);
    acc = __builtin_amdgcn_mfma_f32_16x16x32_bf16(pa, pb, acc, 0, 0, 0);
  }

  // edge-index broadcasts in UNIFORM control flow (all 64 lanes active)
  int ebc[4];
  #pragma unroll
  for (int j = 0; j < 4; ++j)
    ebc[j] = __shfl(mv.x, (g << 2) + j);

  int col = lane & 15;
  if (col < 3){
    float ob = d2b[col];
    #pragma unroll
    for (int j = 0; j < 4; ++j)
      out[(size_t)ebc[j]*3 + col] = acc[j] + ob;
  }
}

extern "C" void kernel_launch(void* const* d_in, const int* in_sizes, int n_in,
                              void* d_out, int out_size, void* d_ws, size_t ws_size,
                              hipStream_t stream)
{
  const float* x_pol    = (const float*)d_in[0];
  const float* x_stock  = (const float*)d_in[1];
  const float* attr     = (const float*)d_in[2];
  const float* Wp       = (const float*)d_in[3];
  const float* bp       = (const float*)d_in[4];
  const float* Wst      = (const float*)d_in[5];
  const float* bst      = (const float*)d_in[6];
  const float* c1_ps_Wl = (const float*)d_in[7];
  const float* c1_ps_bl = (const float*)d_in[8];
  const float* c1_ps_Wr = (const float*)d_in[9];
  const float* c1_sp_Wl = (const float*)d_in[10];
  const float* c1_sp_bl = (const float*)d_in[11];
  const float* c1_sp_Wr = (const float*)d_in[12];
  const float* c2_ps_Wl = (const float*)d_in[13];
  const float* c2_ps_bl = (const float*)d_in[14];
  const float* c2_ps_Wr = (const float*)d_in[15];
  const float* c2_sp_Wl = (const float*)d_in[16];
  const float* c2_sp_bl = (const float*)d_in[17];
  const float* c2_sp_Wr = (const float*)d_in[18];
  const float* d1W      = (const float*)d_in[19];
  const float* d1b      = (const float*)d_in[20];
  const float* d2W      = (const float*)d_in[21];
  const float* d2b      = (const float*)d_in[22];
  const int* ps_src     = (const int*)d_in[23];
  const int* ps_dst     = (const int*)d_in[24];
  const int* sp_src     = (const int*)d_in[25];
  const int* sp_dst     = (const int*)d_in[26];
  const int* trow       = (const int*)d_in[27];
  const int* tcol       = (const int*)d_in[28];
  float* out = (float*)d_out;

  char* ws = (char*)d_ws;
  size_t off = 0;
  auto alloc = [&](size_t bytes)->char*{
    char* p = ws + off;
    off += (bytes + 255) & ~(size_t)255;
    return p;
  };
  u16* P0 = (u16*)alloc((size_t)NP*H*2);   // hp -> hp2
  u16* P1 = (u16*)alloc((size_t)NP*H*2);   // hp1
  u16* S0 = (u16*)alloc((size_t)NS*H*2);   // hs -> hs2
  u16* S1 = (u16*)alloc((size_t)NS*H*2);   // hs1
  u16* MP = (u16*)alloc((size_t)NP*H*2);   // mean into pol / Adec
  u16* MS = (u16*)alloc((size_t)NS*H*2);   // mean into stock / Bdec
  u16* Wt[10];
  for (int i = 0; i < 10; ++i) Wt[i] = (u16*)alloc((size_t)H*H*2);
  int* cnt_s    = (int*)alloc((size_t)NS*4);      // becomes cursor after scan
  int* cnt_p    = (int*)alloc((size_t)NP*4);
  int* cnt_t    = (int*)alloc((size_t)NP*4);
  int* rowptr_s = (int*)alloc((size_t)(NS+1)*4);
  int* rowptr_p = (int*)alloc((size_t)(NP+1)*4);
  int* rowptr_t = (int*)alloc((size_t)(NP+1)*4);
  int* sorted_ps = (int*)alloc((size_t)NE*4);
  int* sorted_sp = (int*)alloc((size_t)NE*4);
  int4* meta_t   = (int4*)alloc((size_t)NE*16);
  float2* attr_t = (float2*)alloc((size_t)NE*8);
  uint4* w2f     = (uint4*)alloc((size_t)16*64*16);
  // pad region: 256-row tile-tail staging reads past last matrix stay in-bounds
  alloc((size_t)256*H*2);

  // weight convert+transpose (independent of everything else)
  TArgs ta;
  ta.m[0] = {c1_ps_Wl, Wt[0]}; ta.m[1] = {c1_ps_Wr, Wt[1]};
  ta.m[2] = {c1_sp_Wl, Wt[2]}; ta.m[3] = {c1_sp_Wr, Wt[3]};
  ta.m[4] = {c2_ps_Wl, Wt[4]}; ta.m[5] = {c2_ps_Wr, Wt[5]};
  ta.m[6] = {c2_sp_Wl, Wt[6]}; ta.m[7] = {c2_sp_Wr, Wt[7]};
  ta.m[8] = {d1W, Wt[8]};                      // d1_W rows 0..511   (pol part)
  ta.m[9] = {d1W + (size_t)512*H, Wt[9]};      // d1_W rows 512..1023 (stock part)
  wtrans_kernel<<<dim3(16,16,10), 256, 0, stream>>>(ta);
  w2frag_kernel<<<4, 256, 0, stream>>>(d2W, w2f);

  // CSR build (ps->stock, sp->pol, trade->pol)
  hipMemsetAsync(cnt_s, 0, (size_t)NS*4, stream);
  hipMemsetAsync(cnt_p, 0, (size_t)NP*4, stream);
  hipMemsetAsync(cnt_t, 0, (size_t)NP*4, stream);
  hist_kernel<<<(NE+255)/256, 256, 0, stream>>>(ps_dst, sp_dst, trow, cnt_s, cnt_p, cnt_t);
  scan3_kernel<<<3, 1024, 0, stream>>>(cnt_s, NS, rowptr_s, cnt_p, NP, rowptr_p, cnt_t, NP, rowptr_t);
  scatter_kernel<<<(NE+255)/256, 256, 0, stream>>>(ps_src, ps_dst, sp_src, sp_dst, trow, tcol, attr,
                                                   cnt_s, cnt_p, cnt_t,
                                                   sorted_ps, sorted_sp, meta_t, attr_t);

  // input projections
  proj_kernel<<<(NP+7)/8, 256, 0, stream>>>(x_pol, Wp, bp, P0, NP);
  proj_kernel<<<(NS+7)/8, 256, 0, stream>>>(x_stock, Wst, bst, S0, NS);

  int aggGrid = (NS + NP + 3) / 4;
  int gRows = (NP + 255) / 256;   // max row tiles across paired problems

  // conv1: MS = mean_ps(P0), MP = mean_sp(S0); then paired GEMM
  agg2_kernel<<<aggGrid, 256, 0, stream>>>(P0, rowptr_s, sorted_ps, MS, NS,
                                           S0, rowptr_p, sorted_sp, MP, NP);
  {
    GemmProb a = {MS, Wt[0], S0, Wt[1], c1_ps_bl, S1, NS, 1};
    GemmProb b = {MP, Wt[2], P0, Wt[3], c1_sp_bl, P1, NP, 1};
    gemm_mfma256<<<dim3(2, gRows, 2), 512, 0, stream>>>(a, b);
  }

  // conv2
  agg2_kernel<<<aggGrid, 256, 0, stream>>>(P1, rowptr_s, sorted_ps, MS, NS,
                                           S1, rowptr_p, sorted_sp, MP, NP);
  {
    GemmProb a = {MS, Wt[4], S1, Wt[5], c2_ps_bl, S0, NS, 1};
    GemmProb b = {MP, Wt[6], P1, Wt[7], c2_sp_bl, P0, NP, 1};
    gemm_mfma256<<<dim3(2, gRows, 2), 512, 0, stream>>>(a, b);
  }

  // decoder precompute pair: Adec = hp2 @ d1W[0:512,:] + d1b (bias folded), Bdec = hs2 @ d1W[512:1024,:]
  {
    GemmProb a = {P0, Wt[8], nullptr, nullptr, d1b, MP, NP, 0};
    GemmProb b = {S0, Wt[9], nullptr, nullptr, nullptr, MS, NS, 0};
    gemm_mfma256<<<dim3(2, gRows, 2), 512, 0, stream>>>(a, b);
  }

  // edge decoder (bf16 MFMA): one wave per 16-edge chunk
  int nchunks = NE / ECHUNK;
  edge_mfma_kernel<<<(nchunks + 3) / 4, 256, 0, stream>>>(MP, MS, w2f, d1W, d2b,
                                                          meta_t, attr_t, out);
}

// Round 11
// 561.072 us; speedup vs baseline: 3.0127x; 1.0345x over previous
//
#include <hip/hip_runtime.h>
#include <hip/hip_bf16.h>

typedef unsigned short u16;
typedef unsigned int u32;
typedef __attribute__((ext_vector_type(8))) short short8;
typedef __attribute__((ext_vector_type(4))) float f32x4;
typedef __attribute__((ext_vector_type(2))) float f32x2;

#define NP 20000
#define NS 10000
#define NE 400000
#define H  512
#define FDIM 64
#define ECHUNK 16

// fused-kernel block ranges
#define NB_HIST 1563            // hist: ceil(NE/256)
#define NB_WT   2560            // wtrans: 10 mats x 16x16 tiles
#define NB_W2F  4               // w2 fragment precompute
#define NB_SC   1563            // scatter: ceil(NE/256)
#define NB_PP   2500            // proj pol: ceil(NP/8)
#define NB_PS   1250            // proj stock: ceil(NS/8)

__device__ __forceinline__ float bl16(u32 w){ return __uint_as_float(w << 16); }
__device__ __forceinline__ float bh16(u32 w){ return __uint_as_float(w & 0xffff0000u); }
__device__ __forceinline__ u16 f2bf(float f){
  u32 u = __float_as_uint(f);
  u32 r = u + 0x7fffu + ((u >> 16) & 1u);
  return (u16)(r >> 16);
}
__device__ __forceinline__ u32 pack2(float a, float b){
  return (u32)f2bf(a) | ((u32)f2bf(b) << 16);
}
__device__ __forceinline__ void gload16(const void* g, void* l){
  __builtin_amdgcn_global_load_lds((const __attribute__((address_space(1))) u32*)g,
                                   (__attribute__((address_space(3))) u32*)l, 16, 0, 0);
}
// packed fp32 (VOP3P, gfx90a+): 2 fma / 2 add per instruction
__device__ __forceinline__ f32x2 pk_fma(f32x2 a, f32x2 b, f32x2 c){
  f32x2 d;
  asm("v_pk_fma_f32 %0, %1, %2, %3" : "=v"(d) : "v"(a), "v"(b), "v"(c));
  return d;
}
__device__ __forceinline__ f32x2 pk_add(f32x2 a, f32x2 b){
  f32x2 d;
  asm("v_pk_add_f32 %0, %1, %2" : "=v"(d) : "v"(a), "v"(b));
  return d;
}

// ---------------- fused setup: hist + wtrans + w2frag ----------------
struct TPair { const float* src; u16* dst; };
struct TArgs { TPair m[10]; };

__global__ __launch_bounds__(256) void setup_kernel(
    TArgs ta,
    const int* __restrict__ ps_dst, const int* __restrict__ sp_dst, const int* __restrict__ trow,
    int* __restrict__ cnt_s, int* __restrict__ cnt_p, int* __restrict__ cnt_t,
    const float* __restrict__ d2W, uint4* __restrict__ w2f)
{
  __shared__ float lds[32][33];
  int b = blockIdx.x;
  if (b < NB_HIST){
    int e = b*256 + threadIdx.x;
    if (e < NE){
      atomicAdd(&cnt_s[ps_dst[e]], 1);
      atomicAdd(&cnt_p[sp_dst[e]], 1);
      atomicAdd(&cnt_t[trow[e]], 1);
    }
    return;
  }
  b -= NB_HIST;
  if (b < NB_WT){
    int mat = b >> 8;
    int rem = b & 255;
    const float* __restrict__ src = ta.m[mat].src;
    u16* __restrict__ dst = ta.m[mat].dst;
    int k0 = (rem >> 4) << 5, n0 = (rem & 15) << 5;
    int t = threadIdx.x;
    int r = t >> 3, c4 = (t & 7) << 2;
    float4 v = *(const float4*)(src + (size_t)(k0 + r)*H + n0 + c4);
    lds[r][c4+0] = v.x; lds[r][c4+1] = v.y; lds[r][c4+2] = v.z; lds[r][c4+3] = v.w;
    __syncthreads();
    uint2 o;
    o.x = pack2(lds[c4+0][r], lds[c4+1][r]);
    o.y = pack2(lds[c4+2][r], lds[c4+3][r]);
    *(uint2*)(dst + (size_t)(n0 + r)*H + k0 + c4) = o;
    return;
  }
  b -= NB_WT;
  {
    // W2 B-fragment precompute: w2f[ks*64+l] = bf16 W2[ks*32+(l>>4)*8 .. +7][l&15]
    int tid = b*256 + threadIdx.x;   // [0,1024)
    int l = tid & 63;
    int col = l & 15, g = l >> 4;
    int k = (tid >> 6)*32 + g*8;
    float v[8];
    #pragma unroll
    for (int j = 0; j < 8; ++j)
      v[j] = (col < 3) ? d2W[(size_t)(k+j)*3 + col] : 0.f;
    uint4 o;
    o.x = pack2(v[0], v[1]); o.y = pack2(v[2], v[3]);
    o.z = pack2(v[4], v[5]); o.w = pack2(v[6], v[7]);
    w2f[tid] = o;
  }
}

// ---------------- scan (wave-shuffle) ----------------
__device__ void scan_one(int* cnt, int n, int* rowptr)
{
  __shared__ int wsum[16];
  __shared__ int carry_s;
  int tid = threadIdx.x;
  int lane = tid & 63, wv = tid >> 6;
  if (tid == 0) carry_s = 0;
  for (int base = 0; base < n; base += 1024){
    __syncthreads();                       // protects carry_s/wsum reuse
    int i = base + tid;
    int v = (i < n) ? cnt[i] : 0;
    int x = v;
    #pragma unroll
    for (int off = 1; off < 64; off <<= 1){
      int t = __shfl_up(x, off);
      if (lane >= off) x += t;
    }
    if (lane == 63) wsum[wv] = x;
    __syncthreads();
    if (wv == 0 && lane < 16){
      int y = wsum[lane];
      #pragma unroll
      for (int off = 1; off < 16; off <<= 1){
        int t = __shfl_up(y, off, 16);
        if (lane >= off) y += t;
      }
      wsum[lane] = y;
    }
    __syncthreads();
    int woff = (wv > 0) ? wsum[wv-1] : 0;
    int cb = carry_s;
    int excl = cb + woff + x - v;
    if (i < n){ rowptr[i] = excl; cnt[i] = excl; }
    __syncthreads();
    if (tid == 1023) carry_s = cb + woff + x;   // running total
  }
  __syncthreads();
  if (tid == 0) rowptr[n] = carry_s;
}

__global__ __launch_bounds__(1024) void scan3_kernel(int* c0, int n0, int* r0,
                                                     int* c1, int n1, int* r1,
                                                     int* c2, int n2, int* r2)
{
  if (blockIdx.x == 0) scan_one(c0, n0, r0);
  else if (blockIdx.x == 1) scan_one(c1, n1, r1);
  else scan_one(c2, n2, r2);
}

// ---------------- fused scatter + proj: scatter blocks first (latency-bound),
// proj blocks overlap on the idle VALU. meta packs {e, row<<16|col, 2xbf16 attr}.
__device__ void proj_body(const float* __restrict__ X, const float* __restrict__ W,
                          const float* __restrict__ b, u16* __restrict__ Y, int n,
                          int blk, float (*xs)[FDIM])
{
  int tid = threadIdx.x;
  int m0 = blk * 8;
  {
    int r = tid >> 6, c = tid & 63;
    int m = m0 + r;
    xs[r][c] = (m < n) ? X[(size_t)m*FDIM + c] : 0.f;
    m = m0 + r + 4;
    xs[r+4][c] = (m < n) ? X[(size_t)m*FDIM + c] : 0.f;
  }
  __syncthreads();
  float acc[8][2] = {};
  int c0 = tid, c1 = tid + 256;
  for (int k = 0; k < FDIM; ++k){
    float w0 = W[k*H + c0];
    float w1 = W[k*H + c1];
    #pragma unroll
    for (int r = 0; r < 8; ++r){
      float xv = xs[r][k];
      acc[r][0] = fmaf(xv, w0, acc[r][0]);
      acc[r][1] = fmaf(xv, w1, acc[r][1]);
    }
  }
  float b0 = b[c0], b1 = b[c1];
  #pragma unroll
  for (int r = 0; r < 8; ++r){
    int m = m0 + r;
    if (m < n){
      Y[(size_t)m*H + c0] = f2bf(fmaxf(acc[r][0] + b0, 0.f));
      Y[(size_t)m*H + c1] = f2bf(fmaxf(acc[r][1] + b1, 0.f));
    }
  }
}

__global__ __launch_bounds__(256) void scatter_proj_kernel(
    const int* __restrict__ ps_src, const int* __restrict__ ps_dst,
    const int* __restrict__ sp_src, const int* __restrict__ sp_dst,
    const int* __restrict__ trow, const int* __restrict__ tcol,
    const float* __restrict__ attr,
    int* __restrict__ cur_s, int* __restrict__ cur_p, int* __restrict__ cur_t,
    int* __restrict__ sorted_ps, int* __restrict__ sorted_sp, int4* __restrict__ meta_t,
    const float* __restrict__ x_pol, const float* __restrict__ Wp, const float* __restrict__ bp, u16* __restrict__ P0,
    const float* __restrict__ x_stock, const float* __restrict__ Ws_, const float* __restrict__ bs_, u16* __restrict__ S0)
{
  __shared__ float xs[8][FDIM];
  int b = blockIdx.x;
  if (b < NB_SC){
    int e = b*256 + threadIdx.x;
    if (e < NE){
      int pos = atomicAdd(&cur_s[ps_dst[e]], 1);
      sorted_ps[pos] = ps_src[e];
      int pos2 = atomicAdd(&cur_p[sp_dst[e]], 1);
      sorted_sp[pos2] = sp_src[e];
      int r = trow[e];
      int pos3 = atomicAdd(&cur_t[r], 1);
      meta_t[pos3] = make_int4(e, (r << 16) | tcol[e],
                               (int)pack2(attr[2*e], attr[2*e+1]), 0);
    }
    return;
  }
  b -= NB_SC;
  if (b < NB_PP){ proj_body(x_pol, Wp, bp, P0, NP, b, xs); return; }
  b -= NB_PP;
  proj_body(x_stock, Ws_, bs_, S0, NS, b, xs);
}

// ---------------- paired mean aggregation: one wave per dst row, 8 gathers in flight ----------------
__global__ __launch_bounds__(256) void agg2_kernel(
    const u16* __restrict__ X0, const int* __restrict__ rp0, const int* __restrict__ s0,
    u16* __restrict__ M0, int n0,
    const u16* __restrict__ X1, const int* __restrict__ rp1, const int* __restrict__ s1,
    u16* __restrict__ M1, int n1)
{
  int wid = (blockIdx.x << 2) + (threadIdx.x >> 6);
  int lane = threadIdx.x & 63;
  const u16* X; const int* rp; const int* ss; u16* M; int row;
  if (wid < n0){ X = X0; rp = rp0; ss = s0; M = M0; row = wid; }
  else if (wid < n0 + n1){ X = X1; rp = rp1; ss = s1; M = M1; row = wid - n0; }
  else return;
  int beg = rp[row], end = rp[row + 1];
  f32x2 ac0 = {0,0}, ac1 = {0,0}, ac2 = {0,0}, ac3 = {0,0};
  int j0 = lane << 3;
#define ACCP(v) { ac0 = pk_add(ac0, (f32x2){bl16(v.x), bh16(v.x)}); \
                  ac1 = pk_add(ac1, (f32x2){bl16(v.y), bh16(v.y)}); \
                  ac2 = pk_add(ac2, (f32x2){bl16(v.z), bh16(v.z)}); \
                  ac3 = pk_add(ac3, (f32x2){bl16(v.w), bh16(v.w)}); }
  int i = beg;
  for (; i + 8 <= end; i += 8){
    int sa = ss[i+0], sb = ss[i+1], sc = ss[i+2], sd = ss[i+3];
    int se = ss[i+4], sf = ss[i+5], sg = ss[i+6], sh = ss[i+7];
    uint4 v0 = *(const uint4*)(X + (size_t)sa*H + j0);
    uint4 v1 = *(const uint4*)(X + (size_t)sb*H + j0);
    uint4 v2 = *(const uint4*)(X + (size_t)sc*H + j0);
    uint4 v3 = *(const uint4*)(X + (size_t)sd*H + j0);
    uint4 v4 = *(const uint4*)(X + (size_t)se*H + j0);
    uint4 v5 = *(const uint4*)(X + (size_t)sf*H + j0);
    uint4 v6 = *(const uint4*)(X + (size_t)sg*H + j0);
    uint4 v7 = *(const uint4*)(X + (size_t)sh*H + j0);
    ACCP(v0); ACCP(v1); ACCP(v2); ACCP(v3);
    ACCP(v4); ACCP(v5); ACCP(v6); ACCP(v7);
  }
  for (; i + 2 <= end; i += 2){
    int sa = ss[i], sb = ss[i+1];
    uint4 v0 = *(const uint4*)(X + (size_t)sa*H + j0);
    uint4 v1 = *(const uint4*)(X + (size_t)sb*H + j0);
    ACCP(v0); ACCP(v1);
  }
  if (i < end){
    int sa = ss[i];
    uint4 v0 = *(const uint4*)(X + (size_t)sa*H + j0);
    ACCP(v0);
  }
#undef ACCP
  float inv = 1.f / (float)max(end - beg, 1);
  uint4 o;
  o.x = pack2(ac0.x*inv, ac0.y*inv);
  o.y = pack2(ac1.x*inv, ac1.y*inv);
  o.z = pack2(ac2.x*inv, ac2.y*inv);
  o.w = pack2(ac3.x*inv, ac3.y*inv);
  *(uint4*)(M + (size_t)row*H + j0) = o;
}

// ---------------- 256x256 deep-pipelined MFMA GEMM (T3+T4+T5) — R6-proven ----------------
struct GemmProb {
  const u16* A1; const u16* W1t; const u16* A2; const u16* W2t;
  const float* bias; u16* C; int nrows; int relu;
};

__global__ __launch_bounds__(512) void gemm_mfma256(GemmProb Pa, GemmProb Pb)
{
  GemmProb P = blockIdx.z ? Pb : Pa;
  int m0 = blockIdx.y << 8, n0 = blockIdx.x << 8;
  if (m0 >= P.nrows) return;

  __shared__ u16 lds[2][2][256*64];   // [buf][A/B][rows*k] = 128 KB
  int t = threadIdx.x;
  int w = t >> 6, l = t & 63;
  int wm = w >> 2, wn = w & 3;        // 2 x 4 wave grid
  int lr = l & 15, lg = l >> 4;

  f32x4 acc[8][4];
  #pragma unroll
  for (int i = 0; i < 8; ++i)
    #pragma unroll
    for (int j = 0; j < 4; ++j)
      acc[i][j] = (f32x4){0.f, 0.f, 0.f, 0.f};

  const u16* Asrc0 = P.A1; const u16* Asrc1 = P.A2;
  const u16* Wsrc0 = P.W1t; const u16* Wsrc1 = P.W2t;
  int NT = P.A2 ? 16 : 8;

  auto STAGE = [&](int kt, int buf){
    const u16* Ap = (kt < 8) ? Asrc0 : Asrc1;
    const u16* Wp = (kt < 8) ? Wsrc0 : Wsrc1;
    int k0 = (kt & 7) << 6;
    char* AsB = (char*)lds[buf][0];
    char* BsB = (char*)lds[buf][1];
    #pragma unroll
    for (int i = 0; i < 4; ++i){
      int c = i*512 + t;
      int row = c >> 3, p = c & 7;
      int k8 = p ^ (row & 7);
      gload16(Ap + (size_t)(m0 + row)*H + k0 + k8*8, AsB + c*16);
      gload16(Wp + (size_t)(n0 + row)*H + k0 + k8*8, BsB + c*16);
    }
  };

  STAGE(0, 0);
  for (int kt = 0; kt < NT; ++kt){
    int cur = kt & 1;
    if (kt + 1 < NT){
      STAGE(kt + 1, cur ^ 1);
      asm volatile("s_waitcnt vmcnt(8)" ::: "memory");
    } else {
      asm volatile("s_waitcnt vmcnt(0)" ::: "memory");
    }
    __builtin_amdgcn_sched_barrier(0);
    __builtin_amdgcn_s_barrier();
    __builtin_amdgcn_sched_barrier(0);
    const char* AsB = (const char*)lds[cur][0];
    const char* BsB = (const char*)lds[cur][1];
    #pragma unroll
    for (int ph = 0; ph < 4; ++ph){
      const int mh = ph & 1, ks = ph >> 1;
      short8 a[4], b[4];
      int kc = (ks << 2) + lg;
      #pragma unroll
      for (int i = 0; i < 4; ++i){
        int r = (wm << 7) + (mh << 6) + (i << 4) + lr;
        a[i] = *(const short8*)(AsB + r*128 + ((kc ^ (r & 7)) << 4));
      }
      #pragma unroll
      for (int nf = 0; nf < 4; ++nf){
        int r = (wn << 6) + (nf << 4) + lr;
        b[nf] = *(const short8*)(BsB + r*128 + ((kc ^ (r & 7)) << 4));
      }
      __builtin_amdgcn_s_setprio(1);
      #pragma unroll
      for (int i = 0; i < 4; ++i)
        #pragma unroll
        for (int nf = 0; nf < 4; ++nf)
          acc[(mh << 2) + i][nf] =
            __builtin_amdgcn_mfma_f32_16x16x32_bf16(a[i], b[nf], acc[(mh << 2) + i][nf], 0, 0, 0);
      __builtin_amdgcn_s_setprio(0);
    }
    asm volatile("" ::: "memory");
    __builtin_amdgcn_s_barrier();
    __builtin_amdgcn_sched_barrier(0);
  }

  float bvn[4];
  #pragma unroll
  for (int nf = 0; nf < 4; ++nf)
    bvn[nf] = P.bias ? P.bias[n0 + (wn << 6) + (nf << 4) + lr] : 0.f;
  #pragma unroll
  for (int mf = 0; mf < 8; ++mf){
    #pragma unroll
    for (int j = 0; j < 4; ++j){
      int m = m0 + (wm << 7) + (mf << 4) + (lg << 2) + j;
      if (m < P.nrows){
        #pragma unroll
        for (int nf = 0; nf < 4; ++nf){
          float v = acc[mf][nf][j] + bvn[nf];
          if (P.relu) v = fmaxf(v, 0.f);
          P.C[(size_t)m*H + n0 + (wn << 6) + (nf << 4) + lr] = f2bf(v);
        }
      }
    }
  }
}

// ---------------- edge decoder via bf16 MFMA: one wave per 16-edge chunk ----------------
// lane l -> (edge er=l&15, channel-group g=l>>4). Per K-slice ks (32 channels):
// lane computes h[er][ks*32+g*8 .. +7] = relu(A[p]+B[c]+a0*w1a+a1*w1b) in f32
// packed math, packs to bf16 = the mfma_f32_16x16x32_bf16 A-fragment in place.
// B-fragment = precomputed bf16 W2 frags (LDS). D: row=edge=(l>>4)*4+j, col=class=l&15.
// All cross-lane shuffles in UNIFORM control flow (R10 lesson).
__global__ __launch_bounds__(256) void edge_mfma_kernel(
    const u16* __restrict__ Adec, const u16* __restrict__ Bdec,   // bf16, d1b folded into Adec
    const uint4* __restrict__ w2f, const float* __restrict__ d1W,
    const float* __restrict__ d2b,
    const int4* __restrict__ meta_t,
    float* __restrict__ out)
{
  __shared__ uint4 w2s[16*64];      // 16 KB: bf16 W2 B-fragments per slice
  __shared__ float w1s[2][H];       // 4 KB: d1W rows 1024 (attr0) / 1025 (attr1)
  int t = threadIdx.x;
  #pragma unroll
  for (int i = 0; i < 4; ++i)
    w2s[i*256 + t] = w2f[i*256 + t];
  ((float4*)w1s)[t] = ((const float4*)(d1W + (size_t)1024*H))[t];   // 1024 consecutive floats
  __syncthreads();

  int lane = t & 63;
  int ch = (blockIdx.x << 2) + (t >> 6);
  int base = ch * ECHUNK;
  if (base >= NE) return;
  int er = lane & 15, g = lane >> 4;

  // lane-held metadata: lane i (<16) owns edge base+i; broadcasts are uniform-flow
  int4 mv = make_int4(0,0,0,0);
  if (lane < ECHUNK) mv = meta_t[base + lane];
  int rc  = __shfl(mv.y, er);
  u32 at  = (u32)__shfl(mv.z, er);
  int p = ((u32)rc) >> 16;
  int c = rc & 0xffff;
  float a0 = bl16(at), a1 = bh16(at);
  f32x2 a0v = {a0, a0}, a1v = {a1, a1};

  const u16* Arow = Adec + (size_t)p*H + g*8;
  const u16* Brow = Bdec + (size_t)c*H + g*8;

  f32x4 acc = {0.f, 0.f, 0.f, 0.f};
  #pragma unroll
  for (int ks = 0; ks < 16; ++ks){
    uint4 va = *(const uint4*)(Arow + ks*32);
    uint4 vb = *(const uint4*)(Brow + ks*32);
    const float* wa = &w1s[0][ks*32 + g*8];
    const float* wb = &w1s[1][ks*32 + g*8];
    float4 wa0 = *(const float4*)(wa);
    float4 wa1 = *(const float4*)(wa + 4);
    float4 wb0 = *(const float4*)(wb);
    float4 wb1 = *(const float4*)(wb + 4);
    f32x2 h0 = pk_add((f32x2){bl16(va.x), bh16(va.x)}, (f32x2){bl16(vb.x), bh16(vb.x)});
    f32x2 h1 = pk_add((f32x2){bl16(va.y), bh16(va.y)}, (f32x2){bl16(vb.y), bh16(vb.y)});
    f32x2 h2 = pk_add((f32x2){bl16(va.z), bh16(va.z)}, (f32x2){bl16(vb.z), bh16(vb.z)});
    f32x2 h3 = pk_add((f32x2){bl16(va.w), bh16(va.w)}, (f32x2){bl16(vb.w), bh16(vb.w)});
    h0 = pk_fma(a0v, (f32x2){wa0.x, wa0.y}, h0);
    h1 = pk_fma(a0v, (f32x2){wa0.z, wa0.w}, h1);
    h2 = pk_fma(a0v, (f32x2){wa1.x, wa1.y}, h2);
    h3 = pk_fma(a0v, (f32x2){wa1.z, wa1.w}, h3);
    h0 = pk_fma(a1v, (f32x2){wb0.x, wb0.y}, h0);
    h1 = pk_fma(a1v, (f32x2){wb0.z, wb0.w}, h1);
    h2 = pk_fma(a1v, (f32x2){wb1.x, wb1.y}, h2);
    h3 = pk_fma(a1v, (f32x2){wb1.z, wb1.w}, h3);
    uint4 hh;
    hh.x = pack2(fmaxf(h0.x, 0.f), fmaxf(h0.y, 0.f));
    hh.y = pack2(fmaxf(h1.x, 0.f), fmaxf(h1.y, 0.f));
    hh.z = pack2(fmaxf(h2.x, 0.f), fmaxf(h2.y, 0.f));
    hh.w = pack2(fmaxf(h3.x, 0.f), fmaxf(h3.y, 0.f));
    short8 pa = __builtin_bit_cast(short8, hh);
    short8 pb = __builtin_bit_cast(short8, w2s[ks*64 + lane]);
    acc = __builtin_amdgcn_mfma_f32_16x16x32_bf16(pa, pb, acc, 0, 0, 0);
  }

  // edge-index broadcasts in UNIFORM control flow (all 64 lanes active)
  int ebc[4];
  #pragma unroll
  for (int j = 0; j < 4; ++j)
    ebc[j] = __shfl(mv.x, (g << 2) + j);

  int col = lane & 15;
  if (col < 3){
    float ob = d2b[col];
    #pragma unroll
    for (int j = 0; j < 4; ++j)
      out[(size_t)ebc[j]*3 + col] = acc[j] + ob;
  }
}

extern "C" void kernel_launch(void* const* d_in, const int* in_sizes, int n_in,
                              void* d_out, int out_size, void* d_ws, size_t ws_size,
                              hipStream_t stream)
{
  const float* x_pol    = (const float*)d_in[0];
  const float* x_stock  = (const float*)d_in[1];
  const float* attr     = (const float*)d_in[2];
  const float* Wp       = (const float*)d_in[3];
  const float* bp       = (const float*)d_in[4];
  const float* Wst      = (const float*)d_in[5];
  const float* bst      = (const float*)d_in[6];
  const float* c1_ps_Wl = (const float*)d_in[7];
  const float* c1_ps_bl = (const float*)d_in[8];
  const float* c1_ps_Wr = (const float*)d_in[9];
  const float* c1_sp_Wl = (const float*)d_in[10];
  const float* c1_sp_bl = (const float*)d_in[11];
  const float* c1_sp_Wr = (const float*)d_in[12];
  const float* c2_ps_Wl = (const float*)d_in[13];
  const float* c2_ps_bl = (const float*)d_in[14];
  const float* c2_ps_Wr = (const float*)d_in[15];
  const float* c2_sp_Wl = (const float*)d_in[16];
  const float* c2_sp_bl = (const float*)d_in[17];
  const float* c2_sp_Wr = (const float*)d_in[18];
  const float* d1W      = (const float*)d_in[19];
  const float* d1b      = (const float*)d_in[20];
  const float* d2W      = (const float*)d_in[21];
  const float* d2b      = (const float*)d_in[22];
  const int* ps_src     = (const int*)d_in[23];
  const int* ps_dst     = (const int*)d_in[24];
  const int* sp_src     = (const int*)d_in[25];
  const int* sp_dst     = (const int*)d_in[26];
  const int* trow       = (const int*)d_in[27];
  const int* tcol       = (const int*)d_in[28];
  float* out = (float*)d_out;

  char* ws = (char*)d_ws;
  size_t off = 0;
  auto alloc = [&](size_t bytes)->char*{
    char* p = ws + off;
    off += (bytes + 255) & ~(size_t)255;
    return p;
  };
  u16* P0 = (u16*)alloc((size_t)NP*H*2);   // hp -> hp2
  u16* P1 = (u16*)alloc((size_t)NP*H*2);   // hp1
  u16* S0 = (u16*)alloc((size_t)NS*H*2);   // hs -> hs2
  u16* S1 = (u16*)alloc((size_t)NS*H*2);   // hs1
  u16* MP = (u16*)alloc((size_t)NP*H*2);   // mean into pol / Adec
  u16* MS = (u16*)alloc((size_t)NS*H*2);   // mean into stock / Bdec
  u16* Wt[10];
  for (int i = 0; i < 10; ++i) Wt[i] = (u16*)alloc((size_t)H*H*2);
  int* cnt_s    = (int*)alloc((size_t)NS*4);      // becomes cursor after scan
  int* cnt_p    = (int*)alloc((size_t)NP*4);
  int* cnt_t    = (int*)alloc((size_t)NP*4);
  int* rowptr_s = (int*)alloc((size_t)(NS+1)*4);
  int* rowptr_p = (int*)alloc((size_t)(NP+1)*4);
  int* rowptr_t = (int*)alloc((size_t)(NP+1)*4);
  int* sorted_ps = (int*)alloc((size_t)NE*4);
  int* sorted_sp = (int*)alloc((size_t)NE*4);
  int4* meta_t   = (int4*)alloc((size_t)NE*16);
  uint4* w2f     = (uint4*)alloc((size_t)16*64*16);
  // pad region: 256-row tile-tail staging reads past last matrix stay in-bounds
  alloc((size_t)256*H*2);

  TArgs ta;
  ta.m[0] = {c1_ps_Wl, Wt[0]}; ta.m[1] = {c1_ps_Wr, Wt[1]};
  ta.m[2] = {c1_sp_Wl, Wt[2]}; ta.m[3] = {c1_sp_Wr, Wt[3]};
  ta.m[4] = {c2_ps_Wl, Wt[4]}; ta.m[5] = {c2_ps_Wr, Wt[5]};
  ta.m[6] = {c2_sp_Wl, Wt[6]}; ta.m[7] = {c2_sp_Wr, Wt[7]};
  ta.m[8] = {d1W, Wt[8]};                      // d1_W rows 0..511   (pol part)
  ta.m[9] = {d1W + (size_t)512*H, Wt[9]};      // d1_W rows 512..1023 (stock part)

  // memsets, then fused setup (hist + wtrans + w2frag)
  hipMemsetAsync(cnt_s, 0, (size_t)NS*4, stream);
  hipMemsetAsync(cnt_p, 0, (size_t)NP*4, stream);
  hipMemsetAsync(cnt_t, 0, (size_t)NP*4, stream);
  setup_kernel<<<NB_HIST + NB_WT + NB_W2F, 256, 0, stream>>>(
      ta, ps_dst, sp_dst, trow, cnt_s, cnt_p, cnt_t, d2W, w2f);

  scan3_kernel<<<3, 1024, 0, stream>>>(cnt_s, NS, rowptr_s, cnt_p, NP, rowptr_p, cnt_t, NP, rowptr_t);

  // fused scatter (latency-bound) + input projections (VALU-bound) — overlap
  scatter_proj_kernel<<<NB_SC + NB_PP + NB_PS, 256, 0, stream>>>(
      ps_src, ps_dst, sp_src, sp_dst, trow, tcol, attr,
      cnt_s, cnt_p, cnt_t, sorted_ps, sorted_sp, meta_t,
      x_pol, Wp, bp, P0, x_stock, Wst, bst, S0);

  int aggGrid = (NS + NP + 3) / 4;
  int gRows = (NP + 255) / 256;   // max row tiles across paired problems

  // conv1: MS = mean_ps(P0), MP = mean_sp(S0); then paired GEMM
  agg2_kernel<<<aggGrid, 256, 0, stream>>>(P0, rowptr_s, sorted_ps, MS, NS,
                                           S0, rowptr_p, sorted_sp, MP, NP);
  {
    GemmProb a = {MS, Wt[0], S0, Wt[1], c1_ps_bl, S1, NS, 1};
    GemmProb b = {MP, Wt[2], P0, Wt[3], c1_sp_bl, P1, NP, 1};
    gemm_mfma256<<<dim3(2, gRows, 2), 512, 0, stream>>>(a, b);
  }

  // conv2
  agg2_kernel<<<aggGrid, 256, 0, stream>>>(P1, rowptr_s, sorted_ps, MS, NS,
                                           S1, rowptr_p, sorted_sp, MP, NP);
  {
    GemmProb a = {MS, Wt[4], S1, Wt[5], c2_ps_bl, S0, NS, 1};
    GemmProb b = {MP, Wt[6], P1, Wt[7], c2_sp_bl, P0, NP, 1};
    gemm_mfma256<<<dim3(2, gRows, 2), 512, 0, stream>>>(a, b);
  }

  // decoder precompute pair: Adec = hp2 @ d1W[0:512,:] + d1b (bias folded), Bdec = hs2 @ d1W[512:1024,:]
  {
    GemmProb a = {P0, Wt[8], nullptr, nullptr, d1b, MP, NP, 0};
    GemmProb b = {S0, Wt[9], nullptr, nullptr, nullptr, MS, NS, 0};
    gemm_mfma256<<<dim3(2, gRows, 2), 512, 0, stream>>>(a, b);
  }

  // edge decoder (bf16 MFMA): one wave per 16-edge chunk
  int nchunks = NE / ECHUNK;
  edge_mfma_kernel<<<(nchunks + 3) / 4, 256, 0, stream>>>(MP, MS, w2f, d1W, d2b,
                                                          meta_t, out);
}

// Round 12
// 554.881 us; speedup vs baseline: 3.0463x; 1.0112x over previous
//
#include <hip/hip_runtime.h>
#include <hip/hip_bf16.h>

typedef unsigned short u16;
typedef unsigned int u32;
typedef __attribute__((ext_vector_type(8))) short short8;
typedef __attribute__((ext_vector_type(4))) float f32x4;
typedef __attribute__((ext_vector_type(2))) float f32x2;

#define NP 20000
#define NS 10000
#define NE 400000
#define H  512
#define FDIM 64
#define ECHUNK 16

// fused-kernel block ranges
#define NB_HIST 1563            // hist: ceil(NE/256)
#define NB_WT   2560            // wtrans: 10 mats x 16x16 tiles
#define NB_W2F  4               // w2 fragment precompute
#define NB_SC   1563            // scatter: ceil(NE/256)
#define NB_PP   2500            // proj pol: ceil(NP/8)
#define NB_PS   1250            // proj stock: ceil(NS/8)

__device__ __forceinline__ float bl16(u32 w){ return __uint_as_float(w << 16); }
__device__ __forceinline__ float bh16(u32 w){ return __uint_as_float(w & 0xffff0000u); }
__device__ __forceinline__ u16 f2bf(float f){
  u32 u = __float_as_uint(f);
  u32 r = u + 0x7fffu + ((u >> 16) & 1u);
  return (u16)(r >> 16);
}
__device__ __forceinline__ u32 pack2(float a, float b){
  return (u32)f2bf(a) | ((u32)f2bf(b) << 16);
}
__device__ __forceinline__ void gload16(const void* g, void* l){
  __builtin_amdgcn_global_load_lds((const __attribute__((address_space(1))) u32*)g,
                                   (__attribute__((address_space(3))) u32*)l, 16, 0, 0);
}
// packed fp32 (VOP3P, gfx90a+): 2 fma / 2 add per instruction
__device__ __forceinline__ f32x2 pk_fma(f32x2 a, f32x2 b, f32x2 c){
  f32x2 d;
  asm("v_pk_fma_f32 %0, %1, %2, %3" : "=v"(d) : "v"(a), "v"(b), "v"(c));
  return d;
}
__device__ __forceinline__ f32x2 pk_add(f32x2 a, f32x2 b){
  f32x2 d;
  asm("v_pk_add_f32 %0, %1, %2" : "=v"(d) : "v"(a), "v"(b));
  return d;
}

// ---------------- fused setup: hist + wtrans + w2frag ----------------
struct TPair { const float* src; u16* dst; };
struct TArgs { TPair m[10]; };

__global__ __launch_bounds__(256) void setup_kernel(
    TArgs ta,
    const int* __restrict__ ps_dst, const int* __restrict__ sp_dst, const int* __restrict__ trow,
    int* __restrict__ cnt_s, int* __restrict__ cnt_p, int* __restrict__ cnt_t,
    const float* __restrict__ d2W, uint4* __restrict__ w2f)
{
  __shared__ float lds[32][33];
  int b = blockIdx.x;
  if (b < NB_HIST){
    int e = b*256 + threadIdx.x;
    if (e < NE){
      atomicAdd(&cnt_s[ps_dst[e]], 1);
      atomicAdd(&cnt_p[sp_dst[e]], 1);
      atomicAdd(&cnt_t[trow[e]], 1);
    }
    return;
  }
  b -= NB_HIST;
  if (b < NB_WT){
    int mat = b >> 8;
    int rem = b & 255;
    const float* __restrict__ src = ta.m[mat].src;
    u16* __restrict__ dst = ta.m[mat].dst;
    int k0 = (rem >> 4) << 5, n0 = (rem & 15) << 5;
    int t = threadIdx.x;
    int r = t >> 3, c4 = (t & 7) << 2;
    float4 v = *(const float4*)(src + (size_t)(k0 + r)*H + n0 + c4);
    lds[r][c4+0] = v.x; lds[r][c4+1] = v.y; lds[r][c4+2] = v.z; lds[r][c4+3] = v.w;
    __syncthreads();
    uint2 o;
    o.x = pack2(lds[c4+0][r], lds[c4+1][r]);
    o.y = pack2(lds[c4+2][r], lds[c4+3][r]);
    *(uint2*)(dst + (size_t)(n0 + r)*H + k0 + c4) = o;
    return;
  }
  b -= NB_WT;
  {
    // W2 B-fragment precompute: w2f[ks*64+l] = bf16 W2[ks*32+(l>>4)*8 .. +7][l&15]
    int tid = b*256 + threadIdx.x;   // [0,1024)
    int l = tid & 63;
    int col = l & 15, g = l >> 4;
    int k = (tid >> 6)*32 + g*8;
    float v[8];
    #pragma unroll
    for (int j = 0; j < 8; ++j)
      v[j] = (col < 3) ? d2W[(size_t)(k+j)*3 + col] : 0.f;
    uint4 o;
    o.x = pack2(v[0], v[1]); o.y = pack2(v[2], v[3]);
    o.z = pack2(v[4], v[5]); o.w = pack2(v[6], v[7]);
    w2f[tid] = o;
  }
}

// ---------------- scan (wave-shuffle) ----------------
__device__ void scan_one(int* cnt, int n, int* rowptr)
{
  __shared__ int wsum[16];
  __shared__ int carry_s;
  int tid = threadIdx.x;
  int lane = tid & 63, wv = tid >> 6;
  if (tid == 0) carry_s = 0;
  for (int base = 0; base < n; base += 1024){
    __syncthreads();                       // protects carry_s/wsum reuse
    int i = base + tid;
    int v = (i < n) ? cnt[i] : 0;
    int x = v;
    #pragma unroll
    for (int off = 1; off < 64; off <<= 1){
      int t = __shfl_up(x, off);
      if (lane >= off) x += t;
    }
    if (lane == 63) wsum[wv] = x;
    __syncthreads();
    if (wv == 0 && lane < 16){
      int y = wsum[lane];
      #pragma unroll
      for (int off = 1; off < 16; off <<= 1){
        int t = __shfl_up(y, off, 16);
        if (lane >= off) y += t;
      }
      wsum[lane] = y;
    }
    __syncthreads();
    int woff = (wv > 0) ? wsum[wv-1] : 0;
    int cb = carry_s;
    int excl = cb + woff + x - v;
    if (i < n){ rowptr[i] = excl; cnt[i] = excl; }
    __syncthreads();
    if (tid == 1023) carry_s = cb + woff + x;   // running total
  }
  __syncthreads();
  if (tid == 0) rowptr[n] = carry_s;
}

__global__ __launch_bounds__(1024) void scan3_kernel(int* c0, int n0, int* r0,
                                                     int* c1, int n1, int* r1,
                                                     int* c2, int n2, int* r2)
{
  if (blockIdx.x == 0) scan_one(c0, n0, r0);
  else if (blockIdx.x == 1) scan_one(c1, n1, r1);
  else scan_one(c2, n2, r2);
}

// ---------------- fused scatter + proj ----------------
__device__ void proj_body(const float* __restrict__ X, const float* __restrict__ W,
                          const float* __restrict__ b, u16* __restrict__ Y, int n,
                          int blk, float (*xs)[FDIM])
{
  int tid = threadIdx.x;
  int m0 = blk * 8;
  {
    int r = tid >> 6, c = tid & 63;
    int m = m0 + r;
    xs[r][c] = (m < n) ? X[(size_t)m*FDIM + c] : 0.f;
    m = m0 + r + 4;
    xs[r+4][c] = (m < n) ? X[(size_t)m*FDIM + c] : 0.f;
  }
  __syncthreads();
  float acc[8][2] = {};
  int c0 = tid, c1 = tid + 256;
  for (int k = 0; k < FDIM; ++k){
    float w0 = W[k*H + c0];
    float w1 = W[k*H + c1];
    #pragma unroll
    for (int r = 0; r < 8; ++r){
      float xv = xs[r][k];
      acc[r][0] = fmaf(xv, w0, acc[r][0]);
      acc[r][1] = fmaf(xv, w1, acc[r][1]);
    }
  }
  float b0 = b[c0], b1 = b[c1];
  #pragma unroll
  for (int r = 0; r < 8; ++r){
    int m = m0 + r;
    if (m < n){
      Y[(size_t)m*H + c0] = f2bf(fmaxf(acc[r][0] + b0, 0.f));
      Y[(size_t)m*H + c1] = f2bf(fmaxf(acc[r][1] + b1, 0.f));
    }
  }
}

__global__ __launch_bounds__(256) void scatter_proj_kernel(
    const int* __restrict__ ps_src, const int* __restrict__ ps_dst,
    const int* __restrict__ sp_src, const int* __restrict__ sp_dst,
    const int* __restrict__ trow, const int* __restrict__ tcol,
    const float* __restrict__ attr,
    int* __restrict__ cur_s, int* __restrict__ cur_p, int* __restrict__ cur_t,
    int* __restrict__ sorted_ps, int* __restrict__ sorted_sp, int4* __restrict__ meta_t,
    const float* __restrict__ x_pol, const float* __restrict__ Wp, const float* __restrict__ bp, u16* __restrict__ P0,
    const float* __restrict__ x_stock, const float* __restrict__ Ws_, const float* __restrict__ bs_, u16* __restrict__ S0)
{
  __shared__ float xs[8][FDIM];
  int b = blockIdx.x;
  if (b < NB_SC){
    int e = b*256 + threadIdx.x;
    if (e < NE){
      int pos = atomicAdd(&cur_s[ps_dst[e]], 1);
      sorted_ps[pos] = ps_src[e];
      int pos2 = atomicAdd(&cur_p[sp_dst[e]], 1);
      sorted_sp[pos2] = sp_src[e];
      int r = trow[e];
      int pos3 = atomicAdd(&cur_t[r], 1);
      meta_t[pos3] = make_int4(e, (r << 16) | tcol[e],
                               (int)pack2(attr[2*e], attr[2*e+1]), 0);
    }
    return;
  }
  b -= NB_SC;
  if (b < NB_PP){ proj_body(x_pol, Wp, bp, P0, NP, b, xs); return; }
  b -= NB_PP;
  proj_body(x_stock, Ws_, bs_, S0, NS, b, xs);
}

// ---------------- paired mean aggregation: one wave per dst row, 8 gathers in flight ----------------
__global__ __launch_bounds__(256) void agg2_kernel(
    const u16* __restrict__ X0, const int* __restrict__ rp0, const int* __restrict__ s0,
    u16* __restrict__ M0, int n0,
    const u16* __restrict__ X1, const int* __restrict__ rp1, const int* __restrict__ s1,
    u16* __restrict__ M1, int n1)
{
  int wid = (blockIdx.x << 2) + (threadIdx.x >> 6);
  int lane = threadIdx.x & 63;
  const u16* X; const int* rp; const int* ss; u16* M; int row;
  if (wid < n0){ X = X0; rp = rp0; ss = s0; M = M0; row = wid; }
  else if (wid < n0 + n1){ X = X1; rp = rp1; ss = s1; M = M1; row = wid - n0; }
  else return;
  int beg = rp[row], end = rp[row + 1];
  f32x2 ac0 = {0,0}, ac1 = {0,0}, ac2 = {0,0}, ac3 = {0,0};
  int j0 = lane << 3;
#define ACCP(v) { ac0 = pk_add(ac0, (f32x2){bl16(v.x), bh16(v.x)}); \
                  ac1 = pk_add(ac1, (f32x2){bl16(v.y), bh16(v.y)}); \
                  ac2 = pk_add(ac2, (f32x2){bl16(v.z), bh16(v.z)}); \
                  ac3 = pk_add(ac3, (f32x2){bl16(v.w), bh16(v.w)}); }
  int i = beg;
  for (; i + 8 <= end; i += 8){
    int sa = ss[i+0], sb = ss[i+1], sc = ss[i+2], sd = ss[i+3];
    int se = ss[i+4], sf = ss[i+5], sg = ss[i+6], sh = ss[i+7];
    uint4 v0 = *(const uint4*)(X + (size_t)sa*H + j0);
    uint4 v1 = *(const uint4*)(X + (size_t)sb*H + j0);
    uint4 v2 = *(const uint4*)(X + (size_t)sc*H + j0);
    uint4 v3 = *(const uint4*)(X + (size_t)sd*H + j0);
    uint4 v4 = *(const uint4*)(X + (size_t)se*H + j0);
    uint4 v5 = *(const uint4*)(X + (size_t)sf*H + j0);
    uint4 v6 = *(const uint4*)(X + (size_t)sg*H + j0);
    uint4 v7 = *(const uint4*)(X + (size_t)sh*H + j0);
    ACCP(v0); ACCP(v1); ACCP(v2); ACCP(v3);
    ACCP(v4); ACCP(v5); ACCP(v6); ACCP(v7);
  }
  for (; i + 2 <= end; i += 2){
    int sa = ss[i], sb = ss[i+1];
    uint4 v0 = *(const uint4*)(X + (size_t)sa*H + j0);
    uint4 v1 = *(const uint4*)(X + (size_t)sb*H + j0);
    ACCP(v0); ACCP(v1);
  }
  if (i < end){
    int sa = ss[i];
    uint4 v0 = *(const uint4*)(X + (size_t)sa*H + j0);
    ACCP(v0);
  }
#undef ACCP
  float inv = 1.f / (float)max(end - beg, 1);
  uint4 o;
  o.x = pack2(ac0.x*inv, ac0.y*inv);
  o.y = pack2(ac1.x*inv, ac1.y*inv);
  o.z = pack2(ac2.x*inv, ac2.y*inv);
  o.w = pack2(ac3.x*inv, ac3.y*inv);
  *(uint4*)(M + (size_t)row*H + j0) = o;
}

// ---------------- 256x256 deep-pipelined MFMA GEMM (T3+T4+T5) ----------------
// FLATTENED GRID (R12): blockIdx.x enumerates exactly the useful tiles of both
// problems (a first), 2 N-tiles per M-tile; no idle blocks, single scheduling
// round at <=256 blocks (128 KB LDS -> 1 block/CU).
struct GemmProb {
  const u16* A1; const u16* W1t; const u16* A2; const u16* W2t;
  const float* bias; u16* C; int nrows; int relu;
};

__global__ __launch_bounds__(512) void gemm_mfma256(GemmProb Pa, GemmProb Pb, int aBlocks)
{
  int bid = blockIdx.x;
  GemmProb P; int idx;
  if (bid < aBlocks){ P = Pa; idx = bid; }
  else { P = Pb; idx = bid - aBlocks; }
  int n0 = (idx & 1) << 8;
  int m0 = (idx >> 1) << 8;
  if (m0 >= P.nrows) return;

  __shared__ u16 lds[2][2][256*64];   // [buf][A/B][rows*k] = 128 KB
  int t = threadIdx.x;
  int w = t >> 6, l = t & 63;
  int wm = w >> 2, wn = w & 3;        // 2 x 4 wave grid
  int lr = l & 15, lg = l >> 4;

  f32x4 acc[8][4];
  #pragma unroll
  for (int i = 0; i < 8; ++i)
    #pragma unroll
    for (int j = 0; j < 4; ++j)
      acc[i][j] = (f32x4){0.f, 0.f, 0.f, 0.f};

  const u16* Asrc0 = P.A1; const u16* Asrc1 = P.A2;
  const u16* Wsrc0 = P.W1t; const u16* Wsrc1 = P.W2t;
  int NT = P.A2 ? 16 : 8;

  auto STAGE = [&](int kt, int buf){
    const u16* Ap = (kt < 8) ? Asrc0 : Asrc1;
    const u16* Wp = (kt < 8) ? Wsrc0 : Wsrc1;
    int k0 = (kt & 7) << 6;
    char* AsB = (char*)lds[buf][0];
    char* BsB = (char*)lds[buf][1];
    #pragma unroll
    for (int i = 0; i < 4; ++i){
      int c = i*512 + t;
      int row = c >> 3, p = c & 7;
      int k8 = p ^ (row & 7);
      gload16(Ap + (size_t)(m0 + row)*H + k0 + k8*8, AsB + c*16);
      gload16(Wp + (size_t)(n0 + row)*H + k0 + k8*8, BsB + c*16);
    }
  };

  STAGE(0, 0);
  for (int kt = 0; kt < NT; ++kt){
    int cur = kt & 1;
    if (kt + 1 < NT){
      STAGE(kt + 1, cur ^ 1);
      asm volatile("s_waitcnt vmcnt(8)" ::: "memory");
    } else {
      asm volatile("s_waitcnt vmcnt(0)" ::: "memory");
    }
    __builtin_amdgcn_sched_barrier(0);
    __builtin_amdgcn_s_barrier();
    __builtin_amdgcn_sched_barrier(0);
    const char* AsB = (const char*)lds[cur][0];
    const char* BsB = (const char*)lds[cur][1];
    #pragma unroll
    for (int ph = 0; ph < 4; ++ph){
      const int mh = ph & 1, ks = ph >> 1;
      short8 a[4], b[4];
      int kc = (ks << 2) + lg;
      #pragma unroll
      for (int i = 0; i < 4; ++i){
        int r = (wm << 7) + (mh << 6) + (i << 4) + lr;
        a[i] = *(const short8*)(AsB + r*128 + ((kc ^ (r & 7)) << 4));
      }
      #pragma unroll
      for (int nf = 0; nf < 4; ++nf){
        int r = (wn << 6) + (nf << 4) + lr;
        b[nf] = *(const short8*)(BsB + r*128 + ((kc ^ (r & 7)) << 4));
      }
      __builtin_amdgcn_s_setprio(1);
      #pragma unroll
      for (int i = 0; i < 4; ++i)
        #pragma unroll
        for (int nf = 0; nf < 4; ++nf)
          acc[(mh << 2) + i][nf] =
            __builtin_amdgcn_mfma_f32_16x16x32_bf16(a[i], b[nf], acc[(mh << 2) + i][nf], 0, 0, 0);
      __builtin_amdgcn_s_setprio(0);
    }
    asm volatile("" ::: "memory");
    __builtin_amdgcn_s_barrier();
    __builtin_amdgcn_sched_barrier(0);
  }

  float bvn[4];
  #pragma unroll
  for (int nf = 0; nf < 4; ++nf)
    bvn[nf] = P.bias ? P.bias[n0 + (wn << 6) + (nf << 4) + lr] : 0.f;
  #pragma unroll
  for (int mf = 0; mf < 8; ++mf){
    #pragma unroll
    for (int j = 0; j < 4; ++j){
      int m = m0 + (wm << 7) + (mf << 4) + (lg << 2) + j;
      if (m < P.nrows){
        #pragma unroll
        for (int nf = 0; nf < 4; ++nf){
          float v = acc[mf][nf][j] + bvn[nf];
          if (P.relu) v = fmaxf(v, 0.f);
          P.C[(size_t)m*H + n0 + (wn << 6) + (nf << 4) + lr] = f2bf(v);
        }
      }
    }
  }
}

// ---------------- edge decoder via bf16 MFMA: grid-stride over 16-edge chunks ----------------
// lane l -> (edge er=l&15, channel-group g=l>>4); h computed in f32 packed math,
// packed to bf16 = the MFMA A-fragment in place; W2 B-fragments in LDS (loaded
// ONCE per block, amortized over ~6 chunks/wave by grid-striding — R12).
// D: row=edge=(l>>4)*4+j, col=class=l&15. All shuffles in uniform flow.
__global__ __launch_bounds__(256) void edge_mfma_kernel(
    const u16* __restrict__ Adec, const u16* __restrict__ Bdec,   // bf16, d1b folded into Adec
    const uint4* __restrict__ w2f, const float* __restrict__ d1W,
    const float* __restrict__ d2b,
    const int4* __restrict__ meta_t,
    float* __restrict__ out)
{
  __shared__ uint4 w2s[16*64];      // 16 KB: bf16 W2 B-fragments per slice
  __shared__ float w1s[2][H];       // 4 KB: d1W rows 1024 (attr0) / 1025 (attr1)
  int t = threadIdx.x;
  #pragma unroll
  for (int i = 0; i < 4; ++i)
    w2s[i*256 + t] = w2f[i*256 + t];
  ((float4*)w1s)[t] = ((const float4*)(d1W + (size_t)1024*H))[t];   // 1024 consecutive floats
  __syncthreads();

  int lane = t & 63;
  int er = lane & 15, g = lane >> 4;
  int nch = NE / ECHUNK;
  int wstride = gridDim.x << 2;
  float ob = (er < 3) ? d2b[er] : 0.f;   // er == col for the writer lanes (lane&15)

  for (int ch = (blockIdx.x << 2) + (t >> 6); ch < nch; ch += wstride){
    int base = ch * ECHUNK;

    // lane-held metadata: lane i (<16) owns edge base+i; broadcasts are uniform-flow
    int4 mv = make_int4(0,0,0,0);
    if (lane < ECHUNK) mv = meta_t[base + lane];
    int rc  = __shfl(mv.y, er);
    u32 at  = (u32)__shfl(mv.z, er);
    int p = ((u32)rc) >> 16;
    int c = rc & 0xffff;
    float a0 = bl16(at), a1 = bh16(at);
    f32x2 a0v = {a0, a0}, a1v = {a1, a1};

    const u16* Arow = Adec + (size_t)p*H + g*8;
    const u16* Brow = Bdec + (size_t)c*H + g*8;

    f32x4 acc = {0.f, 0.f, 0.f, 0.f};
    #pragma unroll
    for (int ks = 0; ks < 16; ++ks){
      uint4 va = *(const uint4*)(Arow + ks*32);
      uint4 vb = *(const uint4*)(Brow + ks*32);
      const float* wa = &w1s[0][ks*32 + g*8];
      const float* wb = &w1s[1][ks*32 + g*8];
      float4 wa0 = *(const float4*)(wa);
      float4 wa1 = *(const float4*)(wa + 4);
      float4 wb0 = *(const float4*)(wb);
      float4 wb1 = *(const float4*)(wb + 4);
      f32x2 h0 = pk_add((f32x2){bl16(va.x), bh16(va.x)}, (f32x2){bl16(vb.x), bh16(vb.x)});
      f32x2 h1 = pk_add((f32x2){bl16(va.y), bh16(va.y)}, (f32x2){bl16(vb.y), bh16(vb.y)});
      f32x2 h2 = pk_add((f32x2){bl16(va.z), bh16(va.z)}, (f32x2){bl16(vb.z), bh16(vb.z)});
      f32x2 h3 = pk_add((f32x2){bl16(va.w), bh16(va.w)}, (f32x2){bl16(vb.w), bh16(vb.w)});
      h0 = pk_fma(a0v, (f32x2){wa0.x, wa0.y}, h0);
      h1 = pk_fma(a0v, (f32x2){wa0.z, wa0.w}, h1);
      h2 = pk_fma(a0v, (f32x2){wa1.x, wa1.y}, h2);
      h3 = pk_fma(a0v, (f32x2){wa1.z, wa1.w}, h3);
      h0 = pk_fma(a1v, (f32x2){wb0.x, wb0.y}, h0);
      h1 = pk_fma(a1v, (f32x2){wb0.z, wb0.w}, h1);
      h2 = pk_fma(a1v, (f32x2){wb1.x, wb1.y}, h2);
      h3 = pk_fma(a1v, (f32x2){wb1.z, wb1.w}, h3);
      uint4 hh;
      hh.x = pack2(fmaxf(h0.x, 0.f), fmaxf(h0.y, 0.f));
      hh.y = pack2(fmaxf(h1.x, 0.f), fmaxf(h1.y, 0.f));
      hh.z = pack2(fmaxf(h2.x, 0.f), fmaxf(h2.y, 0.f));
      hh.w = pack2(fmaxf(h3.x, 0.f), fmaxf(h3.y, 0.f));
      short8 pa = __builtin_bit_cast(short8, hh);
      short8 pb = __builtin_bit_cast(short8, w2s[ks*64 + lane]);
      acc = __builtin_amdgcn_mfma_f32_16x16x32_bf16(pa, pb, acc, 0, 0, 0);
    }

    // edge-index broadcasts in UNIFORM control flow (all 64 lanes active)
    int ebc[4];
    #pragma unroll
    for (int j = 0; j < 4; ++j)
      ebc[j] = __shfl(mv.x, (g << 2) + j);

    if (er < 3){
      #pragma unroll
      for (int j = 0; j < 4; ++j)
        out[(size_t)ebc[j]*3 + er] = acc[j] + ob;
    }
  }
}

extern "C" void kernel_launch(void* const* d_in, const int* in_sizes, int n_in,
                              void* d_out, int out_size, void* d_ws, size_t ws_size,
                              hipStream_t stream)
{
  const float* x_pol    = (const float*)d_in[0];
  const float* x_stock  = (const float*)d_in[1];
  const float* attr     = (const float*)d_in[2];
  const float* Wp       = (const float*)d_in[3];
  const float* bp       = (const float*)d_in[4];
  const float* Wst      = (const float*)d_in[5];
  const float* bst      = (const float*)d_in[6];
  const float* c1_ps_Wl = (const float*)d_in[7];
  const float* c1_ps_bl = (const float*)d_in[8];
  const float* c1_ps_Wr = (const float*)d_in[9];
  const float* c1_sp_Wl = (const float*)d_in[10];
  const float* c1_sp_bl = (const float*)d_in[11];
  const float* c1_sp_Wr = (const float*)d_in[12];
  const float* c2_ps_Wl = (const float*)d_in[13];
  const float* c2_ps_bl = (const float*)d_in[14];
  const float* c2_ps_Wr = (const float*)d_in[15];
  const float* c2_sp_Wl = (const float*)d_in[16];
  const float* c2_sp_bl = (const float*)d_in[17];
  const float* c2_sp_Wr = (const float*)d_in[18];
  const float* d1W      = (const float*)d_in[19];
  const float* d1b      = (const float*)d_in[20];
  const float* d2W      = (const float*)d_in[21];
  const float* d2b      = (const float*)d_in[22];
  const int* ps_src     = (const int*)d_in[23];
  const int* ps_dst     = (const int*)d_in[24];
  const int* sp_src     = (const int*)d_in[25];
  const int* sp_dst     = (const int*)d_in[26];
  const int* trow       = (const int*)d_in[27];
  const int* tcol       = (const int*)d_in[28];
  float* out = (float*)d_out;

  char* ws = (char*)d_ws;
  size_t off = 0;
  auto alloc = [&](size_t bytes)->char*{
    char* p = ws + off;
    off += (bytes + 255) & ~(size_t)255;
    return p;
  };
  u16* P0 = (u16*)alloc((size_t)NP*H*2);   // hp -> hp2
  u16* P1 = (u16*)alloc((size_t)NP*H*2);   // hp1
  u16* S0 = (u16*)alloc((size_t)NS*H*2);   // hs -> hs2
  u16* S1 = (u16*)alloc((size_t)NS*H*2);   // hs1
  u16* MP = (u16*)alloc((size_t)NP*H*2);   // mean into pol / Adec
  u16* MS = (u16*)alloc((size_t)NS*H*2);   // mean into stock / Bdec
  u16* Wt[10];
  for (int i = 0; i < 10; ++i) Wt[i] = (u16*)alloc((size_t)H*H*2);
  int* cnt_s    = (int*)alloc((size_t)NS*4);      // becomes cursor after scan
  int* cnt_p    = (int*)alloc((size_t)NP*4);
  int* cnt_t    = (int*)alloc((size_t)NP*4);
  int* rowptr_s = (int*)alloc((size_t)(NS+1)*4);
  int* rowptr_p = (int*)alloc((size_t)(NP+1)*4);
  int* rowptr_t = (int*)alloc((size_t)(NP+1)*4);
  int* sorted_ps = (int*)alloc((size_t)NE*4);
  int* sorted_sp = (int*)alloc((size_t)NE*4);
  int4* meta_t   = (int4*)alloc((size_t)NE*16);
  uint4* w2f     = (uint4*)alloc((size_t)16*64*16);
  // pad region: 256-row tile-tail staging reads past last matrix stay in-bounds
  alloc((size_t)256*H*2);

  TArgs ta;
  ta.m[0] = {c1_ps_Wl, Wt[0]}; ta.m[1] = {c1_ps_Wr, Wt[1]};
  ta.m[2] = {c1_sp_Wl, Wt[2]}; ta.m[3] = {c1_sp_Wr, Wt[3]};
  ta.m[4] = {c2_ps_Wl, Wt[4]}; ta.m[5] = {c2_ps_Wr, Wt[5]};
  ta.m[6] = {c2_sp_Wl, Wt[6]}; ta.m[7] = {c2_sp_Wr, Wt[7]};
  ta.m[8] = {d1W, Wt[8]};                      // d1_W rows 0..511   (pol part)
  ta.m[9] = {d1W + (size_t)512*H, Wt[9]};      // d1_W rows 512..1023 (stock part)

  // memsets, then fused setup (hist + wtrans + w2frag)
  hipMemsetAsync(cnt_s, 0, (size_t)NS*4, stream);
  hipMemsetAsync(cnt_p, 0, (size_t)NP*4, stream);
  hipMemsetAsync(cnt_t, 0, (size_t)NP*4, stream);
  setup_kernel<<<NB_HIST + NB_WT + NB_W2F, 256, 0, stream>>>(
      ta, ps_dst, sp_dst, trow, cnt_s, cnt_p, cnt_t, d2W, w2f);

  scan3_kernel<<<3, 1024, 0, stream>>>(cnt_s, NS, rowptr_s, cnt_p, NP, rowptr_p, cnt_t, NP, rowptr_t);

  // fused scatter (latency-bound) + input projections
  scatter_proj_kernel<<<NB_SC + NB_PP + NB_PS, 256, 0, stream>>>(
      ps_src, ps_dst, sp_src, sp_dst, trow, tcol, attr,
      cnt_s, cnt_p, cnt_t, sorted_ps, sorted_sp, meta_t,
      x_pol, Wp, bp, P0, x_stock, Wst, bst, S0);

  int aggGrid = (NS + NP + 3) / 4;
  int tS = ((NS + 255) / 256) * 2;   // N=512 -> 2 column tiles per M tile
  int tP = ((NP + 255) / 256) * 2;

  // conv1: MS = mean_ps(P0), MP = mean_sp(S0); then paired GEMM (flattened grid, 1 round)
  agg2_kernel<<<aggGrid, 256, 0, stream>>>(P0, rowptr_s, sorted_ps, MS, NS,
                                           S0, rowptr_p, sorted_sp, MP, NP);
  {
    GemmProb a = {MS, Wt[0], S0, Wt[1], c1_ps_bl, S1, NS, 1};
    GemmProb b = {MP, Wt[2], P0, Wt[3], c1_sp_bl, P1, NP, 1};
    gemm_mfma256<<<tS + tP, 512, 0, stream>>>(a, b, tS);
  }

  // conv2
  agg2_kernel<<<aggGrid, 256, 0, stream>>>(P1, rowptr_s, sorted_ps, MS, NS,
                                           S1, rowptr_p, sorted_sp, MP, NP);
  {
    GemmProb a = {MS, Wt[4], S1, Wt[5], c2_ps_bl, S0, NS, 1};
    GemmProb b = {MP, Wt[6], P1, Wt[7], c2_sp_bl, P0, NP, 1};
    gemm_mfma256<<<tS + tP, 512, 0, stream>>>(a, b, tS);
  }

  // decoder precompute pair: Adec = hp2 @ d1W[0:512,:] + d1b (bias folded), Bdec = hs2 @ d1W[512:1024,:]
  {
    GemmProb a = {P0, Wt[8], nullptr, nullptr, d1b, MP, NP, 0};
    GemmProb b = {S0, Wt[9], nullptr, nullptr, nullptr, MS, NS, 0};
    gemm_mfma256<<<tP + tS, 512, 0, stream>>>(a, b, tP);
  }

  // edge decoder (bf16 MFMA): grid-stride, W2/w1 LDS load amortized over ~6 chunks/wave
  edge_mfma_kernel<<<1024, 256, 0, stream>>>(MP, MS, w2f, d1W, d2b, meta_t, out);
}

// Round 13
// 529.440 us; speedup vs baseline: 3.1927x; 1.0481x over previous
//
#include <hip/hip_runtime.h>
#include <hip/hip_bf16.h>

typedef unsigned short u16;
typedef unsigned int u32;
typedef __attribute__((ext_vector_type(8))) short short8;
typedef __attribute__((ext_vector_type(4))) float f32x4;
typedef __attribute__((ext_vector_type(2))) float f32x2;

#define NP 20000
#define NS 10000
#define NE 400000
#define H  512
#define FDIM 64
#define ECHUNK 16

// fused-kernel block ranges
#define NB_HIST 1563            // hist: ceil(NE/256)
#define NB_WT   2560            // wtrans: 10 mats x 16x16 tiles
#define NB_W2F  4               // w2 fragment precompute
#define NB_SC   1563            // scatter: ceil(NE/256)
#define NB_PP   2500            // proj pol: ceil(NP/8)
#define NB_PS   1250            // proj stock: ceil(NS/8)

__device__ __forceinline__ float bl16(u32 w){ return __uint_as_float(w << 16); }
__device__ __forceinline__ float bh16(u32 w){ return __uint_as_float(w & 0xffff0000u); }
__device__ __forceinline__ u16 f2bf(float f){
  u32 u = __float_as_uint(f);
  u32 r = u + 0x7fffu + ((u >> 16) & 1u);
  return (u16)(r >> 16);
}
__device__ __forceinline__ u32 pack2(float a, float b){
  return (u32)f2bf(a) | ((u32)f2bf(b) << 16);
}
__device__ __forceinline__ void gload16(const void* g, void* l){
  __builtin_amdgcn_global_load_lds((const __attribute__((address_space(1))) u32*)g,
                                   (__attribute__((address_space(3))) u32*)l, 16, 0, 0);
}
// packed fp32 (VOP3P, gfx90a+): 2 fma / 2 add per instruction
__device__ __forceinline__ f32x2 pk_fma(f32x2 a, f32x2 b, f32x2 c){
  f32x2 d;
  asm("v_pk_fma_f32 %0, %1, %2, %3" : "=v"(d) : "v"(a), "v"(b), "v"(c));
  return d;
}
__device__ __forceinline__ f32x2 pk_add(f32x2 a, f32x2 b){
  f32x2 d;
  asm("v_pk_add_f32 %0, %1, %2" : "=v"(d) : "v"(a), "v"(b));
  return d;
}

// ---------------- fused setup: hist (ps/sp only) + wtrans + w2frag ----------------
struct TPair { const float* src; u16* dst; };
struct TArgs { TPair m[10]; };

__global__ __launch_bounds__(256) void setup_kernel(
    TArgs ta,
    const int* __restrict__ ps_dst, const int* __restrict__ sp_dst,
    int* __restrict__ cnt_s, int* __restrict__ cnt_p,
    const float* __restrict__ d2W, uint4* __restrict__ w2f)
{
  __shared__ float lds[32][33];
  int b = blockIdx.x;
  if (b < NB_HIST){
    int e = b*256 + threadIdx.x;
    if (e < NE){
      atomicAdd(&cnt_s[ps_dst[e]], 1);
      atomicAdd(&cnt_p[sp_dst[e]], 1);
    }
    return;
  }
  b -= NB_HIST;
  if (b < NB_WT){
    int mat = b >> 8;
    int rem = b & 255;
    const float* __restrict__ src = ta.m[mat].src;
    u16* __restrict__ dst = ta.m[mat].dst;
    int k0 = (rem >> 4) << 5, n0 = (rem & 15) << 5;
    int t = threadIdx.x;
    int r = t >> 3, c4 = (t & 7) << 2;
    float4 v = *(const float4*)(src + (size_t)(k0 + r)*H + n0 + c4);
    lds[r][c4+0] = v.x; lds[r][c4+1] = v.y; lds[r][c4+2] = v.z; lds[r][c4+3] = v.w;
    __syncthreads();
    uint2 o;
    o.x = pack2(lds[c4+0][r], lds[c4+1][r]);
    o.y = pack2(lds[c4+2][r], lds[c4+3][r]);
    *(uint2*)(dst + (size_t)(n0 + r)*H + k0 + c4) = o;
    return;
  }
  b -= NB_WT;
  {
    // W2 B-fragment precompute: w2f[ks*64+l] = bf16 W2[ks*32+(l>>4)*8 .. +7][l&15]
    int tid = b*256 + threadIdx.x;   // [0,1024)
    int l = tid & 63;
    int col = l & 15, g = l >> 4;
    int k = (tid >> 6)*32 + g*8;
    float v[8];
    #pragma unroll
    for (int j = 0; j < 8; ++j)
      v[j] = (col < 3) ? d2W[(size_t)(k+j)*3 + col] : 0.f;
    uint4 o;
    o.x = pack2(v[0], v[1]); o.y = pack2(v[2], v[3]);
    o.z = pack2(v[4], v[5]); o.w = pack2(v[6], v[7]);
    w2f[tid] = o;
  }
}

// ---------------- scan (wave-shuffle) ----------------
__device__ void scan_one(int* cnt, int n, int* rowptr)
{
  __shared__ int wsum[16];
  __shared__ int carry_s;
  int tid = threadIdx.x;
  int lane = tid & 63, wv = tid >> 6;
  if (tid == 0) carry_s = 0;
  for (int base = 0; base < n; base += 1024){
    __syncthreads();                       // protects carry_s/wsum reuse
    int i = base + tid;
    int v = (i < n) ? cnt[i] : 0;
    int x = v;
    #pragma unroll
    for (int off = 1; off < 64; off <<= 1){
      int t = __shfl_up(x, off);
      if (lane >= off) x += t;
    }
    if (lane == 63) wsum[wv] = x;
    __syncthreads();
    if (wv == 0 && lane < 16){
      int y = wsum[lane];
      #pragma unroll
      for (int off = 1; off < 16; off <<= 1){
        int t = __shfl_up(y, off, 16);
        if (lane >= off) y += t;
      }
      wsum[lane] = y;
    }
    __syncthreads();
    int woff = (wv > 0) ? wsum[wv-1] : 0;
    int cb = carry_s;
    int excl = cb + woff + x - v;
    if (i < n){ rowptr[i] = excl; cnt[i] = excl; }
    __syncthreads();
    if (tid == 1023) carry_s = cb + woff + x;   // running total
  }
  __syncthreads();
  if (tid == 0) rowptr[n] = carry_s;
}

__global__ __launch_bounds__(1024) void scan2_kernel(int* c0, int n0, int* r0,
                                                     int* c1, int n1, int* r1)
{
  if (blockIdx.x == 0) scan_one(c0, n0, r0);
  else scan_one(c1, n1, r1);
}

// ---------------- fused scatter (ps/sp only) + proj ----------------
__device__ void proj_body(const float* __restrict__ X, const float* __restrict__ W,
                          const float* __restrict__ b, u16* __restrict__ Y, int n,
                          int blk, float (*xs)[FDIM])
{
  int tid = threadIdx.x;
  int m0 = blk * 8;
  {
    int r = tid >> 6, c = tid & 63;
    int m = m0 + r;
    xs[r][c] = (m < n) ? X[(size_t)m*FDIM + c] : 0.f;
    m = m0 + r + 4;
    xs[r+4][c] = (m < n) ? X[(size_t)m*FDIM + c] : 0.f;
  }
  __syncthreads();
  float acc[8][2] = {};
  int c0 = tid, c1 = tid + 256;
  for (int k = 0; k < FDIM; ++k){
    float w0 = W[k*H + c0];
    float w1 = W[k*H + c1];
    #pragma unroll
    for (int r = 0; r < 8; ++r){
      float xv = xs[r][k];
      acc[r][0] = fmaf(xv, w0, acc[r][0]);
      acc[r][1] = fmaf(xv, w1, acc[r][1]);
    }
  }
  float b0 = b[c0], b1 = b[c1];
  #pragma unroll
  for (int r = 0; r < 8; ++r){
    int m = m0 + r;
    if (m < n){
      Y[(size_t)m*H + c0] = f2bf(fmaxf(acc[r][0] + b0, 0.f));
      Y[(size_t)m*H + c1] = f2bf(fmaxf(acc[r][1] + b1, 0.f));
    }
  }
}

__global__ __launch_bounds__(256) void scatter_proj_kernel(
    const int* __restrict__ ps_src, const int* __restrict__ ps_dst,
    const int* __restrict__ sp_src, const int* __restrict__ sp_dst,
    int* __restrict__ cur_s, int* __restrict__ cur_p,
    int* __restrict__ sorted_ps, int* __restrict__ sorted_sp,
    const float* __restrict__ x_pol, const float* __restrict__ Wp, const float* __restrict__ bp, u16* __restrict__ P0,
    const float* __restrict__ x_stock, const float* __restrict__ Ws_, const float* __restrict__ bs_, u16* __restrict__ S0)
{
  __shared__ float xs[8][FDIM];
  int b = blockIdx.x;
  if (b < NB_SC){
    int e = b*256 + threadIdx.x;
    if (e < NE){
      int pos = atomicAdd(&cur_s[ps_dst[e]], 1);
      sorted_ps[pos] = ps_src[e];
      int pos2 = atomicAdd(&cur_p[sp_dst[e]], 1);
      sorted_sp[pos2] = sp_src[e];
    }
    return;
  }
  b -= NB_SC;
  if (b < NB_PP){ proj_body(x_pol, Wp, bp, P0, NP, b, xs); return; }
  b -= NB_PP;
  proj_body(x_stock, Ws_, bs_, S0, NS, b, xs);
}

// ---------------- paired mean aggregation: one wave per dst row, 8 gathers in flight ----------------
__global__ __launch_bounds__(256) void agg2_kernel(
    const u16* __restrict__ X0, const int* __restrict__ rp0, const int* __restrict__ s0,
    u16* __restrict__ M0, int n0,
    const u16* __restrict__ X1, const int* __restrict__ rp1, const int* __restrict__ s1,
    u16* __restrict__ M1, int n1)
{
  int wid = (blockIdx.x << 2) + (threadIdx.x >> 6);
  int lane = threadIdx.x & 63;
  const u16* X; const int* rp; const int* ss; u16* M; int row;
  if (wid < n0){ X = X0; rp = rp0; ss = s0; M = M0; row = wid; }
  else if (wid < n0 + n1){ X = X1; rp = rp1; ss = s1; M = M1; row = wid - n0; }
  else return;
  int beg = rp[row], end = rp[row + 1];
  f32x2 ac0 = {0,0}, ac1 = {0,0}, ac2 = {0,0}, ac3 = {0,0};
  int j0 = lane << 3;
#define ACCP(v) { ac0 = pk_add(ac0, (f32x2){bl16(v.x), bh16(v.x)}); \
                  ac1 = pk_add(ac1, (f32x2){bl16(v.y), bh16(v.y)}); \
                  ac2 = pk_add(ac2, (f32x2){bl16(v.z), bh16(v.z)}); \
                  ac3 = pk_add(ac3, (f32x2){bl16(v.w), bh16(v.w)}); }
  int i = beg;
  for (; i + 8 <= end; i += 8){
    int sa = ss[i+0], sb = ss[i+1], sc = ss[i+2], sd = ss[i+3];
    int se = ss[i+4], sf = ss[i+5], sg = ss[i+6], sh = ss[i+7];
    uint4 v0 = *(const uint4*)(X + (size_t)sa*H + j0);
    uint4 v1 = *(const uint4*)(X + (size_t)sb*H + j0);
    uint4 v2 = *(const uint4*)(X + (size_t)sc*H + j0);
    uint4 v3 = *(const uint4*)(X + (size_t)sd*H + j0);
    uint4 v4 = *(const uint4*)(X + (size_t)se*H + j0);
    uint4 v5 = *(const uint4*)(X + (size_t)sf*H + j0);
    uint4 v6 = *(const uint4*)(X + (size_t)sg*H + j0);
    uint4 v7 = *(const uint4*)(X + (size_t)sh*H + j0);
    ACCP(v0); ACCP(v1); ACCP(v2); ACCP(v3);
    ACCP(v4); ACCP(v5); ACCP(v6); ACCP(v7);
  }
  for (; i + 2 <= end; i += 2){
    int sa = ss[i], sb = ss[i+1];
    uint4 v0 = *(const uint4*)(X + (size_t)sa*H + j0);
    uint4 v1 = *(const uint4*)(X + (size_t)sb*H + j0);
    ACCP(v0); ACCP(v1);
  }
  if (i < end){
    int sa = ss[i];
    uint4 v0 = *(const uint4*)(X + (size_t)sa*H + j0);
    ACCP(v0);
  }
#undef ACCP
  float inv = 1.f / (float)max(end - beg, 1);
  uint4 o;
  o.x = pack2(ac0.x*inv, ac0.y*inv);
  o.y = pack2(ac1.x*inv, ac1.y*inv);
  o.z = pack2(ac2.x*inv, ac2.y*inv);
  o.w = pack2(ac3.x*inv, ac3.y*inv);
  *(uint4*)(M + (size_t)row*H + j0) = o;
}

// ---------------- 256x256 deep-pipelined MFMA GEMM (T3+T4+T5), flattened grid ----------------
struct GemmProb {
  const u16* A1; const u16* W1t; const u16* A2; const u16* W2t;
  const float* bias; u16* C; int nrows; int relu;
};

__global__ __launch_bounds__(512) void gemm_mfma256(GemmProb Pa, GemmProb Pb, int aBlocks)
{
  int bid = blockIdx.x;
  GemmProb P; int idx;
  if (bid < aBlocks){ P = Pa; idx = bid; }
  else { P = Pb; idx = bid - aBlocks; }
  int n0 = (idx & 1) << 8;
  int m0 = (idx >> 1) << 8;
  if (m0 >= P.nrows) return;

  __shared__ u16 lds[2][2][256*64];   // [buf][A/B][rows*k] = 128 KB
  int t = threadIdx.x;
  int w = t >> 6, l = t & 63;
  int wm = w >> 2, wn = w & 3;        // 2 x 4 wave grid
  int lr = l & 15, lg = l >> 4;

  f32x4 acc[8][4];
  #pragma unroll
  for (int i = 0; i < 8; ++i)
    #pragma unroll
    for (int j = 0; j < 4; ++j)
      acc[i][j] = (f32x4){0.f, 0.f, 0.f, 0.f};

  const u16* Asrc0 = P.A1; const u16* Asrc1 = P.A2;
  const u16* Wsrc0 = P.W1t; const u16* Wsrc1 = P.W2t;
  int NT = P.A2 ? 16 : 8;

  auto STAGE = [&](int kt, int buf){
    const u16* Ap = (kt < 8) ? Asrc0 : Asrc1;
    const u16* Wp = (kt < 8) ? Wsrc0 : Wsrc1;
    int k0 = (kt & 7) << 6;
    char* AsB = (char*)lds[buf][0];
    char* BsB = (char*)lds[buf][1];
    #pragma unroll
    for (int i = 0; i < 4; ++i){
      int c = i*512 + t;
      int row = c >> 3, p = c & 7;
      int k8 = p ^ (row & 7);
      gload16(Ap + (size_t)(m0 + row)*H + k0 + k8*8, AsB + c*16);
      gload16(Wp + (size_t)(n0 + row)*H + k0 + k8*8, BsB + c*16);
    }
  };

  STAGE(0, 0);
  for (int kt = 0; kt < NT; ++kt){
    int cur = kt & 1;
    if (kt + 1 < NT){
      STAGE(kt + 1, cur ^ 1);
      asm volatile("s_waitcnt vmcnt(8)" ::: "memory");
    } else {
      asm volatile("s_waitcnt vmcnt(0)" ::: "memory");
    }
    __builtin_amdgcn_sched_barrier(0);
    __builtin_amdgcn_s_barrier();
    __builtin_amdgcn_sched_barrier(0);
    const char* AsB = (const char*)lds[cur][0];
    const char* BsB = (const char*)lds[cur][1];
    #pragma unroll
    for (int ph = 0; ph < 4; ++ph){
      const int mh = ph & 1, ks = ph >> 1;
      short8 a[4], b[4];
      int kc = (ks << 2) + lg;
      #pragma unroll
      for (int i = 0; i < 4; ++i){
        int r = (wm << 7) + (mh << 6) + (i << 4) + lr;
        a[i] = *(const short8*)(AsB + r*128 + ((kc ^ (r & 7)) << 4));
      }
      #pragma unroll
      for (int nf = 0; nf < 4; ++nf){
        int r = (wn << 6) + (nf << 4) + lr;
        b[nf] = *(const short8*)(BsB + r*128 + ((kc ^ (r & 7)) << 4));
      }
      __builtin_amdgcn_s_setprio(1);
      #pragma unroll
      for (int i = 0; i < 4; ++i)
        #pragma unroll
        for (int nf = 0; nf < 4; ++nf)
          acc[(mh << 2) + i][nf] =
            __builtin_amdgcn_mfma_f32_16x16x32_bf16(a[i], b[nf], acc[(mh << 2) + i][nf], 0, 0, 0);
      __builtin_amdgcn_s_setprio(0);
    }
    asm volatile("" ::: "memory");
    __builtin_amdgcn_s_barrier();
    __builtin_amdgcn_sched_barrier(0);
  }

  float bvn[4];
  #pragma unroll
  for (int nf = 0; nf < 4; ++nf)
    bvn[nf] = P.bias ? P.bias[n0 + (wn << 6) + (nf << 4) + lr] : 0.f;
  #pragma unroll
  for (int mf = 0; mf < 8; ++mf){
    #pragma unroll
    for (int j = 0; j < 4; ++j){
      int m = m0 + (wm << 7) + (mf << 4) + (lg << 2) + j;
      if (m < P.nrows){
        #pragma unroll
        for (int nf = 0; nf < 4; ++nf){
          float v = acc[mf][nf][j] + bvn[nf];
          if (P.relu) v = fmaxf(v, 0.f);
          P.C[(size_t)m*H + n0 + (wn << 6) + (nf << 4) + lr] = f2bf(v);
        }
      }
    }
  }
}

// ---------------- edge decoder via bf16 MFMA, CSR-FREE (R13) ----------------
// Grid-stride over 16-edge chunks in ORIGINAL edge order: metadata reads
// (trow/tcol/attr) are sequential+coalesced, and output writes are sequential
// (e = base + (g<<2)+j computed directly, no shuffle). lane l -> (edge er=l&15,
// channel-group g=l>>4); h in f32 packed math, packed to bf16 = the MFMA
// A-fragment in place; W2 B-fragments in LDS. D: row=edge, col=class.
__global__ __launch_bounds__(256) void edge_mfma_kernel(
    const u16* __restrict__ Adec, const u16* __restrict__ Bdec,   // bf16, d1b folded into Adec
    const uint4* __restrict__ w2f, const float* __restrict__ d1W,
    const float* __restrict__ d2b,
    const int* __restrict__ trow, const int* __restrict__ tcol,
    const float* __restrict__ attr,
    float* __restrict__ out)
{
  __shared__ uint4 w2s[16*64];      // 16 KB: bf16 W2 B-fragments per slice
  __shared__ float w1s[2][H];       // 4 KB: d1W rows 1024 (attr0) / 1025 (attr1)
  int t = threadIdx.x;
  #pragma unroll
  for (int i = 0; i < 4; ++i)
    w2s[i*256 + t] = w2f[i*256 + t];
  ((float4*)w1s)[t] = ((const float4*)(d1W + (size_t)1024*H))[t];   // 1024 consecutive floats
  __syncthreads();

  int lane = t & 63;
  int er = lane & 15, g = lane >> 4;
  int nch = NE / ECHUNK;
  int wstride = gridDim.x << 2;
  float ob = (er < 3) ? d2b[er] : 0.f;   // er == output class for writer lanes

  for (int ch = (blockIdx.x << 2) + (t >> 6); ch < nch; ch += wstride){
    int base = ch * ECHUNK;

    // lane i<16 loads edge base+i metadata directly (sequential, coalesced);
    // broadcasts below are in uniform control flow (R10 lesson)
    int rld = 0, cld = 0; float a0ld = 0.f, a1ld = 0.f;
    if (lane < ECHUNK){
      int e = base + lane;
      rld = trow[e]; cld = tcol[e];
      float2 av = *(const float2*)(attr + 2*(size_t)e);
      a0ld = av.x; a1ld = av.y;
    }
    int p  = __shfl(rld, er);
    int c  = __shfl(cld, er);
    float a0 = __shfl(a0ld, er);
    float a1 = __shfl(a1ld, er);
    f32x2 a0v = {a0, a0}, a1v = {a1, a1};

    const u16* Arow = Adec + (size_t)p*H + g*8;
    const u16* Brow = Bdec + (size_t)c*H + g*8;

    f32x4 acc = {0.f, 0.f, 0.f, 0.f};
    #pragma unroll
    for (int ks = 0; ks < 16; ++ks){
      uint4 va = *(const uint4*)(Arow + ks*32);
      uint4 vb = *(const uint4*)(Brow + ks*32);
      const float* wa = &w1s[0][ks*32 + g*8];
      const float* wb = &w1s[1][ks*32 + g*8];
      float4 wa0 = *(const float4*)(wa);
      float4 wa1 = *(const float4*)(wa + 4);
      float4 wb0 = *(const float4*)(wb);
      float4 wb1 = *(const float4*)(wb + 4);
      f32x2 h0 = pk_add((f32x2){bl16(va.x), bh16(va.x)}, (f32x2){bl16(vb.x), bh16(vb.x)});
      f32x2 h1 = pk_add((f32x2){bl16(va.y), bh16(va.y)}, (f32x2){bl16(vb.y), bh16(vb.y)});
      f32x2 h2 = pk_add((f32x2){bl16(va.z), bh16(va.z)}, (f32x2){bl16(vb.z), bh16(vb.z)});
      f32x2 h3 = pk_add((f32x2){bl16(va.w), bh16(va.w)}, (f32x2){bl16(vb.w), bh16(vb.w)});
      h0 = pk_fma(a0v, (f32x2){wa0.x, wa0.y}, h0);
      h1 = pk_fma(a0v, (f32x2){wa0.z, wa0.w}, h1);
      h2 = pk_fma(a0v, (f32x2){wa1.x, wa1.y}, h2);
      h3 = pk_fma(a0v, (f32x2){wa1.z, wa1.w}, h3);
      h0 = pk_fma(a1v, (f32x2){wb0.x, wb0.y}, h0);
      h1 = pk_fma(a1v, (f32x2){wb0.z, wb0.w}, h1);
      h2 = pk_fma(a1v, (f32x2){wb1.x, wb1.y}, h2);
      h3 = pk_fma(a1v, (f32x2){wb1.z, wb1.w}, h3);
      uint4 hh;
      hh.x = pack2(fmaxf(h0.x, 0.f), fmaxf(h0.y, 0.f));
      hh.y = pack2(fmaxf(h1.x, 0.f), fmaxf(h1.y, 0.f));
      hh.z = pack2(fmaxf(h2.x, 0.f), fmaxf(h2.y, 0.f));
      hh.w = pack2(fmaxf(h3.x, 0.f), fmaxf(h3.y, 0.f));
      short8 pa = __builtin_bit_cast(short8, hh);
      short8 pb = __builtin_bit_cast(short8, w2s[ks*64 + lane]);
      acc = __builtin_amdgcn_mfma_f32_16x16x32_bf16(pa, pb, acc, 0, 0, 0);
    }

    if (er < 3){
      #pragma unroll
      for (int j = 0; j < 4; ++j){
        int e = base + (g << 2) + j;           // direct, sequential output index
        out[(size_t)e*3 + er] = acc[j] + ob;
      }
    }
  }
}

extern "C" void kernel_launch(void* const* d_in, const int* in_sizes, int n_in,
                              void* d_out, int out_size, void* d_ws, size_t ws_size,
                              hipStream_t stream)
{
  const float* x_pol    = (const float*)d_in[0];
  const float* x_stock  = (const float*)d_in[1];
  const float* attr     = (const float*)d_in[2];
  const float* Wp       = (const float*)d_in[3];
  const float* bp       = (const float*)d_in[4];
  const float* Wst      = (const float*)d_in[5];
  const float* bst      = (const float*)d_in[6];
  const float* c1_ps_Wl = (const float*)d_in[7];
  const float* c1_ps_bl = (const float*)d_in[8];
  const float* c1_ps_Wr = (const float*)d_in[9];
  const float* c1_sp_Wl = (const float*)d_in[10];
  const float* c1_sp_bl = (const float*)d_in[11];
  const float* c1_sp_Wr = (const float*)d_in[12];
  const float* c2_ps_Wl = (const float*)d_in[13];
  const float* c2_ps_bl = (const float*)d_in[14];
  const float* c2_ps_Wr = (const float*)d_in[15];
  const float* c2_sp_Wl = (const float*)d_in[16];
  const float* c2_sp_bl = (const float*)d_in[17];
  const float* c2_sp_Wr = (const float*)d_in[18];
  const float* d1W      = (const float*)d_in[19];
  const float* d1b      = (const float*)d_in[20];
  const float* d2W      = (const float*)d_in[21];
  const float* d2b      = (const float*)d_in[22];
  const int* ps_src     = (const int*)d_in[23];
  const int* ps_dst     = (const int*)d_in[24];
  const int* sp_src     = (const int*)d_in[25];
  const int* sp_dst     = (const int*)d_in[26];
  const int* trow       = (const int*)d_in[27];
  const int* tcol       = (const int*)d_in[28];
  float* out = (float*)d_out;

  char* ws = (char*)d_ws;
  size_t off = 0;
  auto alloc = [&](size_t bytes)->char*{
    char* p = ws + off;
    off += (bytes + 255) & ~(size_t)255;
    return p;
  };
  u16* P0 = (u16*)alloc((size_t)NP*H*2);   // hp -> hp2
  u16* P1 = (u16*)alloc((size_t)NP*H*2);   // hp1
  u16* S0 = (u16*)alloc((size_t)NS*H*2);   // hs -> hs2
  u16* S1 = (u16*)alloc((size_t)NS*H*2);   // hs1
  u16* MP = (u16*)alloc((size_t)NP*H*2);   // mean into pol / Adec
  u16* MS = (u16*)alloc((size_t)NS*H*2);   // mean into stock / Bdec
  u16* Wt[10];
  for (int i = 0; i < 10; ++i) Wt[i] = (u16*)alloc((size_t)H*H*2);
  int* cnt_s    = (int*)alloc((size_t)NS*4);      // becomes cursor after scan
  int* cnt_p    = (int*)alloc((size_t)NP*4);
  int* rowptr_s = (int*)alloc((size_t)(NS+1)*4);
  int* rowptr_p = (int*)alloc((size_t)(NP+1)*4);
  int* sorted_ps = (int*)alloc((size_t)NE*4);
  int* sorted_sp = (int*)alloc((size_t)NE*4);
  uint4* w2f     = (uint4*)alloc((size_t)16*64*16);
  // pad region: 256-row tile-tail staging reads past last matrix stay in-bounds
  alloc((size_t)256*H*2);

  TArgs ta;
  ta.m[0] = {c1_ps_Wl, Wt[0]}; ta.m[1] = {c1_ps_Wr, Wt[1]};
  ta.m[2] = {c1_sp_Wl, Wt[2]}; ta.m[3] = {c1_sp_Wr, Wt[3]};
  ta.m[4] = {c2_ps_Wl, Wt[4]}; ta.m[5] = {c2_ps_Wr, Wt[5]};
  ta.m[6] = {c2_sp_Wl, Wt[6]}; ta.m[7] = {c2_sp_Wr, Wt[7]};
  ta.m[8] = {d1W, Wt[8]};                      // d1_W rows 0..511   (pol part)
  ta.m[9] = {d1W + (size_t)512*H, Wt[9]};      // d1_W rows 512..1023 (stock part)

  // memsets, then fused setup (hist + wtrans + w2frag)
  hipMemsetAsync(cnt_s, 0, (size_t)NS*4, stream);
  hipMemsetAsync(cnt_p, 0, (size_t)NP*4, stream);
  setup_kernel<<<NB_HIST + NB_WT + NB_W2F, 256, 0, stream>>>(
      ta, ps_dst, sp_dst, cnt_s, cnt_p, d2W, w2f);

  scan2_kernel<<<2, 1024, 0, stream>>>(cnt_s, NS, rowptr_s, cnt_p, NP, rowptr_p);

  // fused scatter (ps/sp only, latency-bound) + input projections
  scatter_proj_kernel<<<NB_SC + NB_PP + NB_PS, 256, 0, stream>>>(
      ps_src, ps_dst, sp_src, sp_dst,
      cnt_s, cnt_p, sorted_ps, sorted_sp,
      x_pol, Wp, bp, P0, x_stock, Wst, bst, S0);

  int aggGrid = (NS + NP + 3) / 4;
  int tS = ((NS + 255) / 256) * 2;   // N=512 -> 2 column tiles per M tile
  int tP = ((NP + 255) / 256) * 2;

  // conv1: MS = mean_ps(P0), MP = mean_sp(S0); then paired GEMM (flattened grid)
  agg2_kernel<<<aggGrid, 256, 0, stream>>>(P0, rowptr_s, sorted_ps, MS, NS,
                                           S0, rowptr_p, sorted_sp, MP, NP);
  {
    GemmProb a = {MS, Wt[0], S0, Wt[1], c1_ps_bl, S1, NS, 1};
    GemmProb b = {MP, Wt[2], P0, Wt[3], c1_sp_bl, P1, NP, 1};
    gemm_mfma256<<<tS + tP, 512, 0, stream>>>(a, b, tS);
  }

  // conv2
  agg2_kernel<<<aggGrid, 256, 0, stream>>>(P1, rowptr_s, sorted_ps, MS, NS,
                                           S1, rowptr_p, sorted_sp, MP, NP);
  {
    GemmProb a = {MS, Wt[4], S1, Wt[5], c2_ps_bl, S0, NS, 1};
    GemmProb b = {MP, Wt[6], P1, Wt[7], c2_sp_bl, P0, NP, 1};
    gemm_mfma256<<<tS + tP, 512, 0, stream>>>(a, b, tS);
  }

  // decoder precompute pair: Adec = hp2 @ d1W[0:512,:] + d1b (bias folded), Bdec = hs2 @ d1W[512:1024,:]
  {
    GemmProb a = {P0, Wt[8], nullptr, nullptr, d1b, MP, NP, 0};
    GemmProb b = {S0, Wt[9], nullptr, nullptr, nullptr, MS, NS, 0};
    gemm_mfma256<<<tP + tS, 512, 0, stream>>>(a, b, tP);
  }

  // edge decoder (bf16 MFMA, CSR-free): grid-stride over 16-edge chunks
  edge_mfma_kernel<<<1024, 256, 0, stream>>>(MP, MS, w2f, d1W, d2b,
                                             trow, tcol, attr, out);
}